// Round 1
// 689.686 us; speedup vs baseline: 1.0970x; 1.0970x over previous
//
#include <hip/hip_runtime.h>
#include <hip/hip_bf16.h>
#include <math.h>

// MLA forward: B=2, S=2048, D=2048, H=16, KV_RANK=512, NOPE=128, ROPE=64
#define B_ 2
#define S_ 2048
#define H_ 16
#define SCALE_ 0.07216878364870323f   // 192^-0.5
#define EPS_ 1.1920929e-07f
#define M0_ 8.0f                      // constant exp shift (cancels in o/l)

typedef __attribute__((ext_vector_type(8))) short bf16x8;
typedef __attribute__((ext_vector_type(4))) float f32x4;
union U4 { uint4 u; bf16x8 v; f32x4 f; };

__device__ __forceinline__ uint bfbits(float x) {   // f32 -> bf16 bits, RNE
    uint u = __float_as_uint(x);
    return (u + 0x7fffu + ((u >> 16) & 1u)) >> 16;
}
__device__ __forceinline__ uint pack2bf(float a, float b) {
    return bfbits(a) | (bfbits(b) << 16);
}
__device__ __forceinline__ void gld_lds16(const ushort* g, ushort* l) {
    // async global->LDS DMA, 16B/lane; LDS dest = wave-uniform base + lane*16
    __builtin_amdgcn_global_load_lds(
        (const __attribute__((address_space(1))) uint*)g,
        (__attribute__((address_space(3))) uint*)l, 16, 0, 0);
}

// ---------------------------------------------------------------------------
// MFMA bf16 GEMM (NT): C[m,n] = scale * sum_k A[m,k]*B[n,k] + bias[n]
// 128x128 tile, BK=32, 256 thr (4 waves 2x2 of 64x64), 16x16x32 MFMA.
// ---------------------------------------------------------------------------
template<bool OUT_BF16>
__global__ __launch_bounds__(256) void mgemm(
    const ushort* __restrict__ A, int lda, long long aOff,
    const ushort* __restrict__ Bm, int ldb, long long bOff,
    const float* __restrict__ bias, float scale,
    void* __restrict__ Cv, int ldc, long long cOff, int K)
{
    __shared__ ushort As[128 * 32];
    __shared__ ushort Bs[128 * 32];

    const int z = blockIdx.z;
    A  += (long long)z * aOff;
    Bm += (long long)z * bOff;

    const int n0 = blockIdx.x * 128;
    const int m0 = blockIdx.y * 128;
    const int tid = threadIdx.x;
    const int w   = tid >> 6;
    const int l   = tid & 63;
    const int m   = l & 15;
    const int q4  = l >> 4;
    const int mw  = (w & 1) * 64;
    const int nw  = (w >> 1) * 64;
    const int sr  = l >> 2;
    const int sc  = l & 3;

    f32x4 acc[4][4];
#pragma unroll
    for (int i = 0; i < 4; ++i)
#pragma unroll
        for (int j = 0; j < 4; ++j) acc[i][j] = (f32x4){0.f, 0.f, 0.f, 0.f};

    for (int k0 = 0; k0 < K; k0 += 32) {
#pragma unroll
        for (int jj = 0; jj < 2; ++jj) {
            const int slot = w * 2 + jj;
            const int row  = slot * 16 + sr;
            const int g    = sc ^ ((row >> 1) & 3);
            gld_lds16(&A[(long long)(m0 + row) * lda + k0 + g * 8], &As[slot * 512]);
            gld_lds16(&Bm[(long long)(n0 + row) * ldb + k0 + g * 8], &Bs[slot * 512]);
        }
        __syncthreads();

        U4 af[4], bf[4];
#pragma unroll
        for (int i = 0; i < 4; ++i) {
            const int ra = mw + i * 16 + m;
            af[i].u = *(const uint4*)&As[ra * 32 + (q4 ^ ((ra >> 1) & 3)) * 8];
            const int rb = nw + i * 16 + m;
            bf[i].u = *(const uint4*)&Bs[rb * 32 + (q4 ^ ((rb >> 1) & 3)) * 8];
        }
#pragma unroll
        for (int i = 0; i < 4; ++i)
#pragma unroll
            for (int j = 0; j < 4; ++j)
                acc[i][j] = __builtin_amdgcn_mfma_f32_16x16x32_bf16(
                    af[i].v, bf[j].v, acc[i][j], 0, 0, 0);
        __syncthreads();
    }

#pragma unroll
    for (int j = 0; j < 4; ++j) {
        const int cn = n0 + nw + j * 16 + m;
        const float bv = bias ? bias[cn] : 0.0f;
#pragma unroll
        for (int i = 0; i < 4; ++i) {
            const int rw = m0 + mw + i * 16 + q4 * 4;
#pragma unroll
            for (int r = 0; r < 4; ++r) {
                const float val = acc[i][j][r] * scale + bv;
                if (OUT_BF16)
                    ((ushort*)Cv)[(long long)z * cOff + (long long)(rw + r) * ldc + cn] =
                        (ushort)bfbits(val);
                else
                    ((float*)Cv)[(long long)z * cOff + (long long)(rw + r) * ldc + cn] = val;
            }
        }
    }
}

// ---------------------------------------------------------------------------
// f32 -> bf16 converters
// ---------------------------------------------------------------------------
__global__ __launch_bounds__(256) void conv_bf16(
    const float* __restrict__ s, ushort* __restrict__ d)
{
    const long long i = ((long long)blockIdx.x * 256 + threadIdx.x) * 4;
    float4 v = *(const float4*)&s[i];
    uint2 p; p.x = pack2bf(v.x, v.y); p.y = pack2bf(v.z, v.w);
    *(uint2*)&d[i] = p;
}

__global__ __launch_bounds__(256) void conv_wkva(
    const float* __restrict__ s, ushort* __restrict__ d)
{
    const int i = (blockIdx.x * 256 + threadIdx.x) * 4;
    const int r = i >> 11;
    uint2 p = make_uint2(0u, 0u);
    if (r < 576) {
        float4 v = *(const float4*)&s[i];
        p.x = pack2bf(v.x, v.y); p.y = pack2bf(v.z, v.w);
    }
    *(uint2*)&d[i] = p;
}

__global__ __launch_bounds__(256) void conv_wkvb_t(
    const float* __restrict__ Wsrc, ushort* __restrict__ T)
{
    __shared__ float tile[32][33];
    const int h = blockIdx.z, dt = blockIdx.y, ct = blockIdx.x;
    const int tx = threadIdx.x & 31, ty = threadIdx.x >> 5;
#pragma unroll
    for (int p8 = 0; p8 < 4; ++p8) {
        const int dd = dt * 32 + ty + p8 * 8;
        tile[ty + p8 * 8][tx] = Wsrc[((long long)(h * 256 + dd)) * 512 + ct * 32 + tx];
    }
    __syncthreads();
#pragma unroll
    for (int p8 = 0; p8 < 4; ++p8) {
        const int cc = ct * 32 + ty + p8 * 8;
        T[((long long)h * 512 + cc) * 128 + dt * 32 + tx] =
            (ushort)bfbits(tile[tx][ty + p8 * 8]);
    }
}

__global__ __launch_bounds__(256) void conv_wkvbv(
    const float* __restrict__ Wsrc, ushort* __restrict__ V)
{
    const int i = (blockIdx.x * 256 + threadIdx.x) * 4;
    const int h = i >> 16;
    const int rem = i & 65535;
    float4 v = *(const float4*)&Wsrc[((long long)(h * 256 + 128)) * 512 + rem];
    uint2 p; p.x = pack2bf(v.x, v.y); p.y = pack2bf(v.z, v.w);
    *(uint2*)&V[i] = p;
}

__global__ __launch_bounds__(256) void conv_qn(
    const float* __restrict__ q_raw, ushort* __restrict__ qn)
{
    const int i = (blockIdx.x * 256 + threadIdx.x) * 4;
    const int bs = i >> 11;
    const int c = i & 2047;
    const int hh = c >> 7, d = c & 127;
    float4 v = *(const float4*)&q_raw[(long long)bs * 3072 + hh * 192 + d];
    uint2 p; p.x = pack2bf(v.x, v.y); p.y = pack2bf(v.z, v.w);
    *(uint2*)&qn[i] = p;
}

// ---------------------------------------------------------------------------
// RoPE on q_raw[...,128:192] -> q_h[...,512:576] bf16, scale folded.
// ---------------------------------------------------------------------------
__global__ __launch_bounds__(256) void rope_q_kernel(
    const float* __restrict__ q_raw, const float* __restrict__ freqs,
    ushort* __restrict__ q_h)
{
    const int idx = blockIdx.x * 256 + threadIdx.x;
    const int i = idx & 31;
    const int h = (idx >> 5) & 15;
    const int s = (idx >> 9) & 2047;
    const int b = idx >> 20;
    const float f = freqs[s * 32 + i];
    float cs, sn;
    __sincosf(f, &sn, &cs);
    const int row = (b * S_ + s) * H_ + h;
    const float a  = q_raw[(long long)row * 192 + 128 + 2 * i];
    const float bb = q_raw[(long long)row * 192 + 128 + 2 * i + 1];
    *(uint*)&q_h[(long long)row * 576 + 512 + 2 * i] =
        pack2bf((a * cs - bb * sn) * SCALE_, (a * sn + bb * cs) * SCALE_);
}

// ---------------------------------------------------------------------------
// kv post: bias add + rmsnorm(kv[:512]) and rope(kv[512:576]) -> kv_h bf16.
// ---------------------------------------------------------------------------
__global__ __launch_bounds__(64) void kv_post_kernel(
    const float* __restrict__ kv_raw, const float* __restrict__ bias,
    const float* __restrict__ w, const float* __restrict__ freqs,
    ushort* __restrict__ kv_h)
{
    const int bs = blockIdx.x;
    const int lane = threadIdx.x;
    const float* src = kv_raw + (long long)bs * 640;
    ushort* dst = kv_h + (long long)bs * 576;

    const int c = 4 * lane;
    float4 v0 = *(const float4*)&src[c];
    float4 v1 = *(const float4*)&src[256 + c];
    float4 b0 = *(const float4*)&bias[c];
    float4 b1 = *(const float4*)&bias[256 + c];
    v0.x += b0.x; v0.y += b0.y; v0.z += b0.z; v0.w += b0.w;
    v1.x += b1.x; v1.y += b1.y; v1.z += b1.z; v1.w += b1.w;
    float ss = v0.x * v0.x + v0.y * v0.y + v0.z * v0.z + v0.w * v0.w +
               v1.x * v1.x + v1.y * v1.y + v1.z * v1.z + v1.w * v1.w;
#pragma unroll
    for (int o = 32; o; o >>= 1) ss += __shfl_xor(ss, o, 64);
    const float rs = rsqrtf(ss * (1.0f / 512.0f) + EPS_);

    float4 w0 = *(const float4*)&w[c];
    float4 w1 = *(const float4*)&w[256 + c];
    uint2 p0, p1;
    p0.x = pack2bf(v0.x * rs * w0.x, v0.y * rs * w0.y);
    p0.y = pack2bf(v0.z * rs * w0.z, v0.w * rs * w0.w);
    p1.x = pack2bf(v1.x * rs * w1.x, v1.y * rs * w1.y);
    p1.y = pack2bf(v1.z * rs * w1.z, v1.w * rs * w1.w);
    *(uint2*)&dst[c] = p0;
    *(uint2*)&dst[256 + c] = p1;

    if (lane < 32) {
        const int s = bs & 2047;
        const float f = freqs[s * 32 + lane];
        float cs, sn;
        __sincosf(f, &sn, &cs);
        const float a  = src[512 + 2 * lane]     + bias[512 + 2 * lane];
        const float b2 = src[512 + 2 * lane + 1] + bias[512 + 2 * lane + 1];
        *(uint*)&dst[512 + 2 * lane] = pack2bf(a * cs - b2 * sn, a * sn + b2 * cs);
    }
}

// ---------------------------------------------------------------------------
// kv_t[b][d][s] = kv_h[b][s][d] (d<512): transposed latent, bf16 (s-pair dw).
// ---------------------------------------------------------------------------
__global__ __launch_bounds__(256) void transpose_kv(
    const ushort* __restrict__ kv_h, ushort* __restrict__ kv_t)
{
    __shared__ ushort t[64][68];
    const int b = blockIdx.z;
    const int s0 = blockIdx.x * 64, d0 = blockIdx.y * 64;
    const int c4 = (threadIdx.x & 15) * 4, rr = threadIdx.x >> 4;
#pragma unroll
    for (int i = 0; i < 4; ++i) {
        const int s = rr + i * 16;
        uint2 v = *(const uint2*)&kv_h[(long long)(b * S_ + s0 + s) * 576 + d0 + c4];
        *(uint2*)&t[s][c4] = v;
    }
    __syncthreads();
#pragma unroll
    for (int i = 0; i < 4; ++i) {
        const int d = rr + i * 16;
        uint2 o;
        o.x = (uint)t[c4 + 0][d] | ((uint)t[c4 + 1][d] << 16);
        o.y = (uint)t[c4 + 2][d] | ((uint)t[c4 + 3][d] << 16);
        *(uint2*)&kv_t[((long long)b * 512 + d0 + d) * 2048 + s0 + c4] = o;
    }
}

// ---------------------------------------------------------------------------
// Fragment-image prep: pre-order KV tiles in global memory so the attention
// staging DMA is fully coalesced 1-KB chunks (lane*16B from a chunk base).
// kv_fk[b][tile][chunk=(f,qsel)][lane=(qh,t)] = K[t0+t][octet k8=f*4+qsel*2+qh]
// ---------------------------------------------------------------------------
__global__ __launch_bounds__(256) void prep_fk(
    const ushort* __restrict__ kv_h, uint4* __restrict__ kv_fk)
{
    const int b = blockIdx.z, tile = blockIdx.y;
    const int g = blockIdx.x * 256 + threadIdx.x;   // 0..2303
    const int chunk = g >> 6, lane = g & 63;
    const int f = chunk >> 1, qsel = chunk & 1;
    const int qh = lane >> 5, t = lane & 31;
    const int k8 = f * 4 + qsel * 2 + qh;
    const uint4 v = *(const uint4*)&kv_h[((long long)(b * S_ + tile * 32 + t)) * 576 + k8 * 8];
    kv_fk[((long long)(b * 64 + tile) * 36 + chunk) * 64 + lane] = v;
}

// kv_fv[b][tile][c][lane=(q4,m)] = kv_t dwords [d=c*16+m][spair=tile*16+q4*4 ..+3]
__global__ __launch_bounds__(256) void prep_fv(
    const uint* __restrict__ kv_t, uint4* __restrict__ kv_fv)
{
    const int b = blockIdx.z, tile = blockIdx.y;
    const int g = blockIdx.x * 256 + threadIdx.x;   // 0..2047
    const int c = g >> 6, lane = g & 63;
    const int q4 = lane >> 4, m = lane & 15;
    const uint4 v = *(const uint4*)&kv_t[((long long)b * 512 + c * 16 + m) * 1024 + tile * 16 + q4 * 4];
    kv_fv[((long long)(b * 64 + tile) * 32 + c) * 64 + lane] = v;
}

// ---------------------------------------------------------------------------
// MFMA flash attention v8 = v7 compute restructured for LDS-read reuse +
// stage/compute overlap + causal load balance.
//   * 2 heads per wave: every K/V A-fragment ds_read feeds 2 MFMAs
//     (halves LDS bytes per FLOP — v7 was LDS-read-bound, 1 KB/MFMA).
//   * double-buffered LDS (2x 68 KB = 136 KB), next tile's global_load_lds
//     issued right after the barrier, overlapped under current tile compute;
//     one __syncthreads (vmcnt drain) per tile.
//   * strip pairing: block px does q-strip 127-px then strip px ->
//     exactly 65 KV tiles per block; grid 64x2x2 = 256 blocks = 1/CU.
// Block = 256 thr = 4 waves; wave = 2 heads x 16 q-rows.
// ---------------------------------------------------------------------------
__global__ __launch_bounds__(256, 1) void attn_kernel(
    const ushort* __restrict__ q_h,   // (B,S,H,576), q*scale
    const uint4*  __restrict__ kv_fk, // (B,64,36,64) K frag chunks
    const uint4*  __restrict__ kv_fv, // (B,64,32,64) V^T frag chunks
    ushort* __restrict__ o_h)         // (B,S,H,512)
{
    __shared__ uint kvsd[2][36 * 256];   // 2 x 36864 B: chunk-ordered K frags
    __shared__ uint vtsd[2][32 * 256];   // 2 x 32768 B: chunk-ordered V^T frags

    const int px   = blockIdx.x;          // 0..63 (strip pair)
    const int hg   = blockIdx.y;          // 0..1
    const int b    = blockIdx.z;
    const int tid  = threadIdx.x;
    const int wid  = tid >> 6;            // 0..3
    const int lane = tid & 63;
    const int m    = lane & 15;
    const int q4   = lane >> 4;
    const int h0   = hg * 8 + wid * 2;    // two heads per wave: h0, h0+1

    auto stage_tile = [&](int bs, int it) {
        const uint4* fkb = kv_fk + ((long long)(b * 64 + it) * 36) * 64;
        const uint4* fvb = kv_fv + ((long long)(b * 64 + it) * 32) * 64;
        uint* kb = kvsd[bs];
        uint* vb = vtsd[bs];
#pragma unroll
        for (int jw = 0; jw < 9; ++jw) {
            const int i = wid + 4 * jw;            // 0..35
            gld_lds16((const ushort*)(fkb + i * 64 + lane), (ushort*)&kb[i * 256]);
        }
#pragma unroll
        for (int jw = 0; jw < 8; ++jw) {
            const int c = wid + 4 * jw;            // 0..31
            gld_lds16((const ushort*)(fvb + c * 64 + lane), (ushort*)&vb[c * 256]);
        }
    };

    int cur = 0;
    for (int pass = 0; pass < 2; ++pass) {
        const int qs   = pass ? px : (127 - px);   // big strip first
        const int row0 = qs * 16;
        const int sRow = row0 + m;

        // Q B-frags for both heads (full 576 k): qf[f] = Q[sRow][f*32+q4*8+j]
        U4 qfa[18], qfb[18];
        {
            const uint4* qpa = (const uint4*)(q_h + ((long long)(b * S_ + sRow) * H_ + h0) * 576);
            const uint4* qpb = (const uint4*)(q_h + ((long long)(b * S_ + sRow) * H_ + h0 + 1) * 576);
#pragma unroll
            for (int f = 0; f < 18; ++f) { qfa[f].u = qpa[f * 4 + q4]; qfb[f].u = qpb[f * 4 + q4]; }
        }

        f32x4 oa[32], ob[32];
#pragma unroll
        for (int c = 0; c < 32; ++c) {
            oa[c] = (f32x4){0.f, 0.f, 0.f, 0.f};
            ob[c] = (f32x4){0.f, 0.f, 0.f, 0.f};
        }
        float lacc0 = 0.0f, lacc1 = 0.0f;

        // softmax + P^T repack into PV B-fragment (per head)
        auto softpack = [&](const f32x4 s0, const f32x4 s1, int t0v, float& lac) -> U4 {
            const int tb0 = t0v + q4 * 4;
            const int tb1 = t0v + 16 + q4 * 4;
            float p00 = (tb0 + 0 <= sRow) ? __expf(s0[0] - M0_) : 0.0f;
            float p01 = (tb0 + 1 <= sRow) ? __expf(s0[1] - M0_) : 0.0f;
            float p02 = (tb0 + 2 <= sRow) ? __expf(s0[2] - M0_) : 0.0f;
            float p03 = (tb0 + 3 <= sRow) ? __expf(s0[3] - M0_) : 0.0f;
            float p10 = (tb1 + 0 <= sRow) ? __expf(s1[0] - M0_) : 0.0f;
            float p11 = (tb1 + 1 <= sRow) ? __expf(s1[1] - M0_) : 0.0f;
            float p12 = (tb1 + 2 <= sRow) ? __expf(s1[2] - M0_) : 0.0f;
            float p13 = (tb1 + 3 <= sRow) ? __expf(s1[3] - M0_) : 0.0f;
            lac += (p00 + p01) + (p02 + p03) + (p10 + p11) + (p12 + p13);
            U4 bb;
            {
                uint pk00 = pack2bf(p00, p01);
                uint pk01 = pack2bf(p02, p03);
                uint pk10 = pack2bf(p10, p11);
                uint pk11 = pack2bf(p12, p13);
                const int srcA = ((lane >> 4) & 1) * 32 + m;
                const int srcB = srcA + 16;
                uint a00 = (uint)__shfl((int)pk00, srcA, 64);
                uint a01 = (uint)__shfl((int)pk01, srcA, 64);
                uint a10 = (uint)__shfl((int)pk10, srcA, 64);
                uint a11 = (uint)__shfl((int)pk11, srcA, 64);
                uint b00 = (uint)__shfl((int)pk00, srcB, 64);
                uint b01 = (uint)__shfl((int)pk01, srcB, 64);
                uint b10 = (uint)__shfl((int)pk10, srcB, 64);
                uint b11 = (uint)__shfl((int)pk11, srcB, 64);
                const bool hi2 = (lane >> 5) & 1;
                bb.u.x = hi2 ? a10 : a00;
                bb.u.y = hi2 ? a11 : a01;
                bb.u.z = hi2 ? b10 : b00;
                bb.u.w = hi2 ? b11 : b01;
            }
            return bb;
        };

        const int nT = (row0 + 47) >> 5;
        __syncthreads();                 // all compute on LDS from prev pass done
        stage_tile(cur, 0);              // issue tile 0 of this pass

        for (int it = 0; it < nT; ++it) {
            const int t0 = it * 32;
            __syncthreads();             // drains vmcnt(0): buf[cur] staged, all waves see it
            if (it + 1 < nT) stage_tile(cur ^ 1, it + 1);   // overlap under compute
            __builtin_amdgcn_sched_barrier(0);              // keep load issue before compute

            const uint* kb = kvsd[cur];
            const uint* vb = vtsd[cur];

            // ---- S^T = K . Q^T for both heads; each A-frag read feeds 2 MFMAs
            f32x4 st0a = (f32x4){0.f,0.f,0.f,0.f}, st0b = (f32x4){0.f,0.f,0.f,0.f};
            f32x4 st1a = (f32x4){0.f,0.f,0.f,0.f}, st1b = (f32x4){0.f,0.f,0.f,0.f};
            const bool skip1 = (t0 >= row0);
            const int abase = (q4 & 1) * 128 + m * 4;
            if (!skip1) {
#pragma unroll
                for (int f = 0; f < 18; ++f) {
                    const uint* cb = &kb[(f * 2 + (q4 >> 1)) * 256];
                    U4 a0, a1;
                    a0.u = *(const uint4*)&cb[abase];
                    a1.u = *(const uint4*)&cb[abase + 64];
                    st0a = __builtin_amdgcn_mfma_f32_16x16x32_bf16(a0.v, qfa[f].v, st0a, 0, 0, 0);
                    st0b = __builtin_amdgcn_mfma_f32_16x16x32_bf16(a0.v, qfb[f].v, st0b, 0, 0, 0);
                    st1a = __builtin_amdgcn_mfma_f32_16x16x32_bf16(a1.v, qfa[f].v, st1a, 0, 0, 0);
                    st1b = __builtin_amdgcn_mfma_f32_16x16x32_bf16(a1.v, qfb[f].v, st1b, 0, 0, 0);
                }
            } else {
#pragma unroll
                for (int f = 0; f < 18; ++f) {
                    const uint* cb = &kb[(f * 2 + (q4 >> 1)) * 256];
                    U4 a0;
                    a0.u = *(const uint4*)&cb[abase];
                    st0a = __builtin_amdgcn_mfma_f32_16x16x32_bf16(a0.v, qfa[f].v, st0a, 0, 0, 0);
                    st0b = __builtin_amdgcn_mfma_f32_16x16x32_bf16(a0.v, qfb[f].v, st0b, 0, 0, 0);
                }
            }

            // ---- mask + exp(s - M0) + P^T repack, per head
            U4 bba = softpack(st0a, st1a, t0, lacc0);
            U4 bbb = softpack(st0b, st1b, t0, lacc1);

            // ---- PV over full 512 d: O^T += V^T . P^T; av read feeds 2 MFMAs
#pragma unroll
            for (int c = 0; c < 32; ++c) {
                U4 av; av.u = *(const uint4*)&vb[c * 256 + q4 * 64 + m * 4];
                oa[c] = __builtin_amdgcn_mfma_f32_16x16x32_bf16(av.v, bba.v, oa[c], 0, 0, 0);
                ob[c] = __builtin_amdgcn_mfma_f32_16x16x32_bf16(av.v, bbb.v, ob[c], 0, 0, 0);
            }
            cur ^= 1;
        }

        // ---- epilogue: reduce l across q4 groups; normalize; store (both heads)
        lacc0 += __shfl_xor(lacc0, 16, 64);
        lacc0 += __shfl_xor(lacc0, 32, 64);
        lacc1 += __shfl_xor(lacc1, 16, 64);
        lacc1 += __shfl_xor(lacc1, 32, 64);
        const float inv0 = 1.0f / lacc0;
        const float inv1 = 1.0f / lacc1;

        ushort* opa = o_h + ((long long)(b * S_ + sRow) * H_ + h0) * 512;
        ushort* opb = o_h + ((long long)(b * S_ + sRow) * H_ + h0 + 1) * 512;
#pragma unroll
        for (int c = 0; c < 32; ++c) {
            uint2 pva, pvb;
            pva.x = pack2bf(oa[c][0] * inv0, oa[c][1] * inv0);
            pva.y = pack2bf(oa[c][2] * inv0, oa[c][3] * inv0);
            pvb.x = pack2bf(ob[c][0] * inv1, ob[c][1] * inv1);
            pvb.y = pack2bf(ob[c][2] * inv1, ob[c][3] * inv1);
            *(uint2*)&opa[c * 16 + q4 * 4] = pva;
            *(uint2*)&opb[c * 16 + q4 * 4] = pvb;
        }
    }
}

// ---------------------------------------------------------------------------
extern "C" void kernel_launch(void* const* d_in, const int* in_sizes, int n_in,
                              void* d_out, int out_size, void* d_ws, size_t ws_size,
                              hipStream_t stream)
{
    const float* x         = (const float*)d_in[0];
    const float* freqs     = (const float*)d_in[1];
    // d_in[2] = mask (unused: causal handled analytically)
    const float* wq_w      = (const float*)d_in[3];
    const float* wq_b      = (const float*)d_in[4];
    const float* wkv_a_w   = (const float*)d_in[5];
    const float* wkv_a_b   = (const float*)d_in[6];
    const float* kv_norm_w = (const float*)d_in[7];
    const float* wkv_b_w   = (const float*)d_in[8];
    const float* wo_w      = (const float*)d_in[9];
    const float* wo_b      = (const float*)d_in[10];
    float* out = (float*)d_out;

    // ---- workspace layout (~197 MiB)
    char* w = (char*)d_ws;
    ushort* x_bf    = (ushort*)w;  w += 16777216;   // (4096,2048) bf16
    ushort* wq_bf   = (ushort*)w;  w += 12582912;   // (3072,2048) bf16
    ushort* wkva_bf = (ushort*)w;  w += 2621440;    // (640,2048)  bf16 padded
    ushort* wo_bf   = (ushort*)w;  w += 8388608;    // (2048,2048) bf16
    ushort* wkvbT   = (ushort*)w;  w += 2097152;    // (16,512,128) bf16
    ushort* wkvbV   = (ushort*)w;  w += 2097152;    // (16,128,512) bf16
    float*  kv_raw  = (float*)w;   w += 10485760;   // (4096,640) f32; dead after
    uint4*  kv_fk   = (uint4*)kv_raw;               //   kv_post -> frag images:
    uint4*  kv_fv   = (uint4*)((char*)kv_raw + 4718592); // 4.5 MB + 4 MB <= 10.49 MB
    ushort* kv_h    = (ushort*)w;  w += 4718592;    // (4096,576)  bf16
    uint*   kv_t    = (uint*)w;    w += 4194304;    // (2,512,1024) dwords
    char* RA = w;                  w += 67108864;
    float*  q_raw = (float*)RA;                     // (4096,3072) f32
    ushort* qn_bf = (ushort*)(RA + 50331648);       // (4096,2048) bf16
    ushort* o_h   = (ushort*)RA;                    // (4096,8192) bf16 (q dead)
    char* RB = w;                  w += 75497472;
    ushort* q_h  = (ushort*)RB;                     // (4096,9216) bf16
    ushort* outv = (ushort*)RB;                     // (4096,2048) bf16 (q_h dead)

    dim3 blk(256);

    // ---- bf16 conversions
    conv_bf16 <<<dim3(8192), blk, 0, stream>>>(x, x_bf);
    conv_bf16 <<<dim3(6144), blk, 0, stream>>>(wq_w, wq_bf);
    conv_wkva <<<dim3(1280), blk, 0, stream>>>(wkv_a_w, wkva_bf);
    conv_bf16 <<<dim3(4096), blk, 0, stream>>>(wo_w, wo_bf);
    conv_wkvb_t<<<dim3(16, 4, 16), blk, 0, stream>>>(wkv_b_w, wkvbT);
    conv_wkvbv <<<dim3(1024), blk, 0, stream>>>(wkv_b_w, wkvbV);

    // 1) q_raw = x @ wq_w^T + wq_b
    mgemm<false><<<dim3(24, 32, 1), blk, 0, stream>>>(
        x_bf, 2048, 0LL, wq_bf, 2048, 0LL, wq_b, 1.0f, q_raw, 3072, 0LL, 2048);

    // 2) kv_raw = x @ wkv_a_w^T (N=640 padded; bias folded into kv_post)
    mgemm<false><<<dim3(5, 32, 1), blk, 0, stream>>>(
        x_bf, 2048, 0LL, wkva_bf, 2048, 0LL, nullptr, 1.0f, kv_raw, 640, 0LL, 2048);

    // 3) RoPE(q_pe) -> q_h[...,512:576]; q_nope -> packed bf16
    rope_q_kernel<<<dim3(8192), blk, 0, stream>>>(q_raw, freqs, q_h);
    conv_qn<<<dim3(8192), blk, 0, stream>>>(q_raw, qn_bf);

    // 4) bias + rmsnorm + rope -> kv_h; transpose -> kv_t; frag images
    kv_post_kernel<<<dim3(4096), dim3(64), 0, stream>>>(
        kv_raw, wkv_a_b, kv_norm_w, freqs, kv_h);
    transpose_kv<<<dim3(32, 8, 2), blk, 0, stream>>>(kv_h, (ushort*)kv_t);
    prep_fk<<<dim3(9, 64, 2), blk, 0, stream>>>(kv_h, kv_fk);
    prep_fv<<<dim3(8, 64, 2), blk, 0, stream>>>(kv_t, kv_fv);

    // 5) q_h[...,0:512] = (q_nope @ wkv_b[h,:128,:]) * scale
    mgemm<true><<<dim3(4, 32, 16), blk, 0, stream>>>(
        qn_bf, 2048, 128LL, wkvbT, 128, 65536LL, nullptr, SCALE_,
        q_h, 9216, 576LL, 128);

    // 6) MFMA flash attention v8 -> o_h (2 heads/wave, dbuf overlap, paired strips)
    attn_kernel<<<dim3(64, 2, 2), blk, 0, stream>>>(q_h, kv_fk, kv_fv, o_h);

    // 7) outv = attn @ wkv_b[h,128:,:]^T
    mgemm<true><<<dim3(1, 32, 16), blk, 0, stream>>>(
        o_h, 8192, 512LL, wkvbV, 512, 65536LL, nullptr, 1.0f,
        outv, 2048, 128LL, 512);

    // 8) out = outv @ wo_w^T + wo_b
    mgemm<false><<<dim3(16, 32, 1), blk, 0, stream>>>(
        outv, 2048, 0LL, wo_bf, 2048, 0LL, wo_b, 1.0f, out, 2048, 0LL, 2048);
}

// Round 2
// 509.437 us; speedup vs baseline: 1.4851x; 1.3538x over previous
//
#include <hip/hip_runtime.h>
#include <hip/hip_bf16.h>
#include <math.h>

// MLA forward: B=2, S=2048, D=2048, H=16, KV_RANK=512, NOPE=128, ROPE=64
#define B_ 2
#define S_ 2048
#define H_ 16
#define SCALE_ 0.07216878364870323f   // 192^-0.5
#define EPS_ 1.1920929e-07f
#define M0_ 8.0f                      // constant exp shift (cancels in o/l)

typedef __attribute__((ext_vector_type(8))) short bf16x8;
typedef __attribute__((ext_vector_type(4))) float f32x4;
union U4 { uint4 u; bf16x8 v; f32x4 f; };

__device__ __forceinline__ uint bfbits(float x) {   // f32 -> bf16 bits, RNE
    uint u = __float_as_uint(x);
    return (u + 0x7fffu + ((u >> 16) & 1u)) >> 16;
}
__device__ __forceinline__ uint pack2bf(float a, float b) {
    return bfbits(a) | (bfbits(b) << 16);
}
__device__ __forceinline__ void gld_lds16(const ushort* g, ushort* l) {
    // async global->LDS DMA, 16B/lane; LDS dest = wave-uniform base + lane*16
    __builtin_amdgcn_global_load_lds(
        (const __attribute__((address_space(1))) uint*)g,
        (__attribute__((address_space(3))) uint*)l, 16, 0, 0);
}

// ---------------------------------------------------------------------------
// MFMA bf16 GEMM (NT): C[m,n] = scale * sum_k A[m,k]*B[n,k] + bias[n]
// 128x128 tile, BK=32, 256 thr (4 waves 2x2 of 64x64), 16x16x32 MFMA.
// ---------------------------------------------------------------------------
template<bool OUT_BF16>
__global__ __launch_bounds__(256) void mgemm(
    const ushort* __restrict__ A, int lda, long long aOff,
    const ushort* __restrict__ Bm, int ldb, long long bOff,
    const float* __restrict__ bias, float scale,
    void* __restrict__ Cv, int ldc, long long cOff, int K)
{
    __shared__ ushort As[128 * 32];
    __shared__ ushort Bs[128 * 32];

    const int z = blockIdx.z;
    A  += (long long)z * aOff;
    Bm += (long long)z * bOff;

    const int n0 = blockIdx.x * 128;
    const int m0 = blockIdx.y * 128;
    const int tid = threadIdx.x;
    const int w   = tid >> 6;
    const int l   = tid & 63;
    const int m   = l & 15;
    const int q4  = l >> 4;
    const int mw  = (w & 1) * 64;
    const int nw  = (w >> 1) * 64;
    const int sr  = l >> 2;
    const int sc  = l & 3;

    f32x4 acc[4][4];
#pragma unroll
    for (int i = 0; i < 4; ++i)
#pragma unroll
        for (int j = 0; j < 4; ++j) acc[i][j] = (f32x4){0.f, 0.f, 0.f, 0.f};

    for (int k0 = 0; k0 < K; k0 += 32) {
#pragma unroll
        for (int jj = 0; jj < 2; ++jj) {
            const int slot = w * 2 + jj;
            const int row  = slot * 16 + sr;
            const int g    = sc ^ ((row >> 1) & 3);
            gld_lds16(&A[(long long)(m0 + row) * lda + k0 + g * 8], &As[slot * 512]);
            gld_lds16(&Bm[(long long)(n0 + row) * ldb + k0 + g * 8], &Bs[slot * 512]);
        }
        __syncthreads();

        U4 af[4], bf[4];
#pragma unroll
        for (int i = 0; i < 4; ++i) {
            const int ra = mw + i * 16 + m;
            af[i].u = *(const uint4*)&As[ra * 32 + (q4 ^ ((ra >> 1) & 3)) * 8];
            const int rb = nw + i * 16 + m;
            bf[i].u = *(const uint4*)&Bs[rb * 32 + (q4 ^ ((rb >> 1) & 3)) * 8];
        }
#pragma unroll
        for (int i = 0; i < 4; ++i)
#pragma unroll
            for (int j = 0; j < 4; ++j)
                acc[i][j] = __builtin_amdgcn_mfma_f32_16x16x32_bf16(
                    af[i].v, bf[j].v, acc[i][j], 0, 0, 0);
        __syncthreads();
    }

#pragma unroll
    for (int j = 0; j < 4; ++j) {
        const int cn = n0 + nw + j * 16 + m;
        const float bv = bias ? bias[cn] : 0.0f;
#pragma unroll
        for (int i = 0; i < 4; ++i) {
            const int rw = m0 + mw + i * 16 + q4 * 4;
#pragma unroll
            for (int r = 0; r < 4; ++r) {
                const float val = acc[i][j][r] * scale + bv;
                if (OUT_BF16)
                    ((ushort*)Cv)[(long long)z * cOff + (long long)(rw + r) * ldc + cn] =
                        (ushort)bfbits(val);
                else
                    ((float*)Cv)[(long long)z * cOff + (long long)(rw + r) * ldc + cn] = val;
            }
        }
    }
}

// ---------------------------------------------------------------------------
// f32 -> bf16 converters
// ---------------------------------------------------------------------------
__global__ __launch_bounds__(256) void conv_bf16(
    const float* __restrict__ s, ushort* __restrict__ d)
{
    const long long i = ((long long)blockIdx.x * 256 + threadIdx.x) * 4;
    float4 v = *(const float4*)&s[i];
    uint2 p; p.x = pack2bf(v.x, v.y); p.y = pack2bf(v.z, v.w);
    *(uint2*)&d[i] = p;
}

__global__ __launch_bounds__(256) void conv_wkva(
    const float* __restrict__ s, ushort* __restrict__ d)
{
    const int i = (blockIdx.x * 256 + threadIdx.x) * 4;
    const int r = i >> 11;
    uint2 p = make_uint2(0u, 0u);
    if (r < 576) {
        float4 v = *(const float4*)&s[i];
        p.x = pack2bf(v.x, v.y); p.y = pack2bf(v.z, v.w);
    }
    *(uint2*)&d[i] = p;
}

// wkv_b half-slice (128 rows per head, starting at rowoff) -> bf16 (16,128,512)
__global__ __launch_bounds__(256) void conv_wkvb_half(
    const float* __restrict__ Wsrc, ushort* __restrict__ V, int rowoff)
{
    const int i = (blockIdx.x * 256 + threadIdx.x) * 4;
    const int h = i >> 16;
    const int rem = i & 65535;
    float4 v = *(const float4*)&Wsrc[((long long)(h * 256 + rowoff)) * 512 + rem];
    uint2 p; p.x = pack2bf(v.x, v.y); p.y = pack2bf(v.z, v.w);
    *(uint2*)&V[i] = p;
}

// q_nope f32 (interleaved 192-stride) -> q192[...,0:128] bf16, SCALE folded
__global__ __launch_bounds__(256) void conv_qn192(
    const float* __restrict__ q_raw, ushort* __restrict__ q192)
{
    const int i = (blockIdx.x * 256 + threadIdx.x) * 4;
    const int bs = i >> 11;
    const int c = i & 2047;
    const int hh = c >> 7, d = c & 127;
    float4 v = *(const float4*)&q_raw[(long long)bs * 3072 + hh * 192 + d];
    uint2 p;
    p.x = pack2bf(v.x * SCALE_, v.y * SCALE_);
    p.y = pack2bf(v.z * SCALE_, v.w * SCALE_);
    *(uint2*)&q192[((long long)bs * 16 + hh) * 192 + d] = p;
}

// ---------------------------------------------------------------------------
// RoPE on q_raw[...,128:192] -> q192[...,128:192] bf16, scale folded.
// ---------------------------------------------------------------------------
__global__ __launch_bounds__(256) void rope_q_kernel(
    const float* __restrict__ q_raw, const float* __restrict__ freqs,
    ushort* __restrict__ q192)
{
    const int idx = blockIdx.x * 256 + threadIdx.x;
    const int i = idx & 31;
    const int h = (idx >> 5) & 15;
    const int s = (idx >> 9) & 2047;
    const int b = idx >> 20;
    const float f = freqs[s * 32 + i];
    float cs, sn;
    __sincosf(f, &sn, &cs);
    const int row = (b * S_ + s) * H_ + h;
    const float a  = q_raw[(long long)(b * S_ + s) * 3072 + h * 192 + 128 + 2 * i];
    const float bb = q_raw[(long long)(b * S_ + s) * 3072 + h * 192 + 128 + 2 * i + 1];
    *(uint*)&q192[(long long)row * 192 + 128 + 2 * i] =
        pack2bf((a * cs - bb * sn) * SCALE_, (a * sn + bb * cs) * SCALE_);
}

// ---------------------------------------------------------------------------
// kv post: bias add + rmsnorm(kv[:512]) and rope(kv[512:576]) -> kv_h bf16.
// ---------------------------------------------------------------------------
__global__ __launch_bounds__(64) void kv_post_kernel(
    const float* __restrict__ kv_raw, const float* __restrict__ bias,
    const float* __restrict__ w, const float* __restrict__ freqs,
    ushort* __restrict__ kv_h)
{
    const int bs = blockIdx.x;
    const int lane = threadIdx.x;
    const float* src = kv_raw + (long long)bs * 640;
    ushort* dst = kv_h + (long long)bs * 576;

    const int c = 4 * lane;
    float4 v0 = *(const float4*)&src[c];
    float4 v1 = *(const float4*)&src[256 + c];
    float4 b0 = *(const float4*)&bias[c];
    float4 b1 = *(const float4*)&bias[256 + c];
    v0.x += b0.x; v0.y += b0.y; v0.z += b0.z; v0.w += b0.w;
    v1.x += b1.x; v1.y += b1.y; v1.z += b1.z; v1.w += b1.w;
    float ss = v0.x * v0.x + v0.y * v0.y + v0.z * v0.z + v0.w * v0.w +
               v1.x * v1.x + v1.y * v1.y + v1.z * v1.z + v1.w * v1.w;
#pragma unroll
    for (int o = 32; o; o >>= 1) ss += __shfl_xor(ss, o, 64);
    const float rs = rsqrtf(ss * (1.0f / 512.0f) + EPS_);

    float4 w0 = *(const float4*)&w[c];
    float4 w1 = *(const float4*)&w[256 + c];
    uint2 p0, p1;
    p0.x = pack2bf(v0.x * rs * w0.x, v0.y * rs * w0.y);
    p0.y = pack2bf(v0.z * rs * w0.z, v0.w * rs * w0.w);
    p1.x = pack2bf(v1.x * rs * w1.x, v1.y * rs * w1.y);
    p1.y = pack2bf(v1.z * rs * w1.z, v1.w * rs * w1.w);
    *(uint2*)&dst[c] = p0;
    *(uint2*)&dst[256 + c] = p1;

    if (lane < 32) {
        const int s = bs & 2047;
        const float f = freqs[s * 32 + lane];
        float cs, sn;
        __sincosf(f, &sn, &cs);
        const float a  = src[512 + 2 * lane]     + bias[512 + 2 * lane];
        const float b2 = src[512 + 2 * lane + 1] + bias[512 + 2 * lane + 1];
        *(uint*)&dst[512 + 2 * lane] = pack2bf(a * cs - b2 * sn, a * sn + b2 * cs);
    }
}

// ---------------------------------------------------------------------------
// Fragment images for attention staging (1-KB gld_lds chunks, lane*16B).
// khimg[b][tile][h][ck=f*2+s][lane=(q4,m)] = K_h[b][t0+s*16+m][h*128+f*32+q4*8..+7]
// ---------------------------------------------------------------------------
__global__ __launch_bounds__(256) void prep_kimg(
    const ushort* __restrict__ K_h, uint4* __restrict__ khimg)
{
    const int g = blockIdx.x * 256 + threadIdx.x;   // 0..1048575
    const int lane = g & 63, ck = (g >> 6) & 7, h = (g >> 9) & 15;
    const int tile = (g >> 13) & 63, b = g >> 19;
    const int m = lane & 15, q4 = lane >> 4, f = ck >> 1, s = ck & 1;
    const uint4 v = *(const uint4*)&K_h[
        ((long long)(b * S_ + tile * 32 + s * 16 + m)) * 2048 + h * 128 + f * 32 + q4 * 8];
    khimg[(((long long)(b * 64 + tile) * 16 + h) * 8 + ck) * 64 + lane] = v;
}

// vhimg[b][tile][h][c][lane=(q4,m)] = V_hT[b][h][c*16+m][t0+q4*8..+7]
__global__ __launch_bounds__(256) void prep_vimg(
    const ushort* __restrict__ V_hT, uint4* __restrict__ vhimg)
{
    const int g = blockIdx.x * 256 + threadIdx.x;   // 0..1048575
    const int lane = g & 63, c = (g >> 6) & 7, h = (g >> 9) & 15;
    const int tile = (g >> 13) & 63, b = g >> 19;
    const int m = lane & 15, q4 = lane >> 4;
    const uint4 v = *(const uint4*)&V_hT[
        ((long long)((b * 16 + h) * 128 + c * 16 + m)) * 2048 + tile * 32 + q4 * 8];
    vhimg[(((long long)(b * 64 + tile) * 16 + h) * 8 + c) * 64 + lane] = v;
}

// rimg[b][tile][ck=f2*2+s][lane] = k_pe octets (shared across heads)
__global__ __launch_bounds__(256) void prep_rimg(
    const ushort* __restrict__ kv_h, uint4* __restrict__ rimg)
{
    const int g = blockIdx.x * 256 + threadIdx.x;   // 0..32767
    const int lane = g & 63, ck = (g >> 6) & 3, tile = (g >> 8) & 63, b = g >> 14;
    const int m = lane & 15, q4 = lane >> 4, f2 = ck >> 1, s = ck & 1;
    const uint4 v = *(const uint4*)&kv_h[
        ((long long)(b * S_ + tile * 32 + s * 16 + m)) * 576 + 512 + f2 * 32 + q4 * 8];
    rimg[((long long)(b * 64 + tile) * 4 + ck) * 64 + lane] = v;
}

// ---------------------------------------------------------------------------
// MFMA flash attention v9: per-head K_h/V_h form (k=192, d=128).
// FLOPs 3.4x below latent form; per-wave regs ~130 -> 2 waves/SIMD.
// Block = 256 thr = 4 waves stacked over q (64 rows), ONE head per block.
// Tile = 32 t: LDS 20 KB (8 K + 4 rope + 8 V chunks), dbuf 40 KB -> 2 blk/CU.
// Chunk pairing (31-p then p): every block exactly 68 tiles, grid 512 = 2/CU.
// Staged bytes read by all 4 waves (reuse x4); 2 barriers/tile, stage overlap.
// ---------------------------------------------------------------------------
__global__ __launch_bounds__(256, 2) void attn_kernel(
    const ushort* __restrict__ q192,  // (B,S,H,192), q*scale
    const uint4*  __restrict__ khimg, // (B,64,16,8,64) K_h frag chunks
    const uint4*  __restrict__ rimg,  // (B,64,4,64)   k_pe frag chunks
    const uint4*  __restrict__ vhimg, // (B,64,16,8,64) V_h^T frag chunks
    ushort* __restrict__ o_h)         // (B,S,H,128)
{
    __shared__ uint buf[2][20 * 256];   // 2 x 20 KB

    const int p    = blockIdx.x;          // 0..15 (chunk pair)
    const int h    = blockIdx.y;          // 0..15
    const int b    = blockIdx.z;
    const int tid  = threadIdx.x;
    const int wid  = tid >> 6;            // 0..3 (q sub-strip)
    const int lane = tid & 63;
    const int m    = lane & 15;
    const int q4   = lane >> 4;

    auto stage = [&](int bs, int it) {
        const long long tb = (long long)(b * 64 + it);
        const uint4* kb = khimg + ((tb * 16 + h) * 8) * 64;
        const uint4* rb = rimg  + (tb * 4) * 64;
        const uint4* vb = vhimg + ((tb * 16 + h) * 8) * 64;
        ushort* l = (ushort*)&buf[bs][0];
        gld_lds16((const ushort*)(kb + (wid    ) * 64 + lane), l + (wid     ) * 512);
        gld_lds16((const ushort*)(kb + (wid + 4) * 64 + lane), l + (wid +  4) * 512);
        gld_lds16((const ushort*)(rb + (wid    ) * 64 + lane), l + (wid +  8) * 512);
        gld_lds16((const ushort*)(vb + (wid    ) * 64 + lane), l + (wid + 12) * 512);
        gld_lds16((const ushort*)(vb + (wid + 4) * 64 + lane), l + (wid + 16) * 512);
    };

    int cur = 0;
    for (int pass = 0; pass < 2; ++pass) {
        const int chunk = pass ? p : (31 - p);   // heavy chunk first
        const int row0  = chunk * 64 + wid * 16;
        const int sRow  = row0 + m;

        // Q B-frags (k=192): qf[f] = Q[sRow][f*32 + q4*8 + j]
        U4 qf[6];
        {
            const uint4* qp = (const uint4*)(q192 + ((long long)(b * S_ + sRow) * H_ + h) * 192);
#pragma unroll
            for (int f = 0; f < 6; ++f) qf[f].u = qp[f * 4 + q4];
        }

        f32x4 o[8];
#pragma unroll
        for (int c = 0; c < 8; ++c) o[c] = (f32x4){0.f, 0.f, 0.f, 0.f};
        float lacc = 0.0f;

        const int nT = chunk * 2 + 2;
        __syncthreads();                 // all reads of prev pass's LDS complete
        stage(cur, 0);

        for (int it = 0; it < nT; ++it) {
            const int t0 = it * 32;
            __syncthreads();             // drains vmcnt(0): buf[cur] staged
            if (it + 1 < nT) stage(cur ^ 1, it + 1);   // overlap under compute
            __builtin_amdgcn_sched_barrier(0);

            if (t0 <= row0 + 15) {       // wave has live rows in this tile
                const uint* bb0 = &buf[cur][0];
                const int abase = lane * 4;

                // ---- S^T = K . Q^T (k = 192: 4 nope frags + 2 rope frags)
                f32x4 st0 = (f32x4){0.f, 0.f, 0.f, 0.f};
                f32x4 st1 = (f32x4){0.f, 0.f, 0.f, 0.f};
                const bool skip1 = (t0 >= row0);
                if (!skip1) {
#pragma unroll
                    for (int f = 0; f < 6; ++f) {
                        const int ck = (f < 4) ? f * 2 : (f - 4) * 2 + 8;
                        U4 a0, a1;
                        a0.u = *(const uint4*)&bb0[ck * 256 + abase];
                        a1.u = *(const uint4*)&bb0[(ck + 1) * 256 + abase];
                        st0 = __builtin_amdgcn_mfma_f32_16x16x32_bf16(a0.v, qf[f].v, st0, 0, 0, 0);
                        st1 = __builtin_amdgcn_mfma_f32_16x16x32_bf16(a1.v, qf[f].v, st1, 0, 0, 0);
                    }
                } else {
#pragma unroll
                    for (int f = 0; f < 6; ++f) {
                        const int ck = (f < 4) ? f * 2 : (f - 4) * 2 + 8;
                        U4 a0;
                        a0.u = *(const uint4*)&bb0[ck * 256 + abase];
                        st0 = __builtin_amdgcn_mfma_f32_16x16x32_bf16(a0.v, qf[f].v, st0, 0, 0, 0);
                    }
                }

                // ---- mask + exp(s - M0), accumulate l
                const int tb0 = t0 + q4 * 4;
                const int tb1 = t0 + 16 + q4 * 4;
                float p00 = (tb0 + 0 <= sRow) ? __expf(st0[0] - M0_) : 0.0f;
                float p01 = (tb0 + 1 <= sRow) ? __expf(st0[1] - M0_) : 0.0f;
                float p02 = (tb0 + 2 <= sRow) ? __expf(st0[2] - M0_) : 0.0f;
                float p03 = (tb0 + 3 <= sRow) ? __expf(st0[3] - M0_) : 0.0f;
                float p10 = (tb1 + 0 <= sRow) ? __expf(st1[0] - M0_) : 0.0f;
                float p11 = (tb1 + 1 <= sRow) ? __expf(st1[1] - M0_) : 0.0f;
                float p12 = (tb1 + 2 <= sRow) ? __expf(st1[2] - M0_) : 0.0f;
                float p13 = (tb1 + 3 <= sRow) ? __expf(st1[3] - M0_) : 0.0f;
                lacc += (p00 + p01) + (p02 + p03) + (p10 + p11) + (p12 + p13);

                // ---- P^T -> PV B-fragment via 8 shuffles
                U4 bb;
                {
                    uint pk00 = pack2bf(p00, p01);
                    uint pk01 = pack2bf(p02, p03);
                    uint pk10 = pack2bf(p10, p11);
                    uint pk11 = pack2bf(p12, p13);
                    const int srcA = ((lane >> 4) & 1) * 32 + m;
                    const int srcB = srcA + 16;
                    uint a00 = (uint)__shfl((int)pk00, srcA, 64);
                    uint a01 = (uint)__shfl((int)pk01, srcA, 64);
                    uint a10 = (uint)__shfl((int)pk10, srcA, 64);
                    uint a11 = (uint)__shfl((int)pk11, srcA, 64);
                    uint b00 = (uint)__shfl((int)pk00, srcB, 64);
                    uint b01 = (uint)__shfl((int)pk01, srcB, 64);
                    uint b10 = (uint)__shfl((int)pk10, srcB, 64);
                    uint b11 = (uint)__shfl((int)pk11, srcB, 64);
                    const bool hi2 = (lane >> 5) & 1;
                    bb.u.x = hi2 ? a10 : a00;
                    bb.u.y = hi2 ? a11 : a01;
                    bb.u.z = hi2 ? b10 : b00;
                    bb.u.w = hi2 ? b11 : b01;
                }

                // ---- PV over d=128: O^T += V^T . P^T
#pragma unroll
                for (int c = 0; c < 8; ++c) {
                    U4 av; av.u = *(const uint4*)&bb0[(12 + c) * 256 + abase];
                    o[c] = __builtin_amdgcn_mfma_f32_16x16x32_bf16(av.v, bb.v, o[c], 0, 0, 0);
                }
            }
            cur ^= 1;
        }

        // ---- epilogue: reduce l across q4 groups; normalize; store
        lacc += __shfl_xor(lacc, 16, 64);
        lacc += __shfl_xor(lacc, 32, 64);
        const float inv = 1.0f / lacc;

        ushort* op = o_h + ((long long)(b * S_ + sRow) * H_ + h) * 128;
#pragma unroll
        for (int c = 0; c < 8; ++c) {
            uint2 pv;
            pv.x = pack2bf(o[c][0] * inv, o[c][1] * inv);
            pv.y = pack2bf(o[c][2] * inv, o[c][3] * inv);
            *(uint2*)&op[c * 16 + q4 * 4] = pv;
        }
    }
}

// ---------------------------------------------------------------------------
extern "C" void kernel_launch(void* const* d_in, const int* in_sizes, int n_in,
                              void* d_out, int out_size, void* d_ws, size_t ws_size,
                              hipStream_t stream)
{
    const float* x         = (const float*)d_in[0];
    const float* freqs     = (const float*)d_in[1];
    // d_in[2] = mask (unused: causal handled analytically)
    const float* wq_w      = (const float*)d_in[3];
    const float* wq_b      = (const float*)d_in[4];
    const float* wkv_a_w   = (const float*)d_in[5];
    const float* wkv_a_b   = (const float*)d_in[6];
    const float* kv_norm_w = (const float*)d_in[7];
    const float* wkv_b_w   = (const float*)d_in[8];
    const float* wo_w      = (const float*)d_in[9];
    const float* wo_b      = (const float*)d_in[10];
    float* out = (float*)d_out;

    // ---- workspace layout (~194 MiB)
    char* w = (char*)d_ws;
    ushort* x_bf    = (ushort*)w;  w += 16777216;   // (4096,2048) bf16
    ushort* wq_bf   = (ushort*)w;  w += 12582912;   // (3072,2048) bf16
    ushort* wkva_bf = (ushort*)w;  w += 2621440;    // (640,2048)  bf16 padded
    ushort* wo_bf   = (ushort*)w;  w += 8388608;    // (2048,2048) bf16
    ushort* wkvbK   = (ushort*)w;  w += 2097152;    // (16,128,512) bf16 (K rows)
    ushort* wkvbV   = (ushort*)w;  w += 2097152;    // (16,128,512) bf16 (V rows)
    float*  kv_raw  = (float*)w;   w += 10485760;   // (4096,640) f32
    ushort* kv_h    = (ushort*)w;  w += 4718592;    // (4096,576)  bf16
    ushort* K_h     = (ushort*)w;  w += 16777216;   // (B,2048,16,128) bf16
    ushort* V_hT    = (ushort*)w;  w += 16777216;   // (B,16,128,2048) bf16
    uint4*  khimg   = (uint4*)w;   w += 16777216;   // (B,64,16,8,64)
    uint4*  vhimg   = (uint4*)w;   w += 16777216;   // (B,64,16,8,64)
    uint4*  rimg    = (uint4*)w;   w += 524288;     // (B,64,4,64)
    char* RA = w;                  w += 50331648;
    float*  q_raw = (float*)RA;                     // (4096,3072) f32
    ushort* o_h   = (ushort*)RA;                    // (4096,16,128) bf16 (q dead)
    ushort* q192  = (ushort*)w;    w += 25165824;   // (4096,16,192) bf16

    dim3 blk(256);

    // ---- bf16 conversions
    conv_bf16 <<<dim3(8192), blk, 0, stream>>>(x, x_bf);
    conv_bf16 <<<dim3(6144), blk, 0, stream>>>(wq_w, wq_bf);
    conv_wkva <<<dim3(1280), blk, 0, stream>>>(wkv_a_w, wkva_bf);
    conv_bf16 <<<dim3(4096), blk, 0, stream>>>(wo_w, wo_bf);
    conv_wkvb_half<<<dim3(1024), blk, 0, stream>>>(wkv_b_w, wkvbK, 0);
    conv_wkvb_half<<<dim3(1024), blk, 0, stream>>>(wkv_b_w, wkvbV, 128);

    // 1) q_raw = x @ wq_w^T + wq_b
    mgemm<false><<<dim3(24, 32, 1), blk, 0, stream>>>(
        x_bf, 2048, 0LL, wq_bf, 2048, 0LL, wq_b, 1.0f, q_raw, 3072, 0LL, 2048);

    // 2) kv_raw = x @ wkv_a_w^T (N=640 padded; bias folded into kv_post)
    mgemm<false><<<dim3(5, 32, 1), blk, 0, stream>>>(
        x_bf, 2048, 0LL, wkva_bf, 2048, 0LL, nullptr, 1.0f, kv_raw, 640, 0LL, 2048);

    // 3) q192 = [q_nope*scale, rope(q_pe)*scale] bf16
    rope_q_kernel<<<dim3(8192), blk, 0, stream>>>(q_raw, freqs, q192);
    conv_qn192<<<dim3(8192), blk, 0, stream>>>(q_raw, q192);

    // 4) bias + rmsnorm + rope -> kv_h
    kv_post_kernel<<<dim3(4096), dim3(64), 0, stream>>>(
        kv_raw, wkv_a_b, kv_norm_w, freqs, kv_h);

    // 5) per-head K/V projections (hoisted out of the S^2 loop):
    //    K_h[b,t,h,:] = kv_proj @ wkv_b[h,:128]^T   (M=2048,N=128,K=512, z=h)
    //    V_hT[b,h,d,t] = wkv_b[h,128:] @ kv_proj^T  (M=128,N=2048,K=512, z=h)
    for (int b = 0; b < 2; ++b) {
        mgemm<true><<<dim3(1, 16, 16), blk, 0, stream>>>(
            kv_h + (long long)b * S_ * 576, 576, 0LL,
            wkvbK, 512, 65536LL, nullptr, 1.0f,
            K_h + (long long)b * S_ * 2048, 2048, 128LL, 512);
        mgemm<true><<<dim3(16, 1, 16), blk, 0, stream>>>(
            wkvbV, 512, 65536LL,
            kv_h + (long long)b * S_ * 576, 576, 0LL, nullptr, 1.0f,
            V_hT + (long long)b * 16 * 128 * 2048, 2048, 262144LL, 512);
    }

    // 6) fragment images for coalesced attention staging
    prep_kimg<<<dim3(4096), blk, 0, stream>>>(K_h, khimg);
    prep_vimg<<<dim3(4096), blk, 0, stream>>>(V_hT, vhimg);
    prep_rimg<<<dim3(128),  blk, 0, stream>>>(kv_h, rimg);

    // 7) MFMA flash attention v9 -> o_h (B,S,H,128) == (4096, 2048) rows
    attn_kernel<<<dim3(16, 16, 2), blk, 0, stream>>>(q192, khimg, rimg, vhimg, o_h);

    // 8) out = o_h @ wo_w^T + wo_b
    mgemm<false><<<dim3(16, 32, 1), blk, 0, stream>>>(
        o_h, 2048, 0LL, wo_bf, 2048, 0LL, wo_b, 1.0f, out, 2048, 0LL, 2048);
}

// Round 3
// 491.123 us; speedup vs baseline: 1.5405x; 1.0373x over previous
//
#include <hip/hip_runtime.h>
#include <hip/hip_bf16.h>
#include <math.h>

// MLA forward: B=2, S=2048, D=2048, H=16, KV_RANK=512, NOPE=128, ROPE=64
#define B_ 2
#define S_ 2048
#define H_ 16
#define SCALE_ 0.07216878364870323f   // 192^-0.5
#define SL2_ (0.07216878364870323f * 1.4426950408889634f)  // scale * log2(e)
#define EPS_ 1.1920929e-07f
#define M0_ 8.0f                      // constant exp2 shift (cancels in o/l)

typedef __attribute__((ext_vector_type(8))) short bf16x8;
typedef __attribute__((ext_vector_type(4))) float f32x4;
union U4 { uint4 u; bf16x8 v; f32x4 f; };

__device__ __forceinline__ uint bfbits(float x) {   // f32 -> bf16 bits, RNE
    uint u = __float_as_uint(x);
    return (u + 0x7fffu + ((u >> 16) & 1u)) >> 16;
}
__device__ __forceinline__ uint pack2bf(float a, float b) {
    return bfbits(a) | (bfbits(b) << 16);
}
__device__ __forceinline__ uint cvtpk(float a, float b) {  // 1 VALU op, RNE
    uint r;
    asm("v_cvt_pk_bf16_f32 %0, %1, %2" : "=v"(r) : "v"(a), "v"(b));
    return r;
}
__device__ __forceinline__ void gld_lds16(const ushort* g, ushort* l) {
    // async global->LDS DMA, 16B/lane; LDS dest = wave-uniform base + lane*16
    __builtin_amdgcn_global_load_lds(
        (const __attribute__((address_space(1))) uint*)g,
        (__attribute__((address_space(3))) uint*)l, 16, 0, 0);
}

// ---------------------------------------------------------------------------
// MFMA bf16 GEMM (NT): C[m,n] = scale * sum_k A[m,k]*B[n,k] + bias[n]
// 128x128 tile, BK=32, 256 thr (4 waves 2x2 of 64x64), 16x16x32 MFMA.
// z decomposed as z1 = z % zDiv (stride *Off1), z2 = z / zDiv (stride *Off2).
// ---------------------------------------------------------------------------
template<bool OUT_BF16>
__global__ __launch_bounds__(256) void mgemm(
    const ushort* __restrict__ A, int lda, long long aOff1, long long aOff2,
    const ushort* __restrict__ Bm, int ldb, long long bOff1, long long bOff2,
    const float* __restrict__ bias, float scale,
    void* __restrict__ Cv, int ldc, long long cOff1, long long cOff2,
    int K, int zDiv)
{
    __shared__ ushort As[128 * 32];
    __shared__ ushort Bs[128 * 32];

    const int z = blockIdx.z;
    const int z1 = z % zDiv, z2 = z / zDiv;
    A  += z1 * aOff1 + z2 * aOff2;
    Bm += z1 * bOff1 + z2 * bOff2;
    const long long cBase = z1 * cOff1 + z2 * cOff2;

    const int n0 = blockIdx.x * 128;
    const int m0 = blockIdx.y * 128;
    const int tid = threadIdx.x;
    const int w   = tid >> 6;
    const int l   = tid & 63;
    const int m   = l & 15;
    const int q4  = l >> 4;
    const int mw  = (w & 1) * 64;
    const int nw  = (w >> 1) * 64;
    const int sr  = l >> 2;
    const int sc  = l & 3;

    f32x4 acc[4][4];
#pragma unroll
    for (int i = 0; i < 4; ++i)
#pragma unroll
        for (int j = 0; j < 4; ++j) acc[i][j] = (f32x4){0.f, 0.f, 0.f, 0.f};

    for (int k0 = 0; k0 < K; k0 += 32) {
#pragma unroll
        for (int jj = 0; jj < 2; ++jj) {
            const int slot = w * 2 + jj;
            const int row  = slot * 16 + sr;
            const int g    = sc ^ ((row >> 1) & 3);
            gld_lds16(&A[(long long)(m0 + row) * lda + k0 + g * 8], &As[slot * 512]);
            gld_lds16(&Bm[(long long)(n0 + row) * ldb + k0 + g * 8], &Bs[slot * 512]);
        }
        __syncthreads();

        U4 af[4], bf[4];
#pragma unroll
        for (int i = 0; i < 4; ++i) {
            const int ra = mw + i * 16 + m;
            af[i].u = *(const uint4*)&As[ra * 32 + (q4 ^ ((ra >> 1) & 3)) * 8];
            const int rb = nw + i * 16 + m;
            bf[i].u = *(const uint4*)&Bs[rb * 32 + (q4 ^ ((rb >> 1) & 3)) * 8];
        }
#pragma unroll
        for (int i = 0; i < 4; ++i)
#pragma unroll
            for (int j = 0; j < 4; ++j)
                acc[i][j] = __builtin_amdgcn_mfma_f32_16x16x32_bf16(
                    af[i].v, bf[j].v, acc[i][j], 0, 0, 0);
        __syncthreads();
    }

#pragma unroll
    for (int j = 0; j < 4; ++j) {
        const int cn = n0 + nw + j * 16 + m;
        const float bv = bias ? bias[cn] : 0.0f;
#pragma unroll
        for (int i = 0; i < 4; ++i) {
            const int rw = m0 + mw + i * 16 + q4 * 4;
#pragma unroll
            for (int r = 0; r < 4; ++r) {
                const float val = acc[i][j][r] * scale + bv;
                if (OUT_BF16)
                    ((ushort*)Cv)[cBase + (long long)(rw + r) * ldc + cn] =
                        (ushort)bfbits(val);
                else
                    ((float*)Cv)[cBase + (long long)(rw + r) * ldc + cn] = val;
            }
        }
    }
}

// ---------------------------------------------------------------------------
// Fused f32 -> bf16 conversions (6 former kernels, one launch).
// ---------------------------------------------------------------------------
__global__ __launch_bounds__(256) void conv_all(
    const float* __restrict__ x, const float* __restrict__ wq,
    const float* __restrict__ wkva, const float* __restrict__ wo,
    const float* __restrict__ wkvb,
    ushort* __restrict__ x_bf, ushort* __restrict__ wq_bf,
    ushort* __restrict__ wkva_bf, ushort* __restrict__ wo_bf,
    ushort* __restrict__ wkvbK, ushort* __restrict__ wkvbV)
{
    const int bid = blockIdx.x;
    const int tid = threadIdx.x;
    if (bid < 8192) {                       // x: (4096,2048)
        const long long i = ((long long)bid * 256 + tid) * 4;
        float4 v = *(const float4*)&x[i];
        uint2 p; p.x = pack2bf(v.x, v.y); p.y = pack2bf(v.z, v.w);
        *(uint2*)&x_bf[i] = p;
    } else if (bid < 14336) {               // wq: (3072,2048)
        const long long i = ((long long)(bid - 8192) * 256 + tid) * 4;
        float4 v = *(const float4*)&wq[i];
        uint2 p; p.x = pack2bf(v.x, v.y); p.y = pack2bf(v.z, v.w);
        *(uint2*)&wq_bf[i] = p;
    } else if (bid < 15616) {               // wkva: (576,2048) pad to 640
        const int i = ((bid - 14336) * 256 + tid) * 4;
        const int r = i >> 11;
        uint2 p = make_uint2(0u, 0u);
        if (r < 576) {
            float4 v = *(const float4*)&wkva[i];
            p.x = pack2bf(v.x, v.y); p.y = pack2bf(v.z, v.w);
        }
        *(uint2*)&wkva_bf[i] = p;
    } else if (bid < 19712) {               // wo: (2048,2048)
        const long long i = ((long long)(bid - 15616) * 256 + tid) * 4;
        float4 v = *(const float4*)&wo[i];
        uint2 p; p.x = pack2bf(v.x, v.y); p.y = pack2bf(v.z, v.w);
        *(uint2*)&wo_bf[i] = p;
    } else if (bid < 20736) {               // wkv_b rows [0:128) per head -> K
        const int i = ((bid - 19712) * 256 + tid) * 4;
        const int h = i >> 16, rem = i & 65535;
        float4 v = *(const float4*)&wkvb[((long long)(h * 256)) * 512 + rem];
        uint2 p; p.x = pack2bf(v.x, v.y); p.y = pack2bf(v.z, v.w);
        *(uint2*)&wkvbK[i] = p;
    } else {                                // wkv_b rows [128:256) per head -> V
        const int i = ((bid - 20736) * 256 + tid) * 4;
        const int h = i >> 16, rem = i & 65535;
        float4 v = *(const float4*)&wkvb[((long long)(h * 256 + 128)) * 512 + rem];
        uint2 p; p.x = pack2bf(v.x, v.y); p.y = pack2bf(v.z, v.w);
        *(uint2*)&wkvbV[i] = p;
    }
}

// ---------------------------------------------------------------------------
// Fused q prep: q192 = [q_nope * SL2, rope(q_pe) * SL2] bf16 (one read pass).
// ---------------------------------------------------------------------------
__global__ __launch_bounds__(256) void qprep(
    const float* __restrict__ q_raw, const float* __restrict__ freqs,
    ushort* __restrict__ q192)
{
    const int idx = blockIdx.x * 256 + threadIdx.x;   // 0..3145727
    const int row = idx / 48;        // (b*S+s)*16+h
    const int c4  = idx % 48;
    const int bs = row >> 4, h = row & 15;
    const float* src = q_raw + (long long)bs * 3072 + h * 192;
    if (c4 < 32) {
        const int d = c4 * 4;
        float4 v = *(const float4*)&src[d];
        uint2 p;
        p.x = pack2bf(v.x * SL2_, v.y * SL2_);
        p.y = pack2bf(v.z * SL2_, v.w * SL2_);
        *(uint2*)&q192[(long long)row * 192 + d] = p;
    } else {
        const int j = c4 - 32;       // 0..15, two rope pairs
        const int s = bs & 2047;
        const float f0 = freqs[s * 32 + j * 2];
        const float f1 = freqs[s * 32 + j * 2 + 1];
        float c0, s0, c1, s1;
        __sincosf(f0, &s0, &c0);
        __sincosf(f1, &s1, &c1);
        float4 v = *(const float4*)&src[128 + j * 4];
        uint2 p;
        p.x = pack2bf((v.x * c0 - v.y * s0) * SL2_, (v.x * s0 + v.y * c0) * SL2_);
        p.y = pack2bf((v.z * c1 - v.w * s1) * SL2_, (v.z * s1 + v.w * c1) * SL2_);
        *(uint2*)&q192[(long long)row * 192 + 128 + j * 4] = p;
    }
}

// ---------------------------------------------------------------------------
// kv post: bias add + rmsnorm(kv[:512]) and rope(kv[512:576]) -> kv_h bf16.
// ---------------------------------------------------------------------------
__global__ __launch_bounds__(64) void kv_post_kernel(
    const float* __restrict__ kv_raw, const float* __restrict__ bias,
    const float* __restrict__ w, const float* __restrict__ freqs,
    ushort* __restrict__ kv_h)
{
    const int bs = blockIdx.x;
    const int lane = threadIdx.x;
    const float* src = kv_raw + (long long)bs * 640;
    ushort* dst = kv_h + (long long)bs * 576;

    const int c = 4 * lane;
    float4 v0 = *(const float4*)&src[c];
    float4 v1 = *(const float4*)&src[256 + c];
    float4 b0 = *(const float4*)&bias[c];
    float4 b1 = *(const float4*)&bias[256 + c];
    v0.x += b0.x; v0.y += b0.y; v0.z += b0.z; v0.w += b0.w;
    v1.x += b1.x; v1.y += b1.y; v1.z += b1.z; v1.w += b1.w;
    float ss = v0.x * v0.x + v0.y * v0.y + v0.z * v0.z + v0.w * v0.w +
               v1.x * v1.x + v1.y * v1.y + v1.z * v1.z + v1.w * v1.w;
#pragma unroll
    for (int o = 32; o; o >>= 1) ss += __shfl_xor(ss, o, 64);
    const float rs = rsqrtf(ss * (1.0f / 512.0f) + EPS_);

    float4 w0 = *(const float4*)&w[c];
    float4 w1 = *(const float4*)&w[256 + c];
    uint2 p0, p1;
    p0.x = pack2bf(v0.x * rs * w0.x, v0.y * rs * w0.y);
    p0.y = pack2bf(v0.z * rs * w0.z, v0.w * rs * w0.w);
    p1.x = pack2bf(v1.x * rs * w1.x, v1.y * rs * w1.y);
    p1.y = pack2bf(v1.z * rs * w1.z, v1.w * rs * w1.w);
    *(uint2*)&dst[c] = p0;
    *(uint2*)&dst[256 + c] = p1;

    if (lane < 32) {
        const int s = bs & 2047;
        const float f = freqs[s * 32 + lane];
        float cs, sn;
        __sincosf(f, &sn, &cs);
        const float a  = src[512 + 2 * lane]     + bias[512 + 2 * lane];
        const float b2 = src[512 + 2 * lane + 1] + bias[512 + 2 * lane + 1];
        *(uint*)&dst[512 + 2 * lane] = pack2bf(a * cs - b2 * sn, a * sn + b2 * cs);
    }
}

// ---------------------------------------------------------------------------
// Fused fragment-image prep (K, V, rope images in one launch).
// khimg[b][tile][h][ck=f*2+s][lane=(q4,m)] = K_h[b][t0+s*16+m][h*128+f*32+q4*8..]
// vhimg[b][tile][h][c][lane=(q4,m)]        = V_hT[b][h][c*16+m][t0+q4*8..]
// rimg [b][tile][ck=f2*2+s][lane]          = k_pe octets (shared across heads)
// ---------------------------------------------------------------------------
__global__ __launch_bounds__(256) void prep_all(
    const ushort* __restrict__ K_h, const ushort* __restrict__ V_hT,
    const ushort* __restrict__ kv_h,
    uint4* __restrict__ khimg, uint4* __restrict__ vhimg,
    uint4* __restrict__ rimg)
{
    const int bid = blockIdx.x;
    if (bid < 4096) {
        const int g = bid * 256 + threadIdx.x;
        const int lane = g & 63, ck = (g >> 6) & 7, h = (g >> 9) & 15;
        const int tile = (g >> 13) & 63, b = g >> 19;
        const int m = lane & 15, q4 = lane >> 4, f = ck >> 1, s = ck & 1;
        const uint4 v = *(const uint4*)&K_h[
            ((long long)(b * S_ + tile * 32 + s * 16 + m)) * 2048 + h * 128 + f * 32 + q4 * 8];
        khimg[(((long long)(b * 64 + tile) * 16 + h) * 8 + ck) * 64 + lane] = v;
    } else if (bid < 8192) {
        const int g = (bid - 4096) * 256 + threadIdx.x;
        const int lane = g & 63, c = (g >> 6) & 7, h = (g >> 9) & 15;
        const int tile = (g >> 13) & 63, b = g >> 19;
        const int m = lane & 15, q4 = lane >> 4;
        const uint4 v = *(const uint4*)&V_hT[
            ((long long)((b * 16 + h) * 128 + c * 16 + m)) * 2048 + tile * 32 + q4 * 8];
        vhimg[(((long long)(b * 64 + tile) * 16 + h) * 8 + c) * 64 + lane] = v;
    } else {
        const int g = (bid - 8192) * 256 + threadIdx.x;
        const int lane = g & 63, ck = (g >> 6) & 3, tile = (g >> 8) & 63, b = g >> 14;
        const int m = lane & 15, q4 = lane >> 4, f2 = ck >> 1, s = ck & 1;
        const uint4 v = *(const uint4*)&kv_h[
            ((long long)(b * S_ + tile * 32 + s * 16 + m)) * 576 + 512 + f2 * 32 + q4 * 8];
        rimg[((long long)(b * 64 + tile) * 4 + ck) * 64 + lane] = v;
    }
}

// ---------------------------------------------------------------------------
// MFMA flash attention v10: per-head (k=192, d=128), 2 q-substrips per wave.
// Every K/V A-frag ds_read feeds 2 MFMAs (halves LDS-read per FLOP vs v9).
// Block = 256 thr = 4 waves, ONE head, 128 q-rows (wave w: rows w*16 and
// w*16+64). Softmax: exp2 with log2e folded into q scale; causal compares
// only on diagonal tiles; v_cvt_pk_bf16_f32 packing. LDS 40 KB dbuf.
// Grid 512 = 16 chunks x 16 h x 2 b, big chunks dispatched first.
// ---------------------------------------------------------------------------
__global__ __launch_bounds__(256, 2) void attn_kernel(
    const ushort* __restrict__ q192,  // (B,S,H,192), q*scale*log2e
    const uint4*  __restrict__ khimg, // (B,64,16,8,64) K_h frag chunks
    const uint4*  __restrict__ rimg,  // (B,64,4,64)   k_pe frag chunks
    const uint4*  __restrict__ vhimg, // (B,64,16,8,64) V_h^T frag chunks
    ushort* __restrict__ o_h)         // (B,S,H,128)
{
    __shared__ uint buf[2][20 * 256];   // 2 x 20 KB

    const int hb   = blockIdx.x;          // 0..31
    const int h    = hb & 15;
    const int b    = hb >> 4;
    const int chunk = 15 - (int)blockIdx.y;   // 15..0: big chunks first
    const int tid  = threadIdx.x;
    const int wid  = tid >> 6;            // 0..3
    const int lane = tid & 63;
    const int m    = lane & 15;
    const int q4   = lane >> 4;

    const int row0a = chunk * 128 + wid * 16;
    const int row0b = row0a + 64;
    const int sRa   = row0a + m;
    const int sRb   = row0b + m;

    auto stage = [&](int bs, int it) {
        const long long tb = (long long)(b * 64 + it);
        const uint4* kb = khimg + ((tb * 16 + h) * 8) * 64;
        const uint4* rb = rimg  + (tb * 4) * 64;
        const uint4* vb = vhimg + ((tb * 16 + h) * 8) * 64;
        ushort* l = (ushort*)&buf[bs][0];
        gld_lds16((const ushort*)(kb + (wid    ) * 64 + lane), l + (wid     ) * 512);
        gld_lds16((const ushort*)(kb + (wid + 4) * 64 + lane), l + (wid +  4) * 512);
        gld_lds16((const ushort*)(rb + (wid    ) * 64 + lane), l + (wid +  8) * 512);
        gld_lds16((const ushort*)(vb + (wid    ) * 64 + lane), l + (wid + 12) * 512);
        gld_lds16((const ushort*)(vb + (wid + 4) * 64 + lane), l + (wid + 16) * 512);
    };

    // Q B-frags for both substrips: qf[f] = Q[sR][f*32 + q4*8 + j]
    U4 qfa[6], qfb[6];
    {
        const uint4* qpa = (const uint4*)(q192 + ((long long)(b * S_ + sRa) * H_ + h) * 192);
        const uint4* qpb = (const uint4*)(q192 + ((long long)(b * S_ + sRb) * H_ + h) * 192);
#pragma unroll
        for (int f = 0; f < 6; ++f) { qfa[f].u = qpa[f * 4 + q4]; qfb[f].u = qpb[f * 4 + q4]; }
    }

    f32x4 oA[8], oB[8];
#pragma unroll
    for (int c = 0; c < 8; ++c) {
        oA[c] = (f32x4){0.f, 0.f, 0.f, 0.f};
        oB[c] = (f32x4){0.f, 0.f, 0.f, 0.f};
    }
    float lA = 0.0f, lB = 0.0f;

    // softmax (exp2, diagonal-only masking) + P^T repack -> PV B-frag
    auto softpack = [&](const f32x4 s0, const f32x4 s1, int t0v, int rw0,
                        float& lac) -> U4 {
        float p00, p01, p02, p03, p10, p11, p12, p13;
        if (t0v + 31 <= rw0) {            // fully unmasked tile
            p00 = exp2f(s0[0] - M0_); p01 = exp2f(s0[1] - M0_);
            p02 = exp2f(s0[2] - M0_); p03 = exp2f(s0[3] - M0_);
            p10 = exp2f(s1[0] - M0_); p11 = exp2f(s1[1] - M0_);
            p12 = exp2f(s1[2] - M0_); p13 = exp2f(s1[3] - M0_);
        } else {                          // diagonal tile
            const int sR = rw0 + m;
            const int tb0 = t0v + q4 * 4;
            const int tb1 = tb0 + 16;
            p00 = (tb0 + 0 <= sR) ? exp2f(s0[0] - M0_) : 0.0f;
            p01 = (tb0 + 1 <= sR) ? exp2f(s0[1] - M0_) : 0.0f;
            p02 = (tb0 + 2 <= sR) ? exp2f(s0[2] - M0_) : 0.0f;
            p03 = (tb0 + 3 <= sR) ? exp2f(s0[3] - M0_) : 0.0f;
            p10 = (tb1 + 0 <= sR) ? exp2f(s1[0] - M0_) : 0.0f;
            p11 = (tb1 + 1 <= sR) ? exp2f(s1[1] - M0_) : 0.0f;
            p12 = (tb1 + 2 <= sR) ? exp2f(s1[2] - M0_) : 0.0f;
            p13 = (tb1 + 3 <= sR) ? exp2f(s1[3] - M0_) : 0.0f;
        }
        lac += (p00 + p01) + (p02 + p03) + (p10 + p11) + (p12 + p13);
        U4 bb;
        {
            uint pk00 = cvtpk(p00, p01);
            uint pk01 = cvtpk(p02, p03);
            uint pk10 = cvtpk(p10, p11);
            uint pk11 = cvtpk(p12, p13);
            const int srcA = ((lane >> 4) & 1) * 32 + m;
            const int srcB = srcA + 16;
            uint a00 = (uint)__shfl((int)pk00, srcA, 64);
            uint a01 = (uint)__shfl((int)pk01, srcA, 64);
            uint a10 = (uint)__shfl((int)pk10, srcA, 64);
            uint a11 = (uint)__shfl((int)pk11, srcA, 64);
            uint b00 = (uint)__shfl((int)pk00, srcB, 64);
            uint b01 = (uint)__shfl((int)pk01, srcB, 64);
            uint b10 = (uint)__shfl((int)pk10, srcB, 64);
            uint b11 = (uint)__shfl((int)pk11, srcB, 64);
            const bool hi2 = (lane >> 5) & 1;
            bb.u.x = hi2 ? a10 : a00;
            bb.u.y = hi2 ? a11 : a01;
            bb.u.z = hi2 ? b10 : b00;
            bb.u.w = hi2 ? b11 : b01;
        }
        return bb;
    };

    const int nT = chunk * 4 + 4;
    stage(0, 0);
    int cur = 0;

    for (int it = 0; it < nT; ++it) {
        const int t0 = it * 32;
        __syncthreads();             // drains vmcnt(0): buf[cur] staged
        if (it + 1 < nT) stage(cur ^ 1, it + 1);   // overlap under compute
        __builtin_amdgcn_sched_barrier(0);

        const uint* bb0 = &buf[cur][0];
        const int abase = lane * 4;
        const bool liveB = (t0 <= row0b + 15);
        const bool liveA = (t0 <= row0a + 15);
        const bool twoA  = (t0 < row0a);
        const bool twoB  = (t0 < row0b);

        if (liveB) {
            f32x4 sA0 = (f32x4){0.f,0.f,0.f,0.f}, sA1 = (f32x4){0.f,0.f,0.f,0.f};
            f32x4 sB0 = (f32x4){0.f,0.f,0.f,0.f}, sB1 = (f32x4){0.f,0.f,0.f,0.f};

            if (twoA) {     // both substrips need both halves: 4 MFMAs / read-pair
#pragma unroll
                for (int f = 0; f < 6; ++f) {
                    const int ck = (f < 4) ? f * 2 : (f - 4) * 2 + 8;
                    U4 a0, a1;
                    a0.u = *(const uint4*)&bb0[ck * 256 + abase];
                    a1.u = *(const uint4*)&bb0[(ck + 1) * 256 + abase];
                    sA0 = __builtin_amdgcn_mfma_f32_16x16x32_bf16(a0.v, qfa[f].v, sA0, 0, 0, 0);
                    sB0 = __builtin_amdgcn_mfma_f32_16x16x32_bf16(a0.v, qfb[f].v, sB0, 0, 0, 0);
                    sA1 = __builtin_amdgcn_mfma_f32_16x16x32_bf16(a1.v, qfa[f].v, sA1, 0, 0, 0);
                    sB1 = __builtin_amdgcn_mfma_f32_16x16x32_bf16(a1.v, qfb[f].v, sB1, 0, 0, 0);
                }
            } else {        // A diagonal/dead; B full or diagonal
#pragma unroll
                for (int f = 0; f < 6; ++f) {
                    const int ck = (f < 4) ? f * 2 : (f - 4) * 2 + 8;
                    U4 a0;
                    a0.u = *(const uint4*)&bb0[ck * 256 + abase];
                    if (liveA)
                        sA0 = __builtin_amdgcn_mfma_f32_16x16x32_bf16(a0.v, qfa[f].v, sA0, 0, 0, 0);
                    sB0 = __builtin_amdgcn_mfma_f32_16x16x32_bf16(a0.v, qfb[f].v, sB0, 0, 0, 0);
                    if (twoB) {
                        U4 a1;
                        a1.u = *(const uint4*)&bb0[(ck + 1) * 256 + abase];
                        sB1 = __builtin_amdgcn_mfma_f32_16x16x32_bf16(a1.v, qfb[f].v, sB1, 0, 0, 0);
                    }
                }
            }

            U4 bbB = softpack(sB0, sB1, t0, row0b, lB);
            if (liveA) {
                U4 bbA = softpack(sA0, sA1, t0, row0a, lA);
#pragma unroll
                for (int c = 0; c < 8; ++c) {
                    U4 av; av.u = *(const uint4*)&bb0[(12 + c) * 256 + abase];
                    oB[c] = __builtin_amdgcn_mfma_f32_16x16x32_bf16(av.v, bbB.v, oB[c], 0, 0, 0);
                    oA[c] = __builtin_amdgcn_mfma_f32_16x16x32_bf16(av.v, bbA.v, oA[c], 0, 0, 0);
                }
            } else {
#pragma unroll
                for (int c = 0; c < 8; ++c) {
                    U4 av; av.u = *(const uint4*)&bb0[(12 + c) * 256 + abase];
                    oB[c] = __builtin_amdgcn_mfma_f32_16x16x32_bf16(av.v, bbB.v, oB[c], 0, 0, 0);
                }
            }
        }
        cur ^= 1;
    }

    // ---- epilogue: reduce l across q4 groups; normalize; store both substrips
    lA += __shfl_xor(lA, 16, 64);
    lA += __shfl_xor(lA, 32, 64);
    lB += __shfl_xor(lB, 16, 64);
    lB += __shfl_xor(lB, 32, 64);
    const float invA = 1.0f / lA;
    const float invB = 1.0f / lB;

    ushort* opa = o_h + ((long long)(b * S_ + sRa) * H_ + h) * 128;
    ushort* opb = o_h + ((long long)(b * S_ + sRb) * H_ + h) * 128;
#pragma unroll
    for (int c = 0; c < 8; ++c) {
        uint2 pva, pvb;
        pva.x = cvtpk(oA[c][0] * invA, oA[c][1] * invA);
        pva.y = cvtpk(oA[c][2] * invA, oA[c][3] * invA);
        pvb.x = cvtpk(oB[c][0] * invB, oB[c][1] * invB);
        pvb.y = cvtpk(oB[c][2] * invB, oB[c][3] * invB);
        *(uint2*)&opa[c * 16 + q4 * 4] = pva;
        *(uint2*)&opb[c * 16 + q4 * 4] = pvb;
    }
}

// ---------------------------------------------------------------------------
extern "C" void kernel_launch(void* const* d_in, const int* in_sizes, int n_in,
                              void* d_out, int out_size, void* d_ws, size_t ws_size,
                              hipStream_t stream)
{
    const float* x         = (const float*)d_in[0];
    const float* freqs     = (const float*)d_in[1];
    // d_in[2] = mask (unused: causal handled analytically)
    const float* wq_w      = (const float*)d_in[3];
    const float* wq_b      = (const float*)d_in[4];
    const float* wkv_a_w   = (const float*)d_in[5];
    const float* wkv_a_b   = (const float*)d_in[6];
    const float* kv_norm_w = (const float*)d_in[7];
    const float* wkv_b_w   = (const float*)d_in[8];
    const float* wo_w      = (const float*)d_in[9];
    const float* wo_b      = (const float*)d_in[10];
    float* out = (float*)d_out;

    // ---- workspace layout (~203 MiB)
    char* w = (char*)d_ws;
    ushort* x_bf    = (ushort*)w;  w += 16777216;   // (4096,2048) bf16
    ushort* wq_bf   = (ushort*)w;  w += 12582912;   // (3072,2048) bf16
    ushort* wkva_bf = (ushort*)w;  w += 2621440;    // (640,2048)  bf16 padded
    ushort* wo_bf   = (ushort*)w;  w += 8388608;    // (2048,2048) bf16
    ushort* wkvbK   = (ushort*)w;  w += 2097152;    // (16,128,512) bf16 (K rows)
    ushort* wkvbV   = (ushort*)w;  w += 2097152;    // (16,128,512) bf16 (V rows)
    float*  kv_raw  = (float*)w;   w += 10485760;   // (4096,640) f32
    ushort* kv_h    = (ushort*)w;  w += 4718592;    // (4096,576)  bf16
    ushort* K_h     = (ushort*)w;  w += 16777216;   // (B,2048,16,128) bf16
    ushort* V_hT    = (ushort*)w;  w += 16777216;   // (B,16,128,2048) bf16
    uint4*  khimg   = (uint4*)w;   w += 16777216;   // (B,64,16,8,64)
    uint4*  vhimg   = (uint4*)w;   w += 16777216;   // (B,64,16,8,64)
    uint4*  rimg    = (uint4*)w;   w += 524288;     // (B,64,4,64)
    char* RA = w;                  w += 50331648;
    float*  q_raw = (float*)RA;                     // (4096,3072) f32
    ushort* o_h   = (ushort*)RA;                    // (4096,16,128) bf16 (q dead)
    ushort* q192  = (ushort*)w;    w += 25165824;   // (4096,16,192) bf16

    dim3 blk(256);

    // 0) all f32->bf16 conversions, one launch
    conv_all<<<dim3(21760), blk, 0, stream>>>(
        x, wq_w, wkv_a_w, wo_w, wkv_b_w,
        x_bf, wq_bf, wkva_bf, wo_bf, wkvbK, wkvbV);

    // 1) q_raw = x @ wq_w^T + wq_b
    mgemm<false><<<dim3(24, 32, 1), blk, 0, stream>>>(
        x_bf, 2048, 0LL, 0LL, wq_bf, 2048, 0LL, 0LL, wq_b, 1.0f,
        q_raw, 3072, 0LL, 0LL, 2048, 1);

    // 2) kv_raw = x @ wkv_a_w^T (N=640 padded; bias folded into kv_post)
    mgemm<false><<<dim3(5, 32, 1), blk, 0, stream>>>(
        x_bf, 2048, 0LL, 0LL, wkva_bf, 2048, 0LL, 0LL, nullptr, 1.0f,
        kv_raw, 640, 0LL, 0LL, 2048, 1);

    // 3) q192 = [q_nope, rope(q_pe)] * scale * log2e, bf16
    qprep<<<dim3(12288), blk, 0, stream>>>(q_raw, freqs, q192);

    // 4) bias + rmsnorm + rope -> kv_h
    kv_post_kernel<<<dim3(4096), dim3(64), 0, stream>>>(
        kv_raw, wkv_a_b, kv_norm_w, freqs, kv_h);

    // 5) per-head K/V projections, batched over (h,b) via 2-axis z:
    //    K_h[b,t,h,:]  = kv_proj @ wkv_b[h,:128]^T
    mgemm<true><<<dim3(1, 16, 32), blk, 0, stream>>>(
        kv_h, 576, 0LL, (long long)S_ * 576,
        wkvbK, 512, 65536LL, 0LL, nullptr, 1.0f,
        K_h, 2048, 128LL, (long long)S_ * 2048, 512, 16);
    //    V_hT[b,h,d,t] = wkv_b[h,128:] @ kv_proj^T
    mgemm<true><<<dim3(16, 1, 32), blk, 0, stream>>>(
        wkvbV, 512, 65536LL, 0LL,
        kv_h, 576, 0LL, (long long)S_ * 576, nullptr, 1.0f,
        V_hT, 2048, 262144LL, 4194304LL, 512, 16);

    // 6) fragment images, one launch
    prep_all<<<dim3(8320), blk, 0, stream>>>(K_h, V_hT, kv_h, khimg, vhimg, rimg);

    // 7) MFMA flash attention v10 -> o_h (B,S,H,128) == (4096,2048) rows
    attn_kernel<<<dim3(32, 16, 1), blk, 0, stream>>>(q192, khimg, rimg, vhimg, o_h);

    // 8) out = o_h @ wo_w^T + wo_b
    mgemm<false><<<dim3(16, 32, 1), blk, 0, stream>>>(
        o_h, 2048, 0LL, 0LL, wo_bf, 2048, 0LL, 0LL, wo_b, 1.0f,
        out, 2048, 0LL, 0LL, 2048, 1);
}

// Round 4
// 483.707 us; speedup vs baseline: 1.5641x; 1.0153x over previous
//
#include <hip/hip_runtime.h>
#include <hip/hip_bf16.h>
#include <math.h>

// MLA forward: B=2, S=2048, D=2048, H=16, KV_RANK=512, NOPE=128, ROPE=64
#define B_ 2
#define S_ 2048
#define H_ 16
#define SCALE_ 0.07216878364870323f   // 192^-0.5
#define SL2_ (0.07216878364870323f * 1.4426950408889634f)  // scale * log2(e)
#define EPS_ 1.1920929e-07f
#define M0_ 8.0f                      // constant exp2 shift (cancels in o/l)

typedef __attribute__((ext_vector_type(8))) short bf16x8;
typedef __attribute__((ext_vector_type(4))) float f32x4;
union U4 { uint4 u; bf16x8 v; f32x4 f; };

__device__ __forceinline__ uint bfbits(float x) {   // f32 -> bf16 bits, RNE
    uint u = __float_as_uint(x);
    return (u + 0x7fffu + ((u >> 16) & 1u)) >> 16;
}
__device__ __forceinline__ uint pack2bf(float a, float b) {
    return bfbits(a) | (bfbits(b) << 16);
}
__device__ __forceinline__ uint cvtpk(float a, float b) {  // 1 VALU op, RNE
    uint r;
    asm("v_cvt_pk_bf16_f32 %0, %1, %2" : "=v"(r) : "v"(a), "v"(b));
    return r;
}
__device__ __forceinline__ void gld_lds16(const ushort* g, ushort* l) {
    // async global->LDS DMA, 16B/lane; LDS dest = wave-uniform base + lane*16
    __builtin_amdgcn_global_load_lds(
        (const __attribute__((address_space(1))) uint*)g,
        (__attribute__((address_space(3))) uint*)l, 16, 0, 0);
}

// ---------------------------------------------------------------------------
// MFMA bf16 GEMM (NT): C[m,n] = scale * sum_k A[m,k]*B[n,k] + bias[n]
// 128x128 tile, BK=32, 256 thr (4 waves 2x2 of 64x64), 16x16x32 MFMA.
// z decomposed as z1 = z % zDiv (stride *Off1), z2 = z / zDiv (stride *Off2).
// ---------------------------------------------------------------------------
template<bool OUT_BF16>
__global__ __launch_bounds__(256) void mgemm(
    const ushort* __restrict__ A, int lda, long long aOff1, long long aOff2,
    const ushort* __restrict__ Bm, int ldb, long long bOff1, long long bOff2,
    const float* __restrict__ bias, float scale,
    void* __restrict__ Cv, int ldc, long long cOff1, long long cOff2,
    int K, int zDiv)
{
    __shared__ ushort As[128 * 32];
    __shared__ ushort Bs[128 * 32];

    const int z = blockIdx.z;
    const int z1 = z % zDiv, z2 = z / zDiv;
    A  += z1 * aOff1 + z2 * aOff2;
    Bm += z1 * bOff1 + z2 * bOff2;
    const long long cBase = z1 * cOff1 + z2 * cOff2;

    const int n0 = blockIdx.x * 128;
    const int m0 = blockIdx.y * 128;
    const int tid = threadIdx.x;
    const int w   = tid >> 6;
    const int l   = tid & 63;
    const int m   = l & 15;
    const int q4  = l >> 4;
    const int mw  = (w & 1) * 64;
    const int nw  = (w >> 1) * 64;
    const int sr  = l >> 2;
    const int sc  = l & 3;

    f32x4 acc[4][4];
#pragma unroll
    for (int i = 0; i < 4; ++i)
#pragma unroll
        for (int j = 0; j < 4; ++j) acc[i][j] = (f32x4){0.f, 0.f, 0.f, 0.f};

    for (int k0 = 0; k0 < K; k0 += 32) {
#pragma unroll
        for (int jj = 0; jj < 2; ++jj) {
            const int slot = w * 2 + jj;
            const int row  = slot * 16 + sr;
            const int g    = sc ^ ((row >> 1) & 3);
            gld_lds16(&A[(long long)(m0 + row) * lda + k0 + g * 8], &As[slot * 512]);
            gld_lds16(&Bm[(long long)(n0 + row) * ldb + k0 + g * 8], &Bs[slot * 512]);
        }
        __syncthreads();

        U4 af[4], bf[4];
#pragma unroll
        for (int i = 0; i < 4; ++i) {
            const int ra = mw + i * 16 + m;
            af[i].u = *(const uint4*)&As[ra * 32 + (q4 ^ ((ra >> 1) & 3)) * 8];
            const int rb = nw + i * 16 + m;
            bf[i].u = *(const uint4*)&Bs[rb * 32 + (q4 ^ ((rb >> 1) & 3)) * 8];
        }
#pragma unroll
        for (int i = 0; i < 4; ++i)
#pragma unroll
            for (int j = 0; j < 4; ++j)
                acc[i][j] = __builtin_amdgcn_mfma_f32_16x16x32_bf16(
                    af[i].v, bf[j].v, acc[i][j], 0, 0, 0);
        __syncthreads();
    }

#pragma unroll
    for (int j = 0; j < 4; ++j) {
        const int cn = n0 + nw + j * 16 + m;
        const float bv = bias ? bias[cn] : 0.0f;
#pragma unroll
        for (int i = 0; i < 4; ++i) {
            const int rw = m0 + mw + i * 16 + q4 * 4;
#pragma unroll
            for (int r = 0; r < 4; ++r) {
                const float val = acc[i][j][r] * scale + bv;
                if (OUT_BF16)
                    ((ushort*)Cv)[cBase + (long long)(rw + r) * ldc + cn] =
                        (ushort)bfbits(val);
                else
                    ((float*)Cv)[cBase + (long long)(rw + r) * ldc + cn] = val;
            }
        }
    }
}

// ---------------------------------------------------------------------------
// Fused f32 -> bf16 conversions (6 former kernels, one launch).
// ---------------------------------------------------------------------------
__global__ __launch_bounds__(256) void conv_all(
    const float* __restrict__ x, const float* __restrict__ wq,
    const float* __restrict__ wkva, const float* __restrict__ wo,
    const float* __restrict__ wkvb,
    ushort* __restrict__ x_bf, ushort* __restrict__ wq_bf,
    ushort* __restrict__ wkva_bf, ushort* __restrict__ wo_bf,
    ushort* __restrict__ wkvbK, ushort* __restrict__ wkvbV)
{
    const int bid = blockIdx.x;
    const int tid = threadIdx.x;
    if (bid < 8192) {                       // x: (4096,2048)
        const long long i = ((long long)bid * 256 + tid) * 4;
        float4 v = *(const float4*)&x[i];
        uint2 p; p.x = pack2bf(v.x, v.y); p.y = pack2bf(v.z, v.w);
        *(uint2*)&x_bf[i] = p;
    } else if (bid < 14336) {               // wq: (3072,2048)
        const long long i = ((long long)(bid - 8192) * 256 + tid) * 4;
        float4 v = *(const float4*)&wq[i];
        uint2 p; p.x = pack2bf(v.x, v.y); p.y = pack2bf(v.z, v.w);
        *(uint2*)&wq_bf[i] = p;
    } else if (bid < 15616) {               // wkva: (576,2048) pad to 640
        const int i = ((bid - 14336) * 256 + tid) * 4;
        const int r = i >> 11;
        uint2 p = make_uint2(0u, 0u);
        if (r < 576) {
            float4 v = *(const float4*)&wkva[i];
            p.x = pack2bf(v.x, v.y); p.y = pack2bf(v.z, v.w);
        }
        *(uint2*)&wkva_bf[i] = p;
    } else if (bid < 19712) {               // wo: (2048,2048)
        const long long i = ((long long)(bid - 15616) * 256 + tid) * 4;
        float4 v = *(const float4*)&wo[i];
        uint2 p; p.x = pack2bf(v.x, v.y); p.y = pack2bf(v.z, v.w);
        *(uint2*)&wo_bf[i] = p;
    } else if (bid < 20736) {               // wkv_b rows [0:128) per head -> K
        const int i = ((bid - 19712) * 256 + tid) * 4;
        const int h = i >> 16, rem = i & 65535;
        float4 v = *(const float4*)&wkvb[((long long)(h * 256)) * 512 + rem];
        uint2 p; p.x = pack2bf(v.x, v.y); p.y = pack2bf(v.z, v.w);
        *(uint2*)&wkvbK[i] = p;
    } else {                                // wkv_b rows [128:256) per head -> V
        const int i = ((bid - 20736) * 256 + tid) * 4;
        const int h = i >> 16, rem = i & 65535;
        float4 v = *(const float4*)&wkvb[((long long)(h * 256 + 128)) * 512 + rem];
        uint2 p; p.x = pack2bf(v.x, v.y); p.y = pack2bf(v.z, v.w);
        *(uint2*)&wkvbV[i] = p;
    }
}

// ---------------------------------------------------------------------------
// Fused q prep: q192 = [q_nope * SL2, rope(q_pe) * SL2] bf16 (one read pass).
// ---------------------------------------------------------------------------
__global__ __launch_bounds__(256) void qprep(
    const float* __restrict__ q_raw, const float* __restrict__ freqs,
    ushort* __restrict__ q192)
{
    const int idx = blockIdx.x * 256 + threadIdx.x;   // 0..3145727
    const int row = idx / 48;        // (b*S+s)*16+h
    const int c4  = idx % 48;
    const int bs = row >> 4, h = row & 15;
    const float* src = q_raw + (long long)bs * 3072 + h * 192;
    if (c4 < 32) {
        const int d = c4 * 4;
        float4 v = *(const float4*)&src[d];
        uint2 p;
        p.x = pack2bf(v.x * SL2_, v.y * SL2_);
        p.y = pack2bf(v.z * SL2_, v.w * SL2_);
        *(uint2*)&q192[(long long)row * 192 + d] = p;
    } else {
        const int j = c4 - 32;       // 0..15, two rope pairs
        const int s = bs & 2047;
        const float f0 = freqs[s * 32 + j * 2];
        const float f1 = freqs[s * 32 + j * 2 + 1];
        float c0, s0, c1, s1;
        __sincosf(f0, &s0, &c0);
        __sincosf(f1, &s1, &c1);
        float4 v = *(const float4*)&src[128 + j * 4];
        uint2 p;
        p.x = pack2bf((v.x * c0 - v.y * s0) * SL2_, (v.x * s0 + v.y * c0) * SL2_);
        p.y = pack2bf((v.z * c1 - v.w * s1) * SL2_, (v.z * s1 + v.w * c1) * SL2_);
        *(uint2*)&q192[(long long)row * 192 + 128 + j * 4] = p;
    }
}

// ---------------------------------------------------------------------------
// kv post: bias add + rmsnorm(kv[:512]) and rope(kv[512:576]) -> kv_h bf16.
// ---------------------------------------------------------------------------
__global__ __launch_bounds__(64) void kv_post_kernel(
    const float* __restrict__ kv_raw, const float* __restrict__ bias,
    const float* __restrict__ w, const float* __restrict__ freqs,
    ushort* __restrict__ kv_h)
{
    const int bs = blockIdx.x;
    const int lane = threadIdx.x;
    const float* src = kv_raw + (long long)bs * 640;
    ushort* dst = kv_h + (long long)bs * 576;

    const int c = 4 * lane;
    float4 v0 = *(const float4*)&src[c];
    float4 v1 = *(const float4*)&src[256 + c];
    float4 b0 = *(const float4*)&bias[c];
    float4 b1 = *(const float4*)&bias[256 + c];
    v0.x += b0.x; v0.y += b0.y; v0.z += b0.z; v0.w += b0.w;
    v1.x += b1.x; v1.y += b1.y; v1.z += b1.z; v1.w += b1.w;
    float ss = v0.x * v0.x + v0.y * v0.y + v0.z * v0.z + v0.w * v0.w +
               v1.x * v1.x + v1.y * v1.y + v1.z * v1.z + v1.w * v1.w;
#pragma unroll
    for (int o = 32; o; o >>= 1) ss += __shfl_xor(ss, o, 64);
    const float rs = rsqrtf(ss * (1.0f / 512.0f) + EPS_);

    float4 w0 = *(const float4*)&w[c];
    float4 w1 = *(const float4*)&w[256 + c];
    uint2 p0, p1;
    p0.x = pack2bf(v0.x * rs * w0.x, v0.y * rs * w0.y);
    p0.y = pack2bf(v0.z * rs * w0.z, v0.w * rs * w0.w);
    p1.x = pack2bf(v1.x * rs * w1.x, v1.y * rs * w1.y);
    p1.y = pack2bf(v1.z * rs * w1.z, v1.w * rs * w1.w);
    *(uint2*)&dst[c] = p0;
    *(uint2*)&dst[256 + c] = p1;

    if (lane < 32) {
        const int s = bs & 2047;
        const float f = freqs[s * 32 + lane];
        float cs, sn;
        __sincosf(f, &sn, &cs);
        const float a  = src[512 + 2 * lane]     + bias[512 + 2 * lane];
        const float b2 = src[512 + 2 * lane + 1] + bias[512 + 2 * lane + 1];
        *(uint*)&dst[512 + 2 * lane] = pack2bf(a * cs - b2 * sn, a * sn + b2 * cs);
    }
}

// ---------------------------------------------------------------------------
// Fused fragment-image prep (K, V, rope images in one launch).
// khimg[b][tile][h][ck=f*2+s][lane=(q4,m)] = K_h[b][t0+s*16+m][h*128+f*32+q4*8..]
// vhimg[b][tile][h][c][lane=(q4,m)]        = V_hT[b][h][c*16+m][t0+q4*8..]
// rimg [b][tile][ck=f2*2+s][lane]          = k_pe octets (shared across heads)
// ---------------------------------------------------------------------------
__global__ __launch_bounds__(256) void prep_all(
    const ushort* __restrict__ K_h, const ushort* __restrict__ V_hT,
    const ushort* __restrict__ kv_h,
    uint4* __restrict__ khimg, uint4* __restrict__ vhimg,
    uint4* __restrict__ rimg)
{
    const int bid = blockIdx.x;
    if (bid < 4096) {
        const int g = bid * 256 + threadIdx.x;
        const int lane = g & 63, ck = (g >> 6) & 7, h = (g >> 9) & 15;
        const int tile = (g >> 13) & 63, b = g >> 19;
        const int m = lane & 15, q4 = lane >> 4, f = ck >> 1, s = ck & 1;
        const uint4 v = *(const uint4*)&K_h[
            ((long long)(b * S_ + tile * 32 + s * 16 + m)) * 2048 + h * 128 + f * 32 + q4 * 8];
        khimg[(((long long)(b * 64 + tile) * 16 + h) * 8 + ck) * 64 + lane] = v;
    } else if (bid < 8192) {
        const int g = (bid - 4096) * 256 + threadIdx.x;
        const int lane = g & 63, c = (g >> 6) & 7, h = (g >> 9) & 15;
        const int tile = (g >> 13) & 63, b = g >> 19;
        const int m = lane & 15, q4 = lane >> 4;
        const uint4 v = *(const uint4*)&V_hT[
            ((long long)((b * 16 + h) * 128 + c * 16 + m)) * 2048 + tile * 32 + q4 * 8];
        vhimg[(((long long)(b * 64 + tile) * 16 + h) * 8 + c) * 64 + lane] = v;
    } else {
        const int g = (bid - 8192) * 256 + threadIdx.x;
        const int lane = g & 63, ck = (g >> 6) & 3, tile = (g >> 8) & 63, b = g >> 14;
        const int m = lane & 15, q4 = lane >> 4, f2 = ck >> 1, s = ck & 1;
        const uint4 v = *(const uint4*)&kv_h[
            ((long long)(b * S_ + tile * 32 + s * 16 + m)) * 576 + 512 + f2 * 32 + q4 * 8];
        rimg[((long long)(b * 64 + tile) * 4 + ck) * 64 + lane] = v;
    }
}

// ---------------------------------------------------------------------------
// MFMA flash attention v11 = v10 compute + uniform chunk pairing +
// permlane/swizzle P-repack (LDS-pipe relief).
//   * Pairing: block p does chunk 15-p (128 rows) then chunk p -> exactly
//     68 tiles per block; grid 8x16x2 = 256 blocks = 1 block/CU, no tail.
//   * P^T repack: 2x v_permlane32_swap (VALU) + 2x ds_swizzle xor16 + selects
//     replaces 16 ds_bpermute per softpack (LDS ops 16 -> 2).
// Block = 256 thr = 4 waves, ONE head, 128 q-rows/pass (wave w: rows w*16
// and w*16+64). LDS 40 KB dbuf.
// ---------------------------------------------------------------------------
__global__ __launch_bounds__(256, 2) void attn_kernel(
    const ushort* __restrict__ q192,  // (B,S,H,192), q*scale*log2e
    const uint4*  __restrict__ khimg, // (B,64,16,8,64) K_h frag chunks
    const uint4*  __restrict__ rimg,  // (B,64,4,64)   k_pe frag chunks
    const uint4*  __restrict__ vhimg, // (B,64,16,8,64) V_h^T frag chunks
    ushort* __restrict__ o_h)         // (B,S,H,128)
{
    __shared__ uint buf[2][20 * 256];   // 2 x 20 KB

    const int p    = blockIdx.x;          // 0..7 (chunk pair)
    const int h    = blockIdx.y;          // 0..15
    const int b    = blockIdx.z;
    const int tid  = threadIdx.x;
    const int wid  = tid >> 6;            // 0..3
    const int lane = tid & 63;
    const int m    = lane & 15;
    const int q4   = lane >> 4;
    const bool odd = q4 & 1;

    auto stage = [&](int bs, int it) {
        const long long tb = (long long)(b * 64 + it);
        const uint4* kb = khimg + ((tb * 16 + h) * 8) * 64;
        const uint4* rb = rimg  + (tb * 4) * 64;
        const uint4* vb = vhimg + ((tb * 16 + h) * 8) * 64;
        ushort* l = (ushort*)&buf[bs][0];
        gld_lds16((const ushort*)(kb + (wid    ) * 64 + lane), l + (wid     ) * 512);
        gld_lds16((const ushort*)(kb + (wid + 4) * 64 + lane), l + (wid +  4) * 512);
        gld_lds16((const ushort*)(rb + (wid    ) * 64 + lane), l + (wid +  8) * 512);
        gld_lds16((const ushort*)(vb + (wid    ) * 64 + lane), l + (wid + 12) * 512);
        gld_lds16((const ushort*)(vb + (wid + 4) * 64 + lane), l + (wid + 16) * 512);
    };

    int cur = 0;
    for (int pass = 0; pass < 2; ++pass) {
        const int chunk = pass ? p : (15 - p);
        const int row0a = chunk * 128 + wid * 16;
        const int row0b = row0a + 64;
        const int sRa   = row0a + m;
        const int sRb   = row0b + m;

        // Q B-frags for both substrips: qf[f] = Q[sR][f*32 + q4*8 + j]
        U4 qfa[6], qfb[6];
        {
            const uint4* qpa = (const uint4*)(q192 + ((long long)(b * S_ + sRa) * H_ + h) * 192);
            const uint4* qpb = (const uint4*)(q192 + ((long long)(b * S_ + sRb) * H_ + h) * 192);
#pragma unroll
            for (int f = 0; f < 6; ++f) { qfa[f].u = qpa[f * 4 + q4]; qfb[f].u = qpb[f * 4 + q4]; }
        }

        f32x4 oA[8], oB[8];
#pragma unroll
        for (int c = 0; c < 8; ++c) {
            oA[c] = (f32x4){0.f, 0.f, 0.f, 0.f};
            oB[c] = (f32x4){0.f, 0.f, 0.f, 0.f};
        }
        float lA = 0.0f, lB = 0.0f;

        // softmax (exp2, diagonal-only masking) + P^T repack -> PV B-frag.
        // Repack: after permlane32_swap, each lane's missing t-octet half
        // sits at lane^16; parity-selected send via ds_swizzle xor16.
        auto softpack = [&](const f32x4 s0, const f32x4 s1, int t0v, int rw0,
                            float& lac) -> U4 {
            float p00, p01, p02, p03, p10, p11, p12, p13;
            if (t0v + 31 <= rw0) {            // fully unmasked tile
                p00 = exp2f(s0[0] - M0_); p01 = exp2f(s0[1] - M0_);
                p02 = exp2f(s0[2] - M0_); p03 = exp2f(s0[3] - M0_);
                p10 = exp2f(s1[0] - M0_); p11 = exp2f(s1[1] - M0_);
                p12 = exp2f(s1[2] - M0_); p13 = exp2f(s1[3] - M0_);
            } else {                          // diagonal tile
                const int sR = rw0 + m;
                const int tb0 = t0v + q4 * 4;
                const int tb1 = tb0 + 16;
                p00 = (tb0 + 0 <= sR) ? exp2f(s0[0] - M0_) : 0.0f;
                p01 = (tb0 + 1 <= sR) ? exp2f(s0[1] - M0_) : 0.0f;
                p02 = (tb0 + 2 <= sR) ? exp2f(s0[2] - M0_) : 0.0f;
                p03 = (tb0 + 3 <= sR) ? exp2f(s0[3] - M0_) : 0.0f;
                p10 = (tb1 + 0 <= sR) ? exp2f(s1[0] - M0_) : 0.0f;
                p11 = (tb1 + 1 <= sR) ? exp2f(s1[1] - M0_) : 0.0f;
                p12 = (tb1 + 2 <= sR) ? exp2f(s1[2] - M0_) : 0.0f;
                p13 = (tb1 + 3 <= sR) ? exp2f(s1[3] - M0_) : 0.0f;
            }
            lac += (p00 + p01) + (p02 + p03) + (p10 + p11) + (p12 + p13);
            // lane (q4',m) packs: X0/X1 = st0 t(4q4'..+3), Y0/Y1 = st1 (+16)
            uint X0 = cvtpk(p00, p01), X1 = cvtpk(p02, p03);
            uint Y0 = cvtpk(p10, p11), Y1 = cvtpk(p12, p13);
            // swap: X = [X.lo32 | Y.lo32], Y = [X.hi32 | Y.hi32]
            asm("v_permlane32_swap_b32 %0, %1" : "+v"(X0), "+v"(Y0));
            asm("v_permlane32_swap_b32 %0, %1" : "+v"(X1), "+v"(Y1));
            // even q4 needs (X of lane^16); odd q4 needs (Y of lane^16)
            uint u0 = odd ? X0 : Y0;          // send what the partner needs
            uint u1 = odd ? X1 : Y1;
            uint w0 = (uint)__builtin_amdgcn_ds_swizzle((int)u0, 0x401F); // xor 16
            uint w1 = (uint)__builtin_amdgcn_ds_swizzle((int)u1, 0x401F);
            U4 bb;
            bb.u.x = odd ? w0 : X0;
            bb.u.y = odd ? w1 : X1;
            bb.u.z = odd ? Y0 : w0;
            bb.u.w = odd ? Y1 : w1;
            return bb;
        };

        const int nT = chunk * 4 + 4;
        __syncthreads();                 // all reads of prev pass's LDS done
        stage(cur, 0);

        for (int it = 0; it < nT; ++it) {
            const int t0 = it * 32;
            __syncthreads();             // drains vmcnt(0): buf[cur] staged
            if (it + 1 < nT) stage(cur ^ 1, it + 1);   // overlap under compute
            __builtin_amdgcn_sched_barrier(0);

            const uint* bb0 = &buf[cur][0];
            const int abase = lane * 4;
            const bool liveB = (t0 <= row0b + 15);
            const bool liveA = (t0 <= row0a + 15);
            const bool twoA  = (t0 < row0a);
            const bool twoB  = (t0 < row0b);

            if (liveB) {
                f32x4 sA0 = (f32x4){0.f,0.f,0.f,0.f}, sA1 = (f32x4){0.f,0.f,0.f,0.f};
                f32x4 sB0 = (f32x4){0.f,0.f,0.f,0.f}, sB1 = (f32x4){0.f,0.f,0.f,0.f};

                if (twoA) {     // both substrips full: 4 MFMAs per read-pair
#pragma unroll
                    for (int f = 0; f < 6; ++f) {
                        const int ck = (f < 4) ? f * 2 : (f - 4) * 2 + 8;
                        U4 a0, a1;
                        a0.u = *(const uint4*)&bb0[ck * 256 + abase];
                        a1.u = *(const uint4*)&bb0[(ck + 1) * 256 + abase];
                        sA0 = __builtin_amdgcn_mfma_f32_16x16x32_bf16(a0.v, qfa[f].v, sA0, 0, 0, 0);
                        sB0 = __builtin_amdgcn_mfma_f32_16x16x32_bf16(a0.v, qfb[f].v, sB0, 0, 0, 0);
                        sA1 = __builtin_amdgcn_mfma_f32_16x16x32_bf16(a1.v, qfa[f].v, sA1, 0, 0, 0);
                        sB1 = __builtin_amdgcn_mfma_f32_16x16x32_bf16(a1.v, qfb[f].v, sB1, 0, 0, 0);
                    }
                } else {        // A diagonal/dead; B full or diagonal
#pragma unroll
                    for (int f = 0; f < 6; ++f) {
                        const int ck = (f < 4) ? f * 2 : (f - 4) * 2 + 8;
                        U4 a0;
                        a0.u = *(const uint4*)&bb0[ck * 256 + abase];
                        if (liveA)
                            sA0 = __builtin_amdgcn_mfma_f32_16x16x32_bf16(a0.v, qfa[f].v, sA0, 0, 0, 0);
                        sB0 = __builtin_amdgcn_mfma_f32_16x16x32_bf16(a0.v, qfb[f].v, sB0, 0, 0, 0);
                        if (twoB) {
                            U4 a1;
                            a1.u = *(const uint4*)&bb0[(ck + 1) * 256 + abase];
                            sB1 = __builtin_amdgcn_mfma_f32_16x16x32_bf16(a1.v, qfb[f].v, sB1, 0, 0, 0);
                        }
                    }
                }

                U4 bbB = softpack(sB0, sB1, t0, row0b, lB);
                if (liveA) {
                    U4 bbA = softpack(sA0, sA1, t0, row0a, lA);
#pragma unroll
                    for (int c = 0; c < 8; ++c) {
                        U4 av; av.u = *(const uint4*)&bb0[(12 + c) * 256 + abase];
                        oB[c] = __builtin_amdgcn_mfma_f32_16x16x32_bf16(av.v, bbB.v, oB[c], 0, 0, 0);
                        oA[c] = __builtin_amdgcn_mfma_f32_16x16x32_bf16(av.v, bbA.v, oA[c], 0, 0, 0);
                    }
                } else {
#pragma unroll
                    for (int c = 0; c < 8; ++c) {
                        U4 av; av.u = *(const uint4*)&bb0[(12 + c) * 256 + abase];
                        oB[c] = __builtin_amdgcn_mfma_f32_16x16x32_bf16(av.v, bbB.v, oB[c], 0, 0, 0);
                    }
                }
            }
            cur ^= 1;
        }

        // ---- epilogue: reduce l across q4 groups; normalize; store
        lA += __shfl_xor(lA, 16, 64);
        lA += __shfl_xor(lA, 32, 64);
        lB += __shfl_xor(lB, 16, 64);
        lB += __shfl_xor(lB, 32, 64);
        const float invA = 1.0f / lA;
        const float invB = 1.0f / lB;

        ushort* opa = o_h + ((long long)(b * S_ + sRa) * H_ + h) * 128;
        ushort* opb = o_h + ((long long)(b * S_ + sRb) * H_ + h) * 128;
#pragma unroll
        for (int c = 0; c < 8; ++c) {
            uint2 pva, pvb;
            pva.x = cvtpk(oA[c][0] * invA, oA[c][1] * invA);
            pva.y = cvtpk(oA[c][2] * invA, oA[c][3] * invA);
            pvb.x = cvtpk(oB[c][0] * invB, oB[c][1] * invB);
            pvb.y = cvtpk(oB[c][2] * invB, oB[c][3] * invB);
            *(uint2*)&opa[c * 16 + q4 * 4] = pva;
            *(uint2*)&opb[c * 16 + q4 * 4] = pvb;
        }
    }
}

// ---------------------------------------------------------------------------
extern "C" void kernel_launch(void* const* d_in, const int* in_sizes, int n_in,
                              void* d_out, int out_size, void* d_ws, size_t ws_size,
                              hipStream_t stream)
{
    const float* x         = (const float*)d_in[0];
    const float* freqs     = (const float*)d_in[1];
    // d_in[2] = mask (unused: causal handled analytically)
    const float* wq_w      = (const float*)d_in[3];
    const float* wq_b      = (const float*)d_in[4];
    const float* wkv_a_w   = (const float*)d_in[5];
    const float* wkv_a_b   = (const float*)d_in[6];
    const float* kv_norm_w = (const float*)d_in[7];
    const float* wkv_b_w   = (const float*)d_in[8];
    const float* wo_w      = (const float*)d_in[9];
    const float* wo_b      = (const float*)d_in[10];
    float* out = (float*)d_out;

    // ---- workspace layout (~203 MiB)
    char* w = (char*)d_ws;
    ushort* x_bf    = (ushort*)w;  w += 16777216;   // (4096,2048) bf16
    ushort* wq_bf   = (ushort*)w;  w += 12582912;   // (3072,2048) bf16
    ushort* wkva_bf = (ushort*)w;  w += 2621440;    // (640,2048)  bf16 padded
    ushort* wo_bf   = (ushort*)w;  w += 8388608;    // (2048,2048) bf16
    ushort* wkvbK   = (ushort*)w;  w += 2097152;    // (16,128,512) bf16 (K rows)
    ushort* wkvbV   = (ushort*)w;  w += 2097152;    // (16,128,512) bf16 (V rows)
    float*  kv_raw  = (float*)w;   w += 10485760;   // (4096,640) f32
    ushort* kv_h    = (ushort*)w;  w += 4718592;    // (4096,576)  bf16
    ushort* K_h     = (ushort*)w;  w += 16777216;   // (B,2048,16,128) bf16
    ushort* V_hT    = (ushort*)w;  w += 16777216;   // (B,16,128,2048) bf16
    uint4*  khimg   = (uint4*)w;   w += 16777216;   // (B,64,16,8,64)
    uint4*  vhimg   = (uint4*)w;   w += 16777216;   // (B,64,16,8,64)
    uint4*  rimg    = (uint4*)w;   w += 524288;     // (B,64,4,64)
    char* RA = w;                  w += 50331648;
    float*  q_raw = (float*)RA;                     // (4096,3072) f32
    ushort* o_h   = (ushort*)RA;                    // (4096,16,128) bf16 (q dead)
    ushort* q192  = (ushort*)w;    w += 25165824;   // (4096,16,192) bf16

    dim3 blk(256);

    // 0) all f32->bf16 conversions, one launch
    conv_all<<<dim3(21760), blk, 0, stream>>>(
        x, wq_w, wkv_a_w, wo_w, wkv_b_w,
        x_bf, wq_bf, wkva_bf, wo_bf, wkvbK, wkvbV);

    // 1) q_raw = x @ wq_w^T + wq_b
    mgemm<false><<<dim3(24, 32, 1), blk, 0, stream>>>(
        x_bf, 2048, 0LL, 0LL, wq_bf, 2048, 0LL, 0LL, wq_b, 1.0f,
        q_raw, 3072, 0LL, 0LL, 2048, 1);

    // 2) kv_raw = x @ wkv_a_w^T (N=640 padded; bias folded into kv_post)
    mgemm<false><<<dim3(5, 32, 1), blk, 0, stream>>>(
        x_bf, 2048, 0LL, 0LL, wkva_bf, 2048, 0LL, 0LL, nullptr, 1.0f,
        kv_raw, 640, 0LL, 0LL, 2048, 1);

    // 3) q192 = [q_nope, rope(q_pe)] * scale * log2e, bf16
    qprep<<<dim3(12288), blk, 0, stream>>>(q_raw, freqs, q192);

    // 4) bias + rmsnorm + rope -> kv_h
    kv_post_kernel<<<dim3(4096), dim3(64), 0, stream>>>(
        kv_raw, wkv_a_b, kv_norm_w, freqs, kv_h);

    // 5) per-head K/V projections, batched over (h,b) via 2-axis z:
    //    K_h[b,t,h,:]  = kv_proj @ wkv_b[h,:128]^T
    mgemm<true><<<dim3(1, 16, 32), blk, 0, stream>>>(
        kv_h, 576, 0LL, (long long)S_ * 576,
        wkvbK, 512, 65536LL, 0LL, nullptr, 1.0f,
        K_h, 2048, 128LL, (long long)S_ * 2048, 512, 16);
    //    V_hT[b,h,d,t] = wkv_b[h,128:] @ kv_proj^T
    mgemm<true><<<dim3(16, 1, 32), blk, 0, stream>>>(
        wkvbV, 512, 65536LL, 0LL,
        kv_h, 576, 0LL, (long long)S_ * 576, nullptr, 1.0f,
        V_hT, 2048, 262144LL, 4194304LL, 512, 16);

    // 6) fragment images, one launch
    prep_all<<<dim3(8320), blk, 0, stream>>>(K_h, V_hT, kv_h, khimg, vhimg, rimg);

    // 7) MFMA flash attention v11 -> o_h (B,S,H,128) == (4096,2048) rows
    attn_kernel<<<dim3(8, 16, 2), blk, 0, stream>>>(q192, khimg, rimg, vhimg, o_h);

    // 8) out = o_h @ wo_w^T + wo_b
    mgemm<false><<<dim3(16, 32, 1), blk, 0, stream>>>(
        o_h, 2048, 0LL, 0LL, wo_bf, 2048, 0LL, 0LL, wo_b, 1.0f,
        out, 2048, 0LL, 0LL, 2048, 1);
}

// Round 5
// 465.985 us; speedup vs baseline: 1.6236x; 1.0380x over previous
//
#include <hip/hip_runtime.h>
#include <hip/hip_bf16.h>
#include <math.h>

// MLA forward: B=2, S=2048, D=2048, H=16, KV_RANK=512, NOPE=128, ROPE=64
#define B_ 2
#define S_ 2048
#define H_ 16
#define SCALE_ 0.07216878364870323f   // 192^-0.5
#define SL2_ (0.07216878364870323f * 1.4426950408889634f)  // scale * log2(e)
#define EPS_ 1.1920929e-07f
#define M0_ 8.0f                      // constant exp2 shift (cancels in o/l)

typedef __attribute__((ext_vector_type(8))) short bf16x8;
typedef __attribute__((ext_vector_type(4))) float f32x4;
union U4 { uint4 u; bf16x8 v; f32x4 f; };

__device__ __forceinline__ uint bfbits(float x) {   // f32 -> bf16 bits, RNE
    uint u = __float_as_uint(x);
    return (u + 0x7fffu + ((u >> 16) & 1u)) >> 16;
}
__device__ __forceinline__ uint pack2bf(float a, float b) {
    return bfbits(a) | (bfbits(b) << 16);
}
__device__ __forceinline__ uint cvtpk(float a, float b) {  // 1 VALU op, RNE
    uint r;
    asm("v_cvt_pk_bf16_f32 %0, %1, %2" : "=v"(r) : "v"(a), "v"(b));
    return r;
}
__device__ __forceinline__ void gld_lds16(const ushort* g, ushort* l) {
    // async global->LDS DMA, 16B/lane; LDS dest = wave-uniform base + lane*16
    __builtin_amdgcn_global_load_lds(
        (const __attribute__((address_space(1))) uint*)g,
        (__attribute__((address_space(3))) uint*)l, 16, 0, 0);
}

// ---------------------------------------------------------------------------
// MFMA bf16 GEMM (NT): C[m,n] = scale * sum_k A[m,k]*B[n,k] + bias[n]
// 128x128 tile, BK=32, 256 thr (4 waves 2x2 of 64x64), 16x16x32 MFMA.
// z decomposed as z1 = z % zDiv (stride *Off1), z2 = z / zDiv (stride *Off2).
// ---------------------------------------------------------------------------
template<bool OUT_BF16>
__global__ __launch_bounds__(256) void mgemm(
    const ushort* __restrict__ A, int lda, long long aOff1, long long aOff2,
    const ushort* __restrict__ Bm, int ldb, long long bOff1, long long bOff2,
    const float* __restrict__ bias, float scale,
    void* __restrict__ Cv, int ldc, long long cOff1, long long cOff2,
    int K, int zDiv)
{
    __shared__ ushort As[128 * 32];
    __shared__ ushort Bs[128 * 32];

    const int z = blockIdx.z;
    const int z1 = z % zDiv, z2 = z / zDiv;
    A  += z1 * aOff1 + z2 * aOff2;
    Bm += z1 * bOff1 + z2 * bOff2;
    const long long cBase = z1 * cOff1 + z2 * cOff2;

    const int n0 = blockIdx.x * 128;
    const int m0 = blockIdx.y * 128;
    const int tid = threadIdx.x;
    const int w   = tid >> 6;
    const int l   = tid & 63;
    const int m   = l & 15;
    const int q4  = l >> 4;
    const int mw  = (w & 1) * 64;
    const int nw  = (w >> 1) * 64;
    const int sr  = l >> 2;
    const int sc  = l & 3;

    f32x4 acc[4][4];
#pragma unroll
    for (int i = 0; i < 4; ++i)
#pragma unroll
        for (int j = 0; j < 4; ++j) acc[i][j] = (f32x4){0.f, 0.f, 0.f, 0.f};

    for (int k0 = 0; k0 < K; k0 += 32) {
#pragma unroll
        for (int jj = 0; jj < 2; ++jj) {
            const int slot = w * 2 + jj;
            const int row  = slot * 16 + sr;
            const int g    = sc ^ ((row >> 1) & 3);
            gld_lds16(&A[(long long)(m0 + row) * lda + k0 + g * 8], &As[slot * 512]);
            gld_lds16(&Bm[(long long)(n0 + row) * ldb + k0 + g * 8], &Bs[slot * 512]);
        }
        __syncthreads();

        U4 af[4], bf[4];
#pragma unroll
        for (int i = 0; i < 4; ++i) {
            const int ra = mw + i * 16 + m;
            af[i].u = *(const uint4*)&As[ra * 32 + (q4 ^ ((ra >> 1) & 3)) * 8];
            const int rb = nw + i * 16 + m;
            bf[i].u = *(const uint4*)&Bs[rb * 32 + (q4 ^ ((rb >> 1) & 3)) * 8];
        }
#pragma unroll
        for (int i = 0; i < 4; ++i)
#pragma unroll
            for (int j = 0; j < 4; ++j)
                acc[i][j] = __builtin_amdgcn_mfma_f32_16x16x32_bf16(
                    af[i].v, bf[j].v, acc[i][j], 0, 0, 0);
        __syncthreads();
    }

#pragma unroll
    for (int j = 0; j < 4; ++j) {
        const int cn = n0 + nw + j * 16 + m;
        const float bv = bias ? bias[cn] : 0.0f;
#pragma unroll
        for (int i = 0; i < 4; ++i) {
            const int rw = m0 + mw + i * 16 + q4 * 4;
#pragma unroll
            for (int r = 0; r < 4; ++r) {
                const float val = acc[i][j][r] * scale + bv;
                if (OUT_BF16)
                    ((ushort*)Cv)[cBase + (long long)(rw + r) * ldc + cn] =
                        (ushort)bfbits(val);
                else
                    ((float*)Cv)[cBase + (long long)(rw + r) * ldc + cn] = val;
            }
        }
    }
}

// ---------------------------------------------------------------------------
// Fused f32 -> bf16 conversions (one launch).
// ---------------------------------------------------------------------------
__global__ __launch_bounds__(256) void conv_all(
    const float* __restrict__ x, const float* __restrict__ wq,
    const float* __restrict__ wkva, const float* __restrict__ wo,
    const float* __restrict__ wkvb,
    ushort* __restrict__ x_bf, ushort* __restrict__ wq_bf,
    ushort* __restrict__ wkva_bf, ushort* __restrict__ wo_bf,
    ushort* __restrict__ wkvbK, ushort* __restrict__ wkvbV)
{
    const int bid = blockIdx.x;
    const int tid = threadIdx.x;
    if (bid < 8192) {                       // x: (4096,2048)
        const long long i = ((long long)bid * 256 + tid) * 4;
        float4 v = *(const float4*)&x[i];
        uint2 p; p.x = pack2bf(v.x, v.y); p.y = pack2bf(v.z, v.w);
        *(uint2*)&x_bf[i] = p;
    } else if (bid < 14336) {               // wq: (3072,2048)
        const long long i = ((long long)(bid - 8192) * 256 + tid) * 4;
        float4 v = *(const float4*)&wq[i];
        uint2 p; p.x = pack2bf(v.x, v.y); p.y = pack2bf(v.z, v.w);
        *(uint2*)&wq_bf[i] = p;
    } else if (bid < 15616) {               // wkva: (576,2048) pad to 640
        const int i = ((bid - 14336) * 256 + tid) * 4;
        const int r = i >> 11;
        uint2 p = make_uint2(0u, 0u);
        if (r < 576) {
            float4 v = *(const float4*)&wkva[i];
            p.x = pack2bf(v.x, v.y); p.y = pack2bf(v.z, v.w);
        }
        *(uint2*)&wkva_bf[i] = p;
    } else if (bid < 19712) {               // wo: (2048,2048)
        const long long i = ((long long)(bid - 15616) * 256 + tid) * 4;
        float4 v = *(const float4*)&wo[i];
        uint2 p; p.x = pack2bf(v.x, v.y); p.y = pack2bf(v.z, v.w);
        *(uint2*)&wo_bf[i] = p;
    } else if (bid < 20736) {               // wkv_b rows [0:128) per head -> K
        const int i = ((bid - 19712) * 256 + tid) * 4;
        const int h = i >> 16, rem = i & 65535;
        float4 v = *(const float4*)&wkvb[((long long)(h * 256)) * 512 + rem];
        uint2 p; p.x = pack2bf(v.x, v.y); p.y = pack2bf(v.z, v.w);
        *(uint2*)&wkvbK[i] = p;
    } else {                                // wkv_b rows [128:256) per head -> V
        const int i = ((bid - 20736) * 256 + tid) * 4;
        const int h = i >> 16, rem = i & 65535;
        float4 v = *(const float4*)&wkvb[((long long)(h * 256 + 128)) * 512 + rem];
        uint2 p; p.x = pack2bf(v.x, v.y); p.y = pack2bf(v.z, v.w);
        *(uint2*)&wkvbV[i] = p;
    }
}

// ---------------------------------------------------------------------------
// Fused q prep: q192 = [q_nope * SL2, rope(q_pe) * SL2] bf16 (one read pass).
// ---------------------------------------------------------------------------
__global__ __launch_bounds__(256) void qprep(
    const float* __restrict__ q_raw, const float* __restrict__ freqs,
    ushort* __restrict__ q192)
{
    const int idx = blockIdx.x * 256 + threadIdx.x;   // 0..3145727
    const int row = idx / 48;        // (b*S+s)*16+h
    const int c4  = idx % 48;
    const int bs = row >> 4, h = row & 15;
    const float* src = q_raw + (long long)bs * 3072 + h * 192;
    if (c4 < 32) {
        const int d = c4 * 4;
        float4 v = *(const float4*)&src[d];
        uint2 p;
        p.x = pack2bf(v.x * SL2_, v.y * SL2_);
        p.y = pack2bf(v.z * SL2_, v.w * SL2_);
        *(uint2*)&q192[(long long)row * 192 + d] = p;
    } else {
        const int j = c4 - 32;       // 0..15, two rope pairs
        const int s = bs & 2047;
        const float f0 = freqs[s * 32 + j * 2];
        const float f1 = freqs[s * 32 + j * 2 + 1];
        float c0, s0, c1, s1;
        __sincosf(f0, &s0, &c0);
        __sincosf(f1, &s1, &c1);
        float4 v = *(const float4*)&src[128 + j * 4];
        uint2 p;
        p.x = pack2bf((v.x * c0 - v.y * s0) * SL2_, (v.x * s0 + v.y * c0) * SL2_);
        p.y = pack2bf((v.z * c1 - v.w * s1) * SL2_, (v.z * s1 + v.w * c1) * SL2_);
        *(uint2*)&q192[(long long)row * 192 + 128 + j * 4] = p;
    }
}

// ---------------------------------------------------------------------------
// kv post: bias add + rmsnorm(kv[:512]) and rope(kv[512:576]) -> kv_h bf16.
// ---------------------------------------------------------------------------
__global__ __launch_bounds__(64) void kv_post_kernel(
    const float* __restrict__ kv_raw, const float* __restrict__ bias,
    const float* __restrict__ w, const float* __restrict__ freqs,
    ushort* __restrict__ kv_h)
{
    const int bs = blockIdx.x;
    const int lane = threadIdx.x;
    const float* src = kv_raw + (long long)bs * 640;
    ushort* dst = kv_h + (long long)bs * 576;

    const int c = 4 * lane;
    float4 v0 = *(const float4*)&src[c];
    float4 v1 = *(const float4*)&src[256 + c];
    float4 b0 = *(const float4*)&bias[c];
    float4 b1 = *(const float4*)&bias[256 + c];
    v0.x += b0.x; v0.y += b0.y; v0.z += b0.z; v0.w += b0.w;
    v1.x += b1.x; v1.y += b1.y; v1.z += b1.z; v1.w += b1.w;
    float ss = v0.x * v0.x + v0.y * v0.y + v0.z * v0.z + v0.w * v0.w +
               v1.x * v1.x + v1.y * v1.y + v1.z * v1.z + v1.w * v1.w;
#pragma unroll
    for (int o = 32; o; o >>= 1) ss += __shfl_xor(ss, o, 64);
    const float rs = rsqrtf(ss * (1.0f / 512.0f) + EPS_);

    float4 w0 = *(const float4*)&w[c];
    float4 w1 = *(const float4*)&w[256 + c];
    uint2 p0, p1;
    p0.x = pack2bf(v0.x * rs * w0.x, v0.y * rs * w0.y);
    p0.y = pack2bf(v0.z * rs * w0.z, v0.w * rs * w0.w);
    p1.x = pack2bf(v1.x * rs * w1.x, v1.y * rs * w1.y);
    p1.y = pack2bf(v1.z * rs * w1.z, v1.w * rs * w1.w);
    *(uint2*)&dst[c] = p0;
    *(uint2*)&dst[256 + c] = p1;

    if (lane < 32) {
        const int s = bs & 2047;
        const float f = freqs[s * 32 + lane];
        float cs, sn;
        __sincosf(f, &sn, &cs);
        const float a  = src[512 + 2 * lane]     + bias[512 + 2 * lane];
        const float b2 = src[512 + 2 * lane + 1] + bias[512 + 2 * lane + 1];
        *(uint*)&dst[512 + 2 * lane] = pack2bf(a * cs - b2 * sn, a * sn + b2 * cs);
    }
}

// ---------------------------------------------------------------------------
// Fused fragment-image prep (K, V, rope images in one launch).
// khimg[b][tile][h][ck=f*2+s][lane=(q4,m)] = K_h[b][t0+s*16+m][h*128+f*32+q4*8..]
// vhimg[b][tile][h][c][lane=(q4,m)]        = V_hT[b][h][c*16+m][t0+q4*8..]
// rimg [b][tile][ck=f2*2+s][lane]          = k_pe octets (shared across heads)
// ---------------------------------------------------------------------------
__global__ __launch_bounds__(256) void prep_all(
    const ushort* __restrict__ K_h, const ushort* __restrict__ V_hT,
    const ushort* __restrict__ kv_h,
    uint4* __restrict__ khimg, uint4* __restrict__ vhimg,
    uint4* __restrict__ rimg)
{
    const int bid = blockIdx.x;
    if (bid < 4096) {
        const int g = bid * 256 + threadIdx.x;
        const int lane = g & 63, ck = (g >> 6) & 7, h = (g >> 9) & 15;
        const int tile = (g >> 13) & 63, b = g >> 19;
        const int m = lane & 15, q4 = lane >> 4, f = ck >> 1, s = ck & 1;
        const uint4 v = *(const uint4*)&K_h[
            ((long long)(b * S_ + tile * 32 + s * 16 + m)) * 2048 + h * 128 + f * 32 + q4 * 8];
        khimg[(((long long)(b * 64 + tile) * 16 + h) * 8 + ck) * 64 + lane] = v;
    } else if (bid < 8192) {
        const int g = (bid - 4096) * 256 + threadIdx.x;
        const int lane = g & 63, c = (g >> 6) & 7, h = (g >> 9) & 15;
        const int tile = (g >> 13) & 63, b = g >> 19;
        const int m = lane & 15, q4 = lane >> 4;
        const uint4 v = *(const uint4*)&V_hT[
            ((long long)((b * 16 + h) * 128 + c * 16 + m)) * 2048 + tile * 32 + q4 * 8];
        vhimg[(((long long)(b * 64 + tile) * 16 + h) * 8 + c) * 64 + lane] = v;
    } else {
        const int g = (bid - 8192) * 256 + threadIdx.x;
        const int lane = g & 63, ck = (g >> 6) & 3, tile = (g >> 8) & 63, b = g >> 14;
        const int m = lane & 15, q4 = lane >> 4, f2 = ck >> 1, s = ck & 1;
        const uint4 v = *(const uint4*)&kv_h[
            ((long long)(b * S_ + tile * 32 + s * 16 + m)) * 576 + 512 + f2 * 32 + q4 * 8];
        rimg[((long long)(b * 64 + tile) * 4 + ck) * 64 + lane] = v;
    }
}

// ---------------------------------------------------------------------------
// MFMA flash attention v12 = v11 compute + tile-parity split-T.
// Constant-shift softmax is associative -> split each paired block's tile
// list by parity (even/odd t): grid 8p x 16h x (2b x 2par) = 512 blocks =
// 2 blocks/CU (TLP restored), each block exactly 34 tiles (uniform), and all
// parity-q blocks of a head sweep the SAME absolute tile in lockstep (L2
// sharing). Blocks write unnormalized f32 partials (o,l); combine_kernel
// reduces. Block = 4 waves, 2 q-substrips/wave (A-frag reuse kept).
// ---------------------------------------------------------------------------
__global__ __launch_bounds__(256, 2) void attn_kernel(
    const ushort* __restrict__ q192,  // (B,S,H,192), q*scale*log2e
    const uint4*  __restrict__ khimg, // (B,64,16,8,64) K_h frag chunks
    const uint4*  __restrict__ rimg,  // (B,64,4,64)   k_pe frag chunks
    const uint4*  __restrict__ vhimg, // (B,64,16,8,64) V_h^T frag chunks
    float* __restrict__ part_o,       // (512*2,128,128) f32 partial O
    float* __restrict__ part_l)       // (512*2,128)     f32 partial l
{
    __shared__ uint buf[2][20 * 256];   // 2 x 20 KB

    const int p    = blockIdx.x;          // 0..7 (chunk pair)
    const int h    = blockIdx.y;          // 0..15
    const int zz   = blockIdx.z;          // 0..3
    const int b    = zz >> 1;
    const int par  = zz & 1;              // tile parity
    const int tid  = threadIdx.x;
    const int wid  = tid >> 6;            // 0..3
    const int lane = tid & 63;
    const int m    = lane & 15;
    const int q4   = lane >> 4;
    const bool odd = q4 & 1;

    auto stage = [&](int bs, int it) {
        const long long tb = (long long)(b * 64 + it);
        const uint4* kb = khimg + ((tb * 16 + h) * 8) * 64;
        const uint4* rb = rimg  + (tb * 4) * 64;
        const uint4* vb = vhimg + ((tb * 16 + h) * 8) * 64;
        ushort* l = (ushort*)&buf[bs][0];
        gld_lds16((const ushort*)(kb + (wid    ) * 64 + lane), l + (wid     ) * 512);
        gld_lds16((const ushort*)(kb + (wid + 4) * 64 + lane), l + (wid +  4) * 512);
        gld_lds16((const ushort*)(rb + (wid    ) * 64 + lane), l + (wid +  8) * 512);
        gld_lds16((const ushort*)(vb + (wid    ) * 64 + lane), l + (wid + 12) * 512);
        gld_lds16((const ushort*)(vb + (wid + 4) * 64 + lane), l + (wid + 16) * 512);
    };

    int cur = 0;
    for (int pass = 0; pass < 2; ++pass) {
        const int chunk = pass ? p : (15 - p);
        const int row0a = chunk * 128 + wid * 16;
        const int row0b = row0a + 64;
        const int sRa   = row0a + m;
        const int sRb   = row0b + m;

        // Q B-frags for both substrips: qf[f] = Q[sR][f*32 + q4*8 + j]
        U4 qfa[6], qfb[6];
        {
            const uint4* qpa = (const uint4*)(q192 + ((long long)(b * S_ + sRa) * H_ + h) * 192);
            const uint4* qpb = (const uint4*)(q192 + ((long long)(b * S_ + sRb) * H_ + h) * 192);
#pragma unroll
            for (int f = 0; f < 6; ++f) { qfa[f].u = qpa[f * 4 + q4]; qfb[f].u = qpb[f * 4 + q4]; }
        }

        f32x4 oA[8], oB[8];
#pragma unroll
        for (int c = 0; c < 8; ++c) {
            oA[c] = (f32x4){0.f, 0.f, 0.f, 0.f};
            oB[c] = (f32x4){0.f, 0.f, 0.f, 0.f};
        }
        float lA = 0.0f, lB = 0.0f;

        // softmax (exp2, diagonal-only masking) + P^T repack -> PV B-frag.
        auto softpack = [&](const f32x4 s0, const f32x4 s1, int t0v, int rw0,
                            float& lac) -> U4 {
            float p00, p01, p02, p03, p10, p11, p12, p13;
            if (t0v + 31 <= rw0) {            // fully unmasked tile
                p00 = exp2f(s0[0] - M0_); p01 = exp2f(s0[1] - M0_);
                p02 = exp2f(s0[2] - M0_); p03 = exp2f(s0[3] - M0_);
                p10 = exp2f(s1[0] - M0_); p11 = exp2f(s1[1] - M0_);
                p12 = exp2f(s1[2] - M0_); p13 = exp2f(s1[3] - M0_);
            } else {                          // diagonal tile
                const int sR = rw0 + m;
                const int tb0 = t0v + q4 * 4;
                const int tb1 = tb0 + 16;
                p00 = (tb0 + 0 <= sR) ? exp2f(s0[0] - M0_) : 0.0f;
                p01 = (tb0 + 1 <= sR) ? exp2f(s0[1] - M0_) : 0.0f;
                p02 = (tb0 + 2 <= sR) ? exp2f(s0[2] - M0_) : 0.0f;
                p03 = (tb0 + 3 <= sR) ? exp2f(s0[3] - M0_) : 0.0f;
                p10 = (tb1 + 0 <= sR) ? exp2f(s1[0] - M0_) : 0.0f;
                p11 = (tb1 + 1 <= sR) ? exp2f(s1[1] - M0_) : 0.0f;
                p12 = (tb1 + 2 <= sR) ? exp2f(s1[2] - M0_) : 0.0f;
                p13 = (tb1 + 3 <= sR) ? exp2f(s1[3] - M0_) : 0.0f;
            }
            lac += (p00 + p01) + (p02 + p03) + (p10 + p11) + (p12 + p13);
            uint X0 = cvtpk(p00, p01), X1 = cvtpk(p02, p03);
            uint Y0 = cvtpk(p10, p11), Y1 = cvtpk(p12, p13);
            asm("v_permlane32_swap_b32 %0, %1" : "+v"(X0), "+v"(Y0));
            asm("v_permlane32_swap_b32 %0, %1" : "+v"(X1), "+v"(Y1));
            uint u0 = odd ? X0 : Y0;          // send what the partner needs
            uint u1 = odd ? X1 : Y1;
            uint w0 = (uint)__builtin_amdgcn_ds_swizzle((int)u0, 0x401F); // xor 16
            uint w1 = (uint)__builtin_amdgcn_ds_swizzle((int)u1, 0x401F);
            U4 bb;
            bb.u.x = odd ? w0 : X0;
            bb.u.y = odd ? w1 : X1;
            bb.u.z = odd ? Y0 : w0;
            bb.u.w = odd ? Y1 : w1;
            return bb;
        };

        const int nT2 = 2 * chunk + 2;        // parity-tiles in this pass
        __syncthreads();                 // all reads of prev pass's LDS done
        stage(cur, par);

        for (int v = 0; v < nT2; ++v) {
            const int it = 2 * v + par;
            const int t0 = it * 32;
            __syncthreads();             // drains vmcnt(0): buf[cur] staged
            if (v + 1 < nT2) stage(cur ^ 1, it + 2);   // overlap under compute
            __builtin_amdgcn_sched_barrier(0);

            const uint* bb0 = &buf[cur][0];
            const int abase = lane * 4;
            const bool liveB = (t0 <= row0b + 15);
            const bool liveA = (t0 <= row0a + 15);
            const bool twoA  = (t0 < row0a);
            const bool twoB  = (t0 < row0b);

            if (liveB) {
                f32x4 sA0 = (f32x4){0.f,0.f,0.f,0.f}, sA1 = (f32x4){0.f,0.f,0.f,0.f};
                f32x4 sB0 = (f32x4){0.f,0.f,0.f,0.f}, sB1 = (f32x4){0.f,0.f,0.f,0.f};

                if (twoA) {     // both substrips full: 4 MFMAs per read-pair
#pragma unroll
                    for (int f = 0; f < 6; ++f) {
                        const int ck = (f < 4) ? f * 2 : (f - 4) * 2 + 8;
                        U4 a0, a1;
                        a0.u = *(const uint4*)&bb0[ck * 256 + abase];
                        a1.u = *(const uint4*)&bb0[(ck + 1) * 256 + abase];
                        sA0 = __builtin_amdgcn_mfma_f32_16x16x32_bf16(a0.v, qfa[f].v, sA0, 0, 0, 0);
                        sB0 = __builtin_amdgcn_mfma_f32_16x16x32_bf16(a0.v, qfb[f].v, sB0, 0, 0, 0);
                        sA1 = __builtin_amdgcn_mfma_f32_16x16x32_bf16(a1.v, qfa[f].v, sA1, 0, 0, 0);
                        sB1 = __builtin_amdgcn_mfma_f32_16x16x32_bf16(a1.v, qfb[f].v, sB1, 0, 0, 0);
                    }
                } else {        // A diagonal/dead; B full or diagonal
#pragma unroll
                    for (int f = 0; f < 6; ++f) {
                        const int ck = (f < 4) ? f * 2 : (f - 4) * 2 + 8;
                        U4 a0;
                        a0.u = *(const uint4*)&bb0[ck * 256 + abase];
                        if (liveA)
                            sA0 = __builtin_amdgcn_mfma_f32_16x16x32_bf16(a0.v, qfa[f].v, sA0, 0, 0, 0);
                        sB0 = __builtin_amdgcn_mfma_f32_16x16x32_bf16(a0.v, qfb[f].v, sB0, 0, 0, 0);
                        if (twoB) {
                            U4 a1;
                            a1.u = *(const uint4*)&bb0[(ck + 1) * 256 + abase];
                            sB1 = __builtin_amdgcn_mfma_f32_16x16x32_bf16(a1.v, qfb[f].v, sB1, 0, 0, 0);
                        }
                    }
                }

                U4 bbB = softpack(sB0, sB1, t0, row0b, lB);
                if (liveA) {
                    U4 bbA = softpack(sA0, sA1, t0, row0a, lA);
#pragma unroll
                    for (int c = 0; c < 8; ++c) {
                        U4 av; av.u = *(const uint4*)&bb0[(12 + c) * 256 + abase];
                        oB[c] = __builtin_amdgcn_mfma_f32_16x16x32_bf16(av.v, bbB.v, oB[c], 0, 0, 0);
                        oA[c] = __builtin_amdgcn_mfma_f32_16x16x32_bf16(av.v, bbA.v, oA[c], 0, 0, 0);
                    }
                } else {
#pragma unroll
                    for (int c = 0; c < 8; ++c) {
                        U4 av; av.u = *(const uint4*)&bb0[(12 + c) * 256 + abase];
                        oB[c] = __builtin_amdgcn_mfma_f32_16x16x32_bf16(av.v, bbB.v, oB[c], 0, 0, 0);
                    }
                }
            }
            cur ^= 1;
        }

        // ---- epilogue: reduce l across q4 groups; store f32 partials
        lA += __shfl_xor(lA, 16, 64);
        lA += __shfl_xor(lA, 32, 64);
        lB += __shfl_xor(lB, 16, 64);
        lB += __shfl_xor(lB, 32, 64);

        const int cid  = (b * 16 + h) * 16 + chunk;
        const int slot = cid * 2 + par;
        float* po = part_o + (long long)slot * 16384;
        const int rA = wid * 16 + m;
        const int rB = rA + 64;
#pragma unroll
        for (int c = 0; c < 8; ++c) {
            *(f32x4*)&po[rA * 128 + c * 16 + q4 * 4] = oA[c];
            *(f32x4*)&po[rB * 128 + c * 16 + q4 * 4] = oB[c];
        }
        if (q4 == 0) {
            part_l[slot * 128 + rA] = lA;
            part_l[slot * 128 + rB] = lB;
        }
    }
}

// ---------------------------------------------------------------------------
// Combine the two parity partials: o = (o0+o1)/(l0+l1) -> o_h bf16.
// ---------------------------------------------------------------------------
__global__ __launch_bounds__(256) void combine_kernel(
    const float* __restrict__ part_o, const float* __restrict__ part_l,
    ushort* __restrict__ o_h)
{
    const int idx = blockIdx.x * 256 + threadIdx.x;    // 0..2,097,151
    const int d4  = (idx & 31) * 4;                    // 0..124
    const int r   = (idx >> 5) & 127;
    const int cid = idx >> 12;                         // 0..511
    const int chunk = cid & 15, h = (cid >> 4) & 15, b = cid >> 8;
    const long long s0 = (long long)(cid * 2) * 16384 + r * 128 + d4;
    float4 a = *(const float4*)&part_o[s0];
    float4 c = *(const float4*)&part_o[s0 + 16384];
    const float l = part_l[cid * 256 + r] + part_l[cid * 256 + 128 + r];
    const float inv = 1.0f / l;
    uint2 pk;
    pk.x = cvtpk((a.x + c.x) * inv, (a.y + c.y) * inv);
    pk.y = cvtpk((a.z + c.z) * inv, (a.w + c.w) * inv);
    const int s = chunk * 128 + r;
    *(uint2*)&o_h[(((long long)(b * S_ + s)) * H_ + h) * 128 + d4] = pk;
}

// ---------------------------------------------------------------------------
extern "C" void kernel_launch(void* const* d_in, const int* in_sizes, int n_in,
                              void* d_out, int out_size, void* d_ws, size_t ws_size,
                              hipStream_t stream)
{
    const float* x         = (const float*)d_in[0];
    const float* freqs     = (const float*)d_in[1];
    // d_in[2] = mask (unused: causal handled analytically)
    const float* wq_w      = (const float*)d_in[3];
    const float* wq_b      = (const float*)d_in[4];
    const float* wkv_a_w   = (const float*)d_in[5];
    const float* wkv_a_b   = (const float*)d_in[6];
    const float* kv_norm_w = (const float*)d_in[7];
    const float* wkv_b_w   = (const float*)d_in[8];
    const float* wo_w      = (const float*)d_in[9];
    const float* wo_b      = (const float*)d_in[10];
    float* out = (float*)d_out;

    // ---- workspace layout (~173 MiB): persistent region + overlaid scratch
    char* w = (char*)d_ws;
    ushort* wo_bf   = (ushort*)w;  w += 8388608;    // (2048,2048) bf16
    uint4*  khimg   = (uint4*)w;   w += 16777216;   // (B,64,16,8,64)
    uint4*  vhimg   = (uint4*)w;   w += 16777216;   // (B,64,16,8,64)
    uint4*  rimg    = (uint4*)w;   w += 524288;     // (B,64,4,64)
    ushort* q192    = (ushort*)w;  w += 25165824;   // (4096,16,192) bf16
    ushort* o_h     = (ushort*)w;  w += 16777216;   // (4096,16,128) bf16
    char* SCR = w;                                  // scratch: 96,993,280 B
    // phase 1 (conv + GEMM1/2):
    ushort* x_bf    = (ushort*)(SCR);               // 16,777,216
    ushort* wq_bf   = (ushort*)(SCR + 16777216);    // 12,582,912
    ushort* wkva_bf = (ushort*)(SCR + 29360128);    //  2,621,440
    ushort* wkvbK   = (ushort*)(SCR + 31981568);    //  2,097,152 (live thru step5)
    ushort* wkvbV   = (ushort*)(SCR + 34078720);    //  2,097,152 (live thru step5)
    float*  kv_raw  = (float*)(SCR + 36175872);     // 10,485,760 (dead after step4)
    float*  q_raw   = (float*)(SCR + 46661632);     // 50,331,648 (dead after step3)
    // phase 2 overlays (all prior occupants dead):
    ushort* kv_h    = (ushort*)(SCR);               //  4,718,592 (over x_bf)
    ushort* K_h     = (ushort*)(SCR + 4718592);     // 16,777,216 (over x/wq tails)
    ushort* V_hT    = (ushort*)(SCR + 36175872);    // 16,777,216 (over kv_raw+q_raw)
    // phase 3 overlays (attn partials; everything above dead by attn):
    float*  part_o  = (float*)(SCR);                // 67,108,864
    float*  part_l  = (float*)(SCR + 67108864);     //    524,288

    dim3 blk(256);

    // 0) all f32->bf16 conversions, one launch
    conv_all<<<dim3(21760), blk, 0, stream>>>(
        x, wq_w, wkv_a_w, wo_w, wkv_b_w,
        x_bf, wq_bf, wkva_bf, wo_bf, wkvbK, wkvbV);

    // 1) q_raw = x @ wq_w^T + wq_b
    mgemm<false><<<dim3(24, 32, 1), blk, 0, stream>>>(
        x_bf, 2048, 0LL, 0LL, wq_bf, 2048, 0LL, 0LL, wq_b, 1.0f,
        q_raw, 3072, 0LL, 0LL, 2048, 1);

    // 2) kv_raw = x @ wkv_a_w^T (N=640 padded; bias folded into kv_post)
    mgemm<false><<<dim3(5, 32, 1), blk, 0, stream>>>(
        x_bf, 2048, 0LL, 0LL, wkva_bf, 2048, 0LL, 0LL, nullptr, 1.0f,
        kv_raw, 640, 0LL, 0LL, 2048, 1);

    // 3) q192 = [q_nope, rope(q_pe)] * scale * log2e, bf16
    qprep<<<dim3(12288), blk, 0, stream>>>(q_raw, freqs, q192);

    // 4) bias + rmsnorm + rope -> kv_h
    kv_post_kernel<<<dim3(4096), dim3(64), 0, stream>>>(
        kv_raw, wkv_a_b, kv_norm_w, freqs, kv_h);

    // 5) per-head K/V projections, batched over (h,b) via 2-axis z:
    //    K_h[b,t,h,:]  = kv_proj @ wkv_b[h,:128]^T
    mgemm<true><<<dim3(1, 16, 32), blk, 0, stream>>>(
        kv_h, 576, 0LL, (long long)S_ * 576,
        wkvbK, 512, 65536LL, 0LL, nullptr, 1.0f,
        K_h, 2048, 128LL, (long long)S_ * 2048, 512, 16);
    //    V_hT[b,h,d,t] = wkv_b[h,128:] @ kv_proj^T
    mgemm<true><<<dim3(16, 1, 32), blk, 0, stream>>>(
        wkvbV, 512, 65536LL, 0LL,
        kv_h, 576, 0LL, (long long)S_ * 576, nullptr, 1.0f,
        V_hT, 2048, 262144LL, 4194304LL, 512, 16);

    // 6) fragment images, one launch
    prep_all<<<dim3(8320), blk, 0, stream>>>(K_h, V_hT, kv_h, khimg, vhimg, rimg);

    // 7) MFMA flash attention v12 (split-T) -> f32 partials
    attn_kernel<<<dim3(8, 16, 4), blk, 0, stream>>>(
        q192, khimg, rimg, vhimg, part_o, part_l);

    // 7b) combine parity partials -> o_h bf16
    combine_kernel<<<dim3(8192), blk, 0, stream>>>(part_o, part_l, o_h);

    // 8) out = o_h @ wo_w^T + wo_b
    mgemm<false><<<dim3(16, 32, 1), blk, 0, stream>>>(
        o_h, 2048, 0LL, 0LL, wo_bf, 2048, 0LL, 0LL, wo_b, 1.0f,
        out, 2048, 0LL, 0LL, 2048, 1);
}

// Round 6
// 443.556 us; speedup vs baseline: 1.7057x; 1.0506x over previous
//
#include <hip/hip_runtime.h>
#include <hip/hip_bf16.h>
#include <math.h>

// MLA forward: B=2, S=2048, D=2048, H=16, KV_RANK=512, NOPE=128, ROPE=64
#define B_ 2
#define S_ 2048
#define H_ 16
#define SCALE_ 0.07216878364870323f   // 192^-0.5
#define SL2_ (0.07216878364870323f * 1.4426950408889634f)  // scale * log2(e)
#define EPS_ 1.1920929e-07f
#define M0_ 8.0f                      // constant exp2 shift (cancels in o/l)

typedef __attribute__((ext_vector_type(8))) short bf16x8;
typedef __attribute__((ext_vector_type(4))) float f32x4;
union U4 { uint4 u; bf16x8 v; f32x4 f; };

__device__ __forceinline__ uint bfbits(float x) {   // f32 -> bf16 bits, RNE
    uint u = __float_as_uint(x);
    return (u + 0x7fffu + ((u >> 16) & 1u)) >> 16;
}
__device__ __forceinline__ uint pack2bf(float a, float b) {
    return bfbits(a) | (bfbits(b) << 16);
}
__device__ __forceinline__ uint cvtpk(float a, float b) {  // 1 VALU op, RNE
    uint r;
    asm("v_cvt_pk_bf16_f32 %0, %1, %2" : "=v"(r) : "v"(a), "v"(b));
    return r;
}
__device__ __forceinline__ void gld_lds16(const ushort* g, ushort* l) {
    // async global->LDS DMA, 16B/lane; LDS dest = wave-uniform base + lane*16
    __builtin_amdgcn_global_load_lds(
        (const __attribute__((address_space(1))) uint*)g,
        (__attribute__((address_space(3))) uint*)l, 16, 0, 0);
}

// ---------------------------------------------------------------------------
// MFMA bf16 GEMM (NT): C[m,n] = scale * sum_k A[m,k]*B[n,k] + bias[n]
// 128x128 tile, BK=32, 256 thr (4 waves 2x2 of 64x64), 16x16x32 MFMA.
// z decomposed as z1 = z % zDiv (stride *Off1), z2 = z / zDiv (stride *Off2).
// XCD-bijective tile swizzle when (gx*gy)%8==0 (L2 panel locality).
// OM: 0 = f32 linear, 2 = khimg layout (z1=h,z2=b), 3 = vhimg layout.
// ---------------------------------------------------------------------------
template<int OM>
__global__ __launch_bounds__(256) void mgemm(
    const ushort* __restrict__ A, int lda, long long aOff1, long long aOff2,
    const ushort* __restrict__ Bm, int ldb, long long bOff1, long long bOff2,
    const float* __restrict__ bias, float scale,
    void* __restrict__ Cv, int ldc, long long cOff1, long long cOff2,
    int K, int zDiv)
{
    __shared__ ushort As[128 * 32];
    __shared__ ushort Bs[128 * 32];

    const int z = blockIdx.z;
    const int z1 = z % zDiv, z2 = z / zDiv;
    A  += z1 * aOff1 + z2 * aOff2;
    Bm += z1 * bOff1 + z2 * bOff2;
    const long long cBase = z1 * cOff1 + z2 * cOff2;

    // XCD-bijective swizzle over the (x,y) tile space
    int bx = blockIdx.x, by = blockIdx.y;
    {
        const int gx = gridDim.x, total = gx * gridDim.y;
        if ((total & 7) == 0) {
            const int flat = bx + gx * by;
            const int nx = total >> 3;
            const int flat2 = (flat & 7) * nx + (flat >> 3);
            bx = flat2 % gx;
            by = flat2 / gx;
        }
    }
    const int n0 = bx * 128;
    const int m0 = by * 128;
    const int tid = threadIdx.x;
    const int w   = tid >> 6;
    const int l   = tid & 63;
    const int m   = l & 15;
    const int q4  = l >> 4;
    const int mw  = (w & 1) * 64;
    const int nw  = (w >> 1) * 64;
    const int sr  = l >> 2;
    const int sc  = l & 3;

    f32x4 acc[4][4];
#pragma unroll
    for (int i = 0; i < 4; ++i)
#pragma unroll
        for (int j = 0; j < 4; ++j) acc[i][j] = (f32x4){0.f, 0.f, 0.f, 0.f};

    for (int k0 = 0; k0 < K; k0 += 32) {
#pragma unroll
        for (int jj = 0; jj < 2; ++jj) {
            const int slot = w * 2 + jj;
            const int row  = slot * 16 + sr;
            const int g    = sc ^ ((row >> 1) & 3);
            gld_lds16(&A[(long long)(m0 + row) * lda + k0 + g * 8], &As[slot * 512]);
            gld_lds16(&Bm[(long long)(n0 + row) * ldb + k0 + g * 8], &Bs[slot * 512]);
        }
        __syncthreads();

        U4 af[4], bf[4];
#pragma unroll
        for (int i = 0; i < 4; ++i) {
            const int ra = mw + i * 16 + m;
            af[i].u = *(const uint4*)&As[ra * 32 + (q4 ^ ((ra >> 1) & 3)) * 8];
            const int rb = nw + i * 16 + m;
            bf[i].u = *(const uint4*)&Bs[rb * 32 + (q4 ^ ((rb >> 1) & 3)) * 8];
        }
#pragma unroll
        for (int i = 0; i < 4; ++i)
#pragma unroll
            for (int j = 0; j < 4; ++j)
                acc[i][j] = __builtin_amdgcn_mfma_f32_16x16x32_bf16(
                    af[i].v, bf[j].v, acc[i][j], 0, 0, 0);
        __syncthreads();
    }

#pragma unroll
    for (int j = 0; j < 4; ++j) {
        const int cn = n0 + nw + j * 16 + m;
        const float bv = bias ? bias[cn] : 0.0f;
#pragma unroll
        for (int i = 0; i < 4; ++i) {
            const int rw = m0 + mw + i * 16 + q4 * 4;
#pragma unroll
            for (int r = 0; r < 4; ++r) {
                const float val = acc[i][j][r] * scale + bv;
                if (OM == 0) {
                    ((float*)Cv)[cBase + (long long)(rw + r) * ldc + cn] = val;
                } else if (OM == 2) {
                    // khimg[b][t>>5][h][(d>>5)*2 + ((t>>4)&1)][(d>>3)&3][t&15][d&7]
                    const int t = rw + r, d = cn;
                    const long long idx =
                        ((((long long)(z2 * 64 + (t >> 5)) * 16 + z1) * 8
                          + (d >> 5) * 2 + ((t >> 4) & 1)) * 64
                         + ((d >> 3) & 3) * 16 + (t & 15)) * 8 + (d & 7);
                    ((ushort*)Cv)[idx] = (ushort)bfbits(val);
                } else {
                    // vhimg[b][t>>5][h][d>>4][(t>>3)&3][d&15][t&7]
                    const int d = rw + r, t = cn;
                    const long long idx =
                        ((((long long)(z2 * 64 + (t >> 5)) * 16 + z1) * 8
                          + (d >> 4)) * 64
                         + ((t >> 3) & 3) * 16 + (d & 15)) * 8 + (t & 7);
                    ((ushort*)Cv)[idx] = (ushort)bfbits(val);
                }
            }
        }
    }
}

// ---------------------------------------------------------------------------
// Fused f32 -> bf16 conversions (one launch).
// ---------------------------------------------------------------------------
__global__ __launch_bounds__(256) void conv_all(
    const float* __restrict__ x, const float* __restrict__ wq,
    const float* __restrict__ wkva, const float* __restrict__ wo,
    const float* __restrict__ wkvb,
    ushort* __restrict__ x_bf, ushort* __restrict__ wq_bf,
    ushort* __restrict__ wkva_bf, ushort* __restrict__ wo_bf,
    ushort* __restrict__ wkvbK, ushort* __restrict__ wkvbV)
{
    const int bid = blockIdx.x;
    const int tid = threadIdx.x;
    if (bid < 8192) {                       // x: (4096,2048)
        const long long i = ((long long)bid * 256 + tid) * 4;
        float4 v = *(const float4*)&x[i];
        uint2 p; p.x = pack2bf(v.x, v.y); p.y = pack2bf(v.z, v.w);
        *(uint2*)&x_bf[i] = p;
    } else if (bid < 14336) {               // wq: (3072,2048)
        const long long i = ((long long)(bid - 8192) * 256 + tid) * 4;
        float4 v = *(const float4*)&wq[i];
        uint2 p; p.x = pack2bf(v.x, v.y); p.y = pack2bf(v.z, v.w);
        *(uint2*)&wq_bf[i] = p;
    } else if (bid < 15616) {               // wkva: (576,2048) pad to 640
        const int i = ((bid - 14336) * 256 + tid) * 4;
        const int r = i >> 11;
        uint2 p = make_uint2(0u, 0u);
        if (r < 576) {
            float4 v = *(const float4*)&wkva[i];
            p.x = pack2bf(v.x, v.y); p.y = pack2bf(v.z, v.w);
        }
        *(uint2*)&wkva_bf[i] = p;
    } else if (bid < 19712) {               // wo: (2048,2048)
        const long long i = ((long long)(bid - 15616) * 256 + tid) * 4;
        float4 v = *(const float4*)&wo[i];
        uint2 p; p.x = pack2bf(v.x, v.y); p.y = pack2bf(v.z, v.w);
        *(uint2*)&wo_bf[i] = p;
    } else if (bid < 20736) {               // wkv_b rows [0:128) per head -> K
        const int i = ((bid - 19712) * 256 + tid) * 4;
        const int h = i >> 16, rem = i & 65535;
        float4 v = *(const float4*)&wkvb[((long long)(h * 256)) * 512 + rem];
        uint2 p; p.x = pack2bf(v.x, v.y); p.y = pack2bf(v.z, v.w);
        *(uint2*)&wkvbK[i] = p;
    } else {                                // wkv_b rows [128:256) per head -> V
        const int i = ((bid - 20736) * 256 + tid) * 4;
        const int h = i >> 16, rem = i & 65535;
        float4 v = *(const float4*)&wkvb[((long long)(h * 256 + 128)) * 512 + rem];
        uint2 p; p.x = pack2bf(v.x, v.y); p.y = pack2bf(v.z, v.w);
        *(uint2*)&wkvbV[i] = p;
    }
}

// ---------------------------------------------------------------------------
// Fused q prep: q192 = [q_nope * SL2, rope(q_pe) * SL2] bf16 (one read pass).
// ---------------------------------------------------------------------------
__global__ __launch_bounds__(256) void qprep(
    const float* __restrict__ q_raw, const float* __restrict__ freqs,
    ushort* __restrict__ q192)
{
    const int idx = blockIdx.x * 256 + threadIdx.x;   // 0..3145727
    const int row = idx / 48;        // (b*S+s)*16+h
    const int c4  = idx % 48;
    const int bs = row >> 4, h = row & 15;
    const float* src = q_raw + (long long)bs * 3072 + h * 192;
    if (c4 < 32) {
        const int d = c4 * 4;
        float4 v = *(const float4*)&src[d];
        uint2 p;
        p.x = pack2bf(v.x * SL2_, v.y * SL2_);
        p.y = pack2bf(v.z * SL2_, v.w * SL2_);
        *(uint2*)&q192[(long long)row * 192 + d] = p;
    } else {
        const int j = c4 - 32;       // 0..15, two rope pairs
        const int s = bs & 2047;
        const float f0 = freqs[s * 32 + j * 2];
        const float f1 = freqs[s * 32 + j * 2 + 1];
        float c0, s0, c1, s1;
        __sincosf(f0, &s0, &c0);
        __sincosf(f1, &s1, &c1);
        float4 v = *(const float4*)&src[128 + j * 4];
        uint2 p;
        p.x = pack2bf((v.x * c0 - v.y * s0) * SL2_, (v.x * s0 + v.y * c0) * SL2_);
        p.y = pack2bf((v.z * c1 - v.w * s1) * SL2_, (v.z * s1 + v.w * c1) * SL2_);
        *(uint2*)&q192[(long long)row * 192 + 128 + j * 4] = p;
    }
}

// ---------------------------------------------------------------------------
// kv post: bias add + rmsnorm(kv[:512]) -> kv_h bf16; rope(kv[512:576])
// written DIRECTLY in rimg fragment layout (kills prep pass).
// ---------------------------------------------------------------------------
__global__ __launch_bounds__(64) void kv_post_kernel(
    const float* __restrict__ kv_raw, const float* __restrict__ bias,
    const float* __restrict__ w, const float* __restrict__ freqs,
    ushort* __restrict__ kv_h, uint* __restrict__ rimg)
{
    const int bs = blockIdx.x;
    const int lane = threadIdx.x;
    const float* src = kv_raw + (long long)bs * 640;
    ushort* dst = kv_h + (long long)bs * 576;

    const int c = 4 * lane;
    float4 v0 = *(const float4*)&src[c];
    float4 v1 = *(const float4*)&src[256 + c];
    float4 b0 = *(const float4*)&bias[c];
    float4 b1 = *(const float4*)&bias[256 + c];
    v0.x += b0.x; v0.y += b0.y; v0.z += b0.z; v0.w += b0.w;
    v1.x += b1.x; v1.y += b1.y; v1.z += b1.z; v1.w += b1.w;
    float ss = v0.x * v0.x + v0.y * v0.y + v0.z * v0.z + v0.w * v0.w +
               v1.x * v1.x + v1.y * v1.y + v1.z * v1.z + v1.w * v1.w;
#pragma unroll
    for (int o = 32; o; o >>= 1) ss += __shfl_xor(ss, o, 64);
    const float rs = rsqrtf(ss * (1.0f / 512.0f) + EPS_);

    float4 w0 = *(const float4*)&w[c];
    float4 w1 = *(const float4*)&w[256 + c];
    uint2 p0, p1;
    p0.x = pack2bf(v0.x * rs * w0.x, v0.y * rs * w0.y);
    p0.y = pack2bf(v0.z * rs * w0.z, v0.w * rs * w0.w);
    p1.x = pack2bf(v1.x * rs * w1.x, v1.y * rs * w1.y);
    p1.y = pack2bf(v1.z * rs * w1.z, v1.w * rs * w1.w);
    *(uint2*)&dst[c] = p0;
    *(uint2*)&dst[256 + c] = p1;

    if (lane < 32) {
        const int b = bs >> 11, s = bs & 2047;
        const int j = lane;
        const float f = freqs[s * 32 + j];
        float cs, sn;
        __sincosf(f, &sn, &cs);
        const float a  = src[512 + 2 * j]     + bias[512 + 2 * j];
        const float b2 = src[512 + 2 * j + 1] + bias[512 + 2 * j + 1];
        const uint p = pack2bf(a * cs - b2 * sn, a * sn + b2 * cs);
        // rimg[b][s>>5][(j>>4)*2 + ((s>>4)&1)][lane=((j>>2)&3)*16 + (s&15)][j&3]
        const long long idx =
            (((long long)(b * 64 + (s >> 5)) * 4 + (j >> 4) * 2 + ((s >> 4) & 1)) * 64
             + ((j >> 2) & 3) * 16 + (s & 15)) * 4 + (j & 3);
        rimg[idx] = p;
    }
}

// ---------------------------------------------------------------------------
// MFMA flash attention v13 = v12 + XCD-grouped grid: all 16 blocks of one
// (b,h) share linear id mod 8 -> same XCD -> image set L2-resident per XCD.
// Grid (32 = h + 16b, 8 = pair, 2 = parity) = 512 blocks = 2/CU, uniform
// 34 tiles each; f32 partials + combine (split-T, constant-shift softmax).
// ---------------------------------------------------------------------------
__global__ __launch_bounds__(256, 2) void attn_kernel(
    const ushort* __restrict__ q192,  // (B,S,H,192), q*scale*log2e
    const uint4*  __restrict__ khimg, // (B,64,16,8,64) K_h frag chunks
    const uint4*  __restrict__ rimg,  // (B,64,4,64)   k_pe frag chunks
    const uint4*  __restrict__ vhimg, // (B,64,16,8,64) V_h^T frag chunks
    float* __restrict__ part_o,       // (512*2,128,128) f32 partial O
    float* __restrict__ part_l)       // (512*2,128)     f32 partial l
{
    __shared__ uint buf[2][20 * 256];   // 2 x 20 KB

    const int hb   = blockIdx.x;          // 0..31: h + 16*b (XCD = hb & 7)
    const int h    = hb & 15;
    const int b    = hb >> 4;
    const int p    = blockIdx.y;          // 0..7 (chunk pair)
    const int par  = blockIdx.z;          // tile parity
    const int tid  = threadIdx.x;
    const int wid  = tid >> 6;            // 0..3
    const int lane = tid & 63;
    const int m    = lane & 15;
    const int q4   = lane >> 4;
    const bool odd = q4 & 1;

    auto stage = [&](int bs, int it) {
        const long long tb = (long long)(b * 64 + it);
        const uint4* kb = khimg + ((tb * 16 + h) * 8) * 64;
        const uint4* rb = rimg  + (tb * 4) * 64;
        const uint4* vb = vhimg + ((tb * 16 + h) * 8) * 64;
        ushort* l = (ushort*)&buf[bs][0];
        gld_lds16((const ushort*)(kb + (wid    ) * 64 + lane), l + (wid     ) * 512);
        gld_lds16((const ushort*)(kb + (wid + 4) * 64 + lane), l + (wid +  4) * 512);
        gld_lds16((const ushort*)(rb + (wid    ) * 64 + lane), l + (wid +  8) * 512);
        gld_lds16((const ushort*)(vb + (wid    ) * 64 + lane), l + (wid + 12) * 512);
        gld_lds16((const ushort*)(vb + (wid + 4) * 64 + lane), l + (wid + 16) * 512);
    };

    int cur = 0;
    for (int pass = 0; pass < 2; ++pass) {
        const int chunk = pass ? p : (15 - p);
        const int row0a = chunk * 128 + wid * 16;
        const int row0b = row0a + 64;
        const int sRa   = row0a + m;
        const int sRb   = row0b + m;

        // Q B-frags for both substrips: qf[f] = Q[sR][f*32 + q4*8 + j]
        U4 qfa[6], qfb[6];
        {
            const uint4* qpa = (const uint4*)(q192 + ((long long)(b * S_ + sRa) * H_ + h) * 192);
            const uint4* qpb = (const uint4*)(q192 + ((long long)(b * S_ + sRb) * H_ + h) * 192);
#pragma unroll
            for (int f = 0; f < 6; ++f) { qfa[f].u = qpa[f * 4 + q4]; qfb[f].u = qpb[f * 4 + q4]; }
        }

        f32x4 oA[8], oB[8];
#pragma unroll
        for (int c = 0; c < 8; ++c) {
            oA[c] = (f32x4){0.f, 0.f, 0.f, 0.f};
            oB[c] = (f32x4){0.f, 0.f, 0.f, 0.f};
        }
        float lA = 0.0f, lB = 0.0f;

        // softmax (exp2, diagonal-only masking) + P^T repack -> PV B-frag.
        auto softpack = [&](const f32x4 s0, const f32x4 s1, int t0v, int rw0,
                            float& lac) -> U4 {
            float p00, p01, p02, p03, p10, p11, p12, p13;
            if (t0v + 31 <= rw0) {            // fully unmasked tile
                p00 = exp2f(s0[0] - M0_); p01 = exp2f(s0[1] - M0_);
                p02 = exp2f(s0[2] - M0_); p03 = exp2f(s0[3] - M0_);
                p10 = exp2f(s1[0] - M0_); p11 = exp2f(s1[1] - M0_);
                p12 = exp2f(s1[2] - M0_); p13 = exp2f(s1[3] - M0_);
            } else {                          // diagonal tile
                const int sR = rw0 + m;
                const int tb0 = t0v + q4 * 4;
                const int tb1 = tb0 + 16;
                p00 = (tb0 + 0 <= sR) ? exp2f(s0[0] - M0_) : 0.0f;
                p01 = (tb0 + 1 <= sR) ? exp2f(s0[1] - M0_) : 0.0f;
                p02 = (tb0 + 2 <= sR) ? exp2f(s0[2] - M0_) : 0.0f;
                p03 = (tb0 + 3 <= sR) ? exp2f(s0[3] - M0_) : 0.0f;
                p10 = (tb1 + 0 <= sR) ? exp2f(s1[0] - M0_) : 0.0f;
                p11 = (tb1 + 1 <= sR) ? exp2f(s1[1] - M0_) : 0.0f;
                p12 = (tb1 + 2 <= sR) ? exp2f(s1[2] - M0_) : 0.0f;
                p13 = (tb1 + 3 <= sR) ? exp2f(s1[3] - M0_) : 0.0f;
            }
            lac += (p00 + p01) + (p02 + p03) + (p10 + p11) + (p12 + p13);
            uint X0 = cvtpk(p00, p01), X1 = cvtpk(p02, p03);
            uint Y0 = cvtpk(p10, p11), Y1 = cvtpk(p12, p13);
            asm("v_permlane32_swap_b32 %0, %1" : "+v"(X0), "+v"(Y0));
            asm("v_permlane32_swap_b32 %0, %1" : "+v"(X1), "+v"(Y1));
            uint u0 = odd ? X0 : Y0;          // send what the partner needs
            uint u1 = odd ? X1 : Y1;
            uint w0 = (uint)__builtin_amdgcn_ds_swizzle((int)u0, 0x401F); // xor 16
            uint w1 = (uint)__builtin_amdgcn_ds_swizzle((int)u1, 0x401F);
            U4 bb;
            bb.u.x = odd ? w0 : X0;
            bb.u.y = odd ? w1 : X1;
            bb.u.z = odd ? Y0 : w0;
            bb.u.w = odd ? Y1 : w1;
            return bb;
        };

        const int nT2 = 2 * chunk + 2;        // parity-tiles in this pass
        __syncthreads();                 // all reads of prev pass's LDS done
        stage(cur, par);

        for (int v = 0; v < nT2; ++v) {
            const int it = 2 * v + par;
            const int t0 = it * 32;
            __syncthreads();             // drains vmcnt(0): buf[cur] staged
            if (v + 1 < nT2) stage(cur ^ 1, it + 2);   // overlap under compute
            __builtin_amdgcn_sched_barrier(0);

            const uint* bb0 = &buf[cur][0];
            const int abase = lane * 4;
            const bool liveB = (t0 <= row0b + 15);
            const bool liveA = (t0 <= row0a + 15);
            const bool twoA  = (t0 < row0a);
            const bool twoB  = (t0 < row0b);

            if (liveB) {
                f32x4 sA0 = (f32x4){0.f,0.f,0.f,0.f}, sA1 = (f32x4){0.f,0.f,0.f,0.f};
                f32x4 sB0 = (f32x4){0.f,0.f,0.f,0.f}, sB1 = (f32x4){0.f,0.f,0.f,0.f};

                if (twoA) {     // both substrips full: 4 MFMAs per read-pair
#pragma unroll
                    for (int f = 0; f < 6; ++f) {
                        const int ck = (f < 4) ? f * 2 : (f - 4) * 2 + 8;
                        U4 a0, a1;
                        a0.u = *(const uint4*)&bb0[ck * 256 + abase];
                        a1.u = *(const uint4*)&bb0[(ck + 1) * 256 + abase];
                        sA0 = __builtin_amdgcn_mfma_f32_16x16x32_bf16(a0.v, qfa[f].v, sA0, 0, 0, 0);
                        sB0 = __builtin_amdgcn_mfma_f32_16x16x32_bf16(a0.v, qfb[f].v, sB0, 0, 0, 0);
                        sA1 = __builtin_amdgcn_mfma_f32_16x16x32_bf16(a1.v, qfa[f].v, sA1, 0, 0, 0);
                        sB1 = __builtin_amdgcn_mfma_f32_16x16x32_bf16(a1.v, qfb[f].v, sB1, 0, 0, 0);
                    }
                } else {        // A diagonal/dead; B full or diagonal
#pragma unroll
                    for (int f = 0; f < 6; ++f) {
                        const int ck = (f < 4) ? f * 2 : (f - 4) * 2 + 8;
                        U4 a0;
                        a0.u = *(const uint4*)&bb0[ck * 256 + abase];
                        if (liveA)
                            sA0 = __builtin_amdgcn_mfma_f32_16x16x32_bf16(a0.v, qfa[f].v, sA0, 0, 0, 0);
                        sB0 = __builtin_amdgcn_mfma_f32_16x16x32_bf16(a0.v, qfb[f].v, sB0, 0, 0, 0);
                        if (twoB) {
                            U4 a1;
                            a1.u = *(const uint4*)&bb0[(ck + 1) * 256 + abase];
                            sB1 = __builtin_amdgcn_mfma_f32_16x16x32_bf16(a1.v, qfb[f].v, sB1, 0, 0, 0);
                        }
                    }
                }

                U4 bbB = softpack(sB0, sB1, t0, row0b, lB);
                if (liveA) {
                    U4 bbA = softpack(sA0, sA1, t0, row0a, lA);
#pragma unroll
                    for (int c = 0; c < 8; ++c) {
                        U4 av; av.u = *(const uint4*)&bb0[(12 + c) * 256 + abase];
                        oB[c] = __builtin_amdgcn_mfma_f32_16x16x32_bf16(av.v, bbB.v, oB[c], 0, 0, 0);
                        oA[c] = __builtin_amdgcn_mfma_f32_16x16x32_bf16(av.v, bbA.v, oA[c], 0, 0, 0);
                    }
                } else {
#pragma unroll
                    for (int c = 0; c < 8; ++c) {
                        U4 av; av.u = *(const uint4*)&bb0[(12 + c) * 256 + abase];
                        oB[c] = __builtin_amdgcn_mfma_f32_16x16x32_bf16(av.v, bbB.v, oB[c], 0, 0, 0);
                    }
                }
            }
            cur ^= 1;
        }

        // ---- epilogue: reduce l across q4 groups; store f32 partials
        lA += __shfl_xor(lA, 16, 64);
        lA += __shfl_xor(lA, 32, 64);
        lB += __shfl_xor(lB, 16, 64);
        lB += __shfl_xor(lB, 32, 64);

        const int cid  = (b * 16 + h) * 16 + chunk;
        const int slot = cid * 2 + par;
        float* po = part_o + (long long)slot * 16384;
        const int rA = wid * 16 + m;
        const int rB = rA + 64;
#pragma unroll
        for (int c = 0; c < 8; ++c) {
            *(f32x4*)&po[rA * 128 + c * 16 + q4 * 4] = oA[c];
            *(f32x4*)&po[rB * 128 + c * 16 + q4 * 4] = oB[c];
        }
        if (q4 == 0) {
            part_l[slot * 128 + rA] = lA;
            part_l[slot * 128 + rB] = lB;
        }
    }
}

// ---------------------------------------------------------------------------
// Combine the two parity partials: o = (o0+o1)/(l0+l1) -> o_h bf16.
// ---------------------------------------------------------------------------
__global__ __launch_bounds__(256) void combine_kernel(
    const float* __restrict__ part_o, const float* __restrict__ part_l,
    ushort* __restrict__ o_h)
{
    const int idx = blockIdx.x * 256 + threadIdx.x;    // 0..2,097,151
    const int d4  = (idx & 31) * 4;                    // 0..124
    const int r   = (idx >> 5) & 127;
    const int cid = idx >> 12;                         // 0..511
    const int chunk = cid & 15, h = (cid >> 4) & 15, b = cid >> 8;
    const long long s0 = (long long)(cid * 2) * 16384 + r * 128 + d4;
    float4 a = *(const float4*)&part_o[s0];
    float4 c = *(const float4*)&part_o[s0 + 16384];
    const float l = part_l[cid * 256 + r] + part_l[cid * 256 + 128 + r];
    const float inv = 1.0f / l;
    uint2 pk;
    pk.x = cvtpk((a.x + c.x) * inv, (a.y + c.y) * inv);
    pk.y = cvtpk((a.z + c.z) * inv, (a.w + c.w) * inv);
    const int s = chunk * 128 + r;
    *(uint2*)&o_h[(((long long)(b * S_ + s)) * H_ + h) * 128 + d4] = pk;
}

// ---------------------------------------------------------------------------
extern "C" void kernel_launch(void* const* d_in, const int* in_sizes, int n_in,
                              void* d_out, int out_size, void* d_ws, size_t ws_size,
                              hipStream_t stream)
{
    const float* x         = (const float*)d_in[0];
    const float* freqs     = (const float*)d_in[1];
    // d_in[2] = mask (unused: causal handled analytically)
    const float* wq_w      = (const float*)d_in[3];
    const float* wq_b      = (const float*)d_in[4];
    const float* wkv_a_w   = (const float*)d_in[5];
    const float* wkv_a_b   = (const float*)d_in[6];
    const float* kv_norm_w = (const float*)d_in[7];
    const float* wkv_b_w   = (const float*)d_in[8];
    const float* wo_w      = (const float*)d_in[9];
    const float* wo_b      = (const float*)d_in[10];
    float* out = (float*)d_out;

    // ---- workspace layout: persistent region + overlaid scratch
    char* w = (char*)d_ws;
    ushort* wo_bf   = (ushort*)w;  w += 8388608;    // (2048,2048) bf16
    uint4*  khimg   = (uint4*)w;   w += 16777216;   // (B,64,16,8,64)
    uint4*  vhimg   = (uint4*)w;   w += 16777216;   // (B,64,16,8,64)
    uint4*  rimg    = (uint4*)w;   w += 524288;     // (B,64,4,64)
    ushort* q192    = (ushort*)w;  w += 25165824;   // (4096,16,192) bf16
    ushort* o_h     = (ushort*)w;  w += 16777216;   // (4096,16,128) bf16
    char* SCR = w;                                  // scratch: ~97 MB
    // phase 1 (conv + GEMM1/2):
    ushort* x_bf    = (ushort*)(SCR);               // 16,777,216
    ushort* wq_bf   = (ushort*)(SCR + 16777216);    // 12,582,912
    ushort* wkva_bf = (ushort*)(SCR + 29360128);    //  2,621,440
    ushort* wkvbK   = (ushort*)(SCR + 31981568);    //  2,097,152 (live thru step5)
    ushort* wkvbV   = (ushort*)(SCR + 34078720);    //  2,097,152 (live thru step5)
    float*  kv_raw  = (float*)(SCR + 36175872);     // 10,485,760 (dead after step4)
    float*  q_raw   = (float*)(SCR + 46661632);     // 50,331,648 (dead after step3)
    // phase 2 overlay (x_bf dead after step2):
    ushort* kv_h    = (ushort*)(SCR);               //  4,718,592 (over x_bf)
    // phase 3 overlays (attn partials; everything above dead by attn):
    float*  part_o  = (float*)(SCR);                // 67,108,864
    float*  part_l  = (float*)(SCR + 67108864);     //    524,288

    dim3 blk(256);

    // 0) all f32->bf16 conversions, one launch
    conv_all<<<dim3(21760), blk, 0, stream>>>(
        x, wq_w, wkv_a_w, wo_w, wkv_b_w,
        x_bf, wq_bf, wkva_bf, wo_bf, wkvbK, wkvbV);

    // 1) q_raw = x @ wq_w^T + wq_b
    mgemm<0><<<dim3(24, 32, 1), blk, 0, stream>>>(
        x_bf, 2048, 0LL, 0LL, wq_bf, 2048, 0LL, 0LL, wq_b, 1.0f,
        q_raw, 3072, 0LL, 0LL, 2048, 1);

    // 2) kv_raw = x @ wkv_a_w^T (N=640 padded; bias folded into kv_post)
    mgemm<0><<<dim3(5, 32, 1), blk, 0, stream>>>(
        x_bf, 2048, 0LL, 0LL, wkva_bf, 2048, 0LL, 0LL, nullptr, 1.0f,
        kv_raw, 640, 0LL, 0LL, 2048, 1);

    // 3) q192 = [q_nope, rope(q_pe)] * scale * log2e, bf16
    qprep<<<dim3(12288), blk, 0, stream>>>(q_raw, freqs, q192);

    // 4) bias + rmsnorm -> kv_h; rope -> rimg directly
    kv_post_kernel<<<dim3(4096), dim3(64), 0, stream>>>(
        kv_raw, wkv_a_b, kv_norm_w, freqs, kv_h, (uint*)rimg);

    // 5) per-head K/V projections writing DIRECTLY in fragment-image layout:
    //    khimg <- kv_proj @ wkv_b[h,:128]^T   (rows t, cols d; z1=h, z2=b)
    mgemm<2><<<dim3(1, 16, 32), blk, 0, stream>>>(
        kv_h, 576, 0LL, (long long)S_ * 576,
        wkvbK, 512, 65536LL, 0LL, nullptr, 1.0f,
        khimg, 0, 0LL, 0LL, 512, 16);
    //    vhimg <- wkv_b[h,128:] @ kv_proj^T   (rows d, cols t; z1=h, z2=b)
    mgemm<3><<<dim3(16, 1, 32), blk, 0, stream>>>(
        wkvbV, 512, 65536LL, 0LL,
        kv_h, 576, 0LL, (long long)S_ * 576, nullptr, 1.0f,
        vhimg, 0, 0LL, 0LL, 512, 16);

    // 6) MFMA flash attention v13 (split-T, XCD-grouped) -> f32 partials
    attn_kernel<<<dim3(32, 8, 2), blk, 0, stream>>>(
        q192, khimg, rimg, vhimg, part_o, part_l);

    // 6b) combine parity partials -> o_h bf16
    combine_kernel<<<dim3(8192), blk, 0, stream>>>(part_o, part_l, o_h);

    // 7) out = o_h @ wo_w^T + wo_b
    mgemm<0><<<dim3(16, 32, 1), blk, 0, stream>>>(
        o_h, 2048, 0LL, 0LL, wo_bf, 2048, 0LL, 0LL, wo_b, 1.0f,
        out, 2048, 0LL, 0LL, 2048, 1);
}

// Round 7
// 440.219 us; speedup vs baseline: 1.7186x; 1.0076x over previous
//
#include <hip/hip_runtime.h>
#include <hip/hip_bf16.h>
#include <math.h>

// MLA forward: B=2, S=2048, D=2048, H=16, KV_RANK=512, NOPE=128, ROPE=64
#define B_ 2
#define S_ 2048
#define H_ 16
#define SCALE_ 0.07216878364870323f   // 192^-0.5
#define SL2_ (0.07216878364870323f * 1.4426950408889634f)  // scale * log2(e)
#define EPS_ 1.1920929e-07f
#define M0_ 8.0f                      // constant exp2 shift (cancels in o/l)

typedef __attribute__((ext_vector_type(8))) short bf16x8;
typedef __attribute__((ext_vector_type(4))) float f32x4;
union U4 { uint4 u; bf16x8 v; f32x4 f; };

__device__ __forceinline__ uint bfbits(float x) {   // f32 -> bf16 bits, RNE
    uint u = __float_as_uint(x);
    return (u + 0x7fffu + ((u >> 16) & 1u)) >> 16;
}
__device__ __forceinline__ uint pack2bf(float a, float b) {
    return bfbits(a) | (bfbits(b) << 16);
}
__device__ __forceinline__ uint cvtpk(float a, float b) {  // 1 VALU op, RNE
    uint r;
    asm("v_cvt_pk_bf16_f32 %0, %1, %2" : "=v"(r) : "v"(a), "v"(b));
    return r;
}
__device__ __forceinline__ void gld_lds16(const ushort* g, ushort* l) {
    // async global->LDS DMA, 16B/lane; LDS dest = wave-uniform base + lane*16
    __builtin_amdgcn_global_load_lds(
        (const __attribute__((address_space(1))) uint*)g,
        (__attribute__((address_space(3))) uint*)l, 16, 0, 0);
}

// ---------------------------------------------------------------------------
// MFMA bf16 GEMM (NT): C[m,n] = scale * sum_k A[m,k]*B[n,k] + bias[n]
// 128x128 tile, BK=32, 256 thr (4 waves 2x2 of 64x64), 16x16x32 MFMA.
// v2: double-buffered LDS, prefetch next K-step under compute (T3 2-phase,
// one barrier per K-step; read-drain guaranteed by waitcnt-before-MFMA +
// barrier, same discipline as the attn loop).
// z decomposed as z1 = z % zDiv (stride *Off1), z2 = z / zDiv (stride *Off2).
// XCD-bijective tile swizzle when (gx*gy)%8==0 (L2 panel locality).
// OM: 0 = f32 linear (+bias,scale)
//     1 = q192 bf16: bias + RoPE on cols d%192>=128 + SL2 scale (freqs used)
//     2 = khimg fragment layout (z1=h, z2=b)
//     3 = vhimg fragment layout (z1=h, z2=b)
// ---------------------------------------------------------------------------
template<int OM>
__global__ __launch_bounds__(256) void mgemm(
    const ushort* __restrict__ A, int lda, long long aOff1, long long aOff2,
    const ushort* __restrict__ Bm, int ldb, long long bOff1, long long bOff2,
    const float* __restrict__ bias, float scale,
    void* __restrict__ Cv, int ldc, long long cOff1, long long cOff2,
    int K, int zDiv, const float* __restrict__ freqs)
{
    __shared__ ushort As[2][128 * 32];
    __shared__ ushort Bs[2][128 * 32];

    const int z = blockIdx.z;
    const int z1 = z % zDiv, z2 = z / zDiv;
    A  += z1 * aOff1 + z2 * aOff2;
    Bm += z1 * bOff1 + z2 * bOff2;
    const long long cBase = z1 * cOff1 + z2 * cOff2;

    // XCD-bijective swizzle over the (x,y) tile space
    int bx = blockIdx.x, by = blockIdx.y;
    {
        const int gx = gridDim.x, total = gx * gridDim.y;
        if ((total & 7) == 0) {
            const int flat = bx + gx * by;
            const int nx = total >> 3;
            const int flat2 = (flat & 7) * nx + (flat >> 3);
            bx = flat2 % gx;
            by = flat2 / gx;
        }
    }
    const int n0 = bx * 128;
    const int m0 = by * 128;
    const int tid = threadIdx.x;
    const int w   = tid >> 6;
    const int l   = tid & 63;
    const int m   = l & 15;
    const int q4  = l >> 4;
    const int mw  = (w & 1) * 64;
    const int nw  = (w >> 1) * 64;
    const int sr  = l >> 2;
    const int sc  = l & 3;

    auto stageT = [&](int bi, int k0) {
#pragma unroll
        for (int jj = 0; jj < 2; ++jj) {
            const int slot = w * 2 + jj;
            const int row  = slot * 16 + sr;
            const int g    = sc ^ ((row >> 1) & 3);
            gld_lds16(&A[(long long)(m0 + row) * lda + k0 + g * 8], &As[bi][slot * 512]);
            gld_lds16(&Bm[(long long)(n0 + row) * ldb + k0 + g * 8], &Bs[bi][slot * 512]);
        }
    };

    f32x4 acc[4][4];
#pragma unroll
    for (int i = 0; i < 4; ++i)
#pragma unroll
        for (int j = 0; j < 4; ++j) acc[i][j] = (f32x4){0.f, 0.f, 0.f, 0.f};

    stageT(0, 0);
    int cur = 0;
    for (int k0 = 0; k0 < K; k0 += 32) {
        __syncthreads();                 // vmcnt drain: buf[cur] staged; prev reads done
        if (k0 + 32 < K) stageT(cur ^ 1, k0 + 32);   // prefetch under compute
        __builtin_amdgcn_sched_barrier(0);

        U4 af[4], bf[4];
#pragma unroll
        for (int i = 0; i < 4; ++i) {
            const int ra = mw + i * 16 + m;
            af[i].u = *(const uint4*)&As[cur][ra * 32 + (q4 ^ ((ra >> 1) & 3)) * 8];
            const int rb = nw + i * 16 + m;
            bf[i].u = *(const uint4*)&Bs[cur][rb * 32 + (q4 ^ ((rb >> 1) & 3)) * 8];
        }
#pragma unroll
        for (int i = 0; i < 4; ++i)
#pragma unroll
            for (int j = 0; j < 4; ++j)
                acc[i][j] = __builtin_amdgcn_mfma_f32_16x16x32_bf16(
                    af[i].v, bf[j].v, acc[i][j], 0, 0, 0);
        cur ^= 1;
    }

#pragma unroll
    for (int j = 0; j < 4; ++j) {
        const int cn = n0 + nw + j * 16 + m;
        const float bv = bias ? bias[cn] : 0.0f;
        const int d192 = cn % 192;             // 16-aligned windows: wave-uniform region
        const bool ropeW = (OM == 1) && (d192 >= 128);
        const int ri = (d192 - 128) >> 1;      // rope pair index (lane-varying)
        const bool evn = !(cn & 1);
#pragma unroll
        for (int i2 = 0; i2 < 4; ++i2) {
            const int rw = m0 + mw + i2 * 16 + q4 * 4;
#pragma unroll
            for (int r = 0; r < 4; ++r) {
                if (OM == 0) {
                    const float val = acc[i2][j][r] * scale + bv;
                    ((float*)Cv)[cBase + (long long)(rw + r) * ldc + cn] = val;
                } else if (OM == 1) {
                    float val = acc[i2][j][r] + bv;      // bias before rope
                    if (ropeW) {
                        const float pv = __shfl_xor(val, 1, 64);
                        const float a  = evn ? val : pv;
                        const float b  = evn ? pv : val;
                        const int s = (rw + r) & 2047;
                        float cs, sn;
                        __sincosf(freqs[s * 32 + ri], &sn, &cs);
                        val = evn ? (a * cs - b * sn) : (a * sn + b * cs);
                    }
                    ((ushort*)Cv)[cBase + (long long)(rw + r) * ldc + cn] =
                        (ushort)bfbits(val * SL2_);
                } else if (OM == 2) {
                    const float val = acc[i2][j][r] * scale + bv;
                    // khimg[b][t>>5][h][(d>>5)*2 + ((t>>4)&1)][(d>>3)&3][t&15][d&7]
                    const int t = rw + r, d = cn;
                    const long long idx =
                        ((((long long)(z2 * 64 + (t >> 5)) * 16 + z1) * 8
                          + (d >> 5) * 2 + ((t >> 4) & 1)) * 64
                         + ((d >> 3) & 3) * 16 + (t & 15)) * 8 + (d & 7);
                    ((ushort*)Cv)[idx] = (ushort)bfbits(val);
                } else {
                    const float val = acc[i2][j][r] * scale + bv;
                    // vhimg[b][t>>5][h][d>>4][(t>>3)&3][d&15][t&7]
                    const int d = rw + r, t = cn;
                    const long long idx =
                        ((((long long)(z2 * 64 + (t >> 5)) * 16 + z1) * 8
                          + (d >> 4)) * 64
                         + ((t >> 3) & 3) * 16 + (d & 15)) * 8 + (t & 7);
                    ((ushort*)Cv)[idx] = (ushort)bfbits(val);
                }
            }
        }
    }
}

// ---------------------------------------------------------------------------
// Fused f32 -> bf16 conversions (one launch).
// ---------------------------------------------------------------------------
__global__ __launch_bounds__(256) void conv_all(
    const float* __restrict__ x, const float* __restrict__ wq,
    const float* __restrict__ wkva, const float* __restrict__ wo,
    const float* __restrict__ wkvb,
    ushort* __restrict__ x_bf, ushort* __restrict__ wq_bf,
    ushort* __restrict__ wkva_bf, ushort* __restrict__ wo_bf,
    ushort* __restrict__ wkvbK, ushort* __restrict__ wkvbV)
{
    const int bid = blockIdx.x;
    const int tid = threadIdx.x;
    if (bid < 8192) {                       // x: (4096,2048)
        const long long i = ((long long)bid * 256 + tid) * 4;
        float4 v = *(const float4*)&x[i];
        uint2 p; p.x = pack2bf(v.x, v.y); p.y = pack2bf(v.z, v.w);
        *(uint2*)&x_bf[i] = p;
    } else if (bid < 14336) {               // wq: (3072,2048)
        const long long i = ((long long)(bid - 8192) * 256 + tid) * 4;
        float4 v = *(const float4*)&wq[i];
        uint2 p; p.x = pack2bf(v.x, v.y); p.y = pack2bf(v.z, v.w);
        *(uint2*)&wq_bf[i] = p;
    } else if (bid < 15616) {               // wkva: (576,2048) pad to 640
        const int i = ((bid - 14336) * 256 + tid) * 4;
        const int r = i >> 11;
        uint2 p = make_uint2(0u, 0u);
        if (r < 576) {
            float4 v = *(const float4*)&wkva[i];
            p.x = pack2bf(v.x, v.y); p.y = pack2bf(v.z, v.w);
        }
        *(uint2*)&wkva_bf[i] = p;
    } else if (bid < 19712) {               // wo: (2048,2048)
        const long long i = ((long long)(bid - 15616) * 256 + tid) * 4;
        float4 v = *(const float4*)&wo[i];
        uint2 p; p.x = pack2bf(v.x, v.y); p.y = pack2bf(v.z, v.w);
        *(uint2*)&wo_bf[i] = p;
    } else if (bid < 20736) {               // wkv_b rows [0:128) per head -> K
        const int i = ((bid - 19712) * 256 + tid) * 4;
        const int h = i >> 16, rem = i & 65535;
        float4 v = *(const float4*)&wkvb[((long long)(h * 256)) * 512 + rem];
        uint2 p; p.x = pack2bf(v.x, v.y); p.y = pack2bf(v.z, v.w);
        *(uint2*)&wkvbK[i] = p;
    } else {                                // wkv_b rows [128:256) per head -> V
        const int i = ((bid - 20736) * 256 + tid) * 4;
        const int h = i >> 16, rem = i & 65535;
        float4 v = *(const float4*)&wkvb[((long long)(h * 256 + 128)) * 512 + rem];
        uint2 p; p.x = pack2bf(v.x, v.y); p.y = pack2bf(v.z, v.w);
        *(uint2*)&wkvbV[i] = p;
    }
}

// ---------------------------------------------------------------------------
// kv post: bias add + rmsnorm(kv[:512]) -> kv_h bf16; rope(kv[512:576])
// written DIRECTLY in rimg fragment layout.
// ---------------------------------------------------------------------------
__global__ __launch_bounds__(64) void kv_post_kernel(
    const float* __restrict__ kv_raw, const float* __restrict__ bias,
    const float* __restrict__ w, const float* __restrict__ freqs,
    ushort* __restrict__ kv_h, uint* __restrict__ rimg)
{
    const int bs = blockIdx.x;
    const int lane = threadIdx.x;
    const float* src = kv_raw + (long long)bs * 640;
    ushort* dst = kv_h + (long long)bs * 576;

    const int c = 4 * lane;
    float4 v0 = *(const float4*)&src[c];
    float4 v1 = *(const float4*)&src[256 + c];
    float4 b0 = *(const float4*)&bias[c];
    float4 b1 = *(const float4*)&bias[256 + c];
    v0.x += b0.x; v0.y += b0.y; v0.z += b0.z; v0.w += b0.w;
    v1.x += b1.x; v1.y += b1.y; v1.z += b1.z; v1.w += b1.w;
    float ss = v0.x * v0.x + v0.y * v0.y + v0.z * v0.z + v0.w * v0.w +
               v1.x * v1.x + v1.y * v1.y + v1.z * v1.z + v1.w * v1.w;
#pragma unroll
    for (int o = 32; o; o >>= 1) ss += __shfl_xor(ss, o, 64);
    const float rs = rsqrtf(ss * (1.0f / 512.0f) + EPS_);

    float4 w0 = *(const float4*)&w[c];
    float4 w1 = *(const float4*)&w[256 + c];
    uint2 p0, p1;
    p0.x = pack2bf(v0.x * rs * w0.x, v0.y * rs * w0.y);
    p0.y = pack2bf(v0.z * rs * w0.z, v0.w * rs * w0.w);
    p1.x = pack2bf(v1.x * rs * w1.x, v1.y * rs * w1.y);
    p1.y = pack2bf(v1.z * rs * w1.z, v1.w * rs * w1.w);
    *(uint2*)&dst[c] = p0;
    *(uint2*)&dst[256 + c] = p1;

    if (lane < 32) {
        const int b = bs >> 11, s = bs & 2047;
        const int j = lane;
        const float f = freqs[s * 32 + j];
        float cs, sn;
        __sincosf(f, &sn, &cs);
        const float a  = src[512 + 2 * j]     + bias[512 + 2 * j];
        const float b2 = src[512 + 2 * j + 1] + bias[512 + 2 * j + 1];
        const uint p = pack2bf(a * cs - b2 * sn, a * sn + b2 * cs);
        const long long idx =
            (((long long)(b * 64 + (s >> 5)) * 4 + (j >> 4) * 2 + ((s >> 4) & 1)) * 64
             + ((j >> 2) & 3) * 16 + (s & 15)) * 4 + (j & 3);
        rimg[idx] = p;
    }
}

// ---------------------------------------------------------------------------
// MFMA flash attention v13 (unchanged from round 6): split-T + XCD-grouped.
// Grid (32 = h + 16b, 8 = pair, 2 = parity) = 512 blocks = 2/CU, uniform
// 34 tiles each; f32 partials + combine (constant-shift softmax).
// ---------------------------------------------------------------------------
__global__ __launch_bounds__(256, 2) void attn_kernel(
    const ushort* __restrict__ q192,  // (B,S,H,192), q*scale*log2e
    const uint4*  __restrict__ khimg, // (B,64,16,8,64) K_h frag chunks
    const uint4*  __restrict__ rimg,  // (B,64,4,64)   k_pe frag chunks
    const uint4*  __restrict__ vhimg, // (B,64,16,8,64) V_h^T frag chunks
    float* __restrict__ part_o,       // (512*2,128,128) f32 partial O
    float* __restrict__ part_l)       // (512*2,128)     f32 partial l
{
    __shared__ uint buf[2][20 * 256];   // 2 x 20 KB

    const int hb   = blockIdx.x;          // 0..31: h + 16*b (XCD = hb & 7)
    const int h    = hb & 15;
    const int b    = hb >> 4;
    const int p    = blockIdx.y;          // 0..7 (chunk pair)
    const int par  = blockIdx.z;          // tile parity
    const int tid  = threadIdx.x;
    const int wid  = tid >> 6;            // 0..3
    const int lane = tid & 63;
    const int m    = lane & 15;
    const int q4   = lane >> 4;
    const bool odd = q4 & 1;

    auto stage = [&](int bs, int it) {
        const long long tb = (long long)(b * 64 + it);
        const uint4* kb = khimg + ((tb * 16 + h) * 8) * 64;
        const uint4* rb = rimg  + (tb * 4) * 64;
        const uint4* vb = vhimg + ((tb * 16 + h) * 8) * 64;
        ushort* l = (ushort*)&buf[bs][0];
        gld_lds16((const ushort*)(kb + (wid    ) * 64 + lane), l + (wid     ) * 512);
        gld_lds16((const ushort*)(kb + (wid + 4) * 64 + lane), l + (wid +  4) * 512);
        gld_lds16((const ushort*)(rb + (wid    ) * 64 + lane), l + (wid +  8) * 512);
        gld_lds16((const ushort*)(vb + (wid    ) * 64 + lane), l + (wid + 12) * 512);
        gld_lds16((const ushort*)(vb + (wid + 4) * 64 + lane), l + (wid + 16) * 512);
    };

    int cur = 0;
    for (int pass = 0; pass < 2; ++pass) {
        const int chunk = pass ? p : (15 - p);
        const int row0a = chunk * 128 + wid * 16;
        const int row0b = row0a + 64;
        const int sRa   = row0a + m;
        const int sRb   = row0b + m;

        U4 qfa[6], qfb[6];
        {
            const uint4* qpa = (const uint4*)(q192 + ((long long)(b * S_ + sRa) * H_ + h) * 192);
            const uint4* qpb = (const uint4*)(q192 + ((long long)(b * S_ + sRb) * H_ + h) * 192);
#pragma unroll
            for (int f = 0; f < 6; ++f) { qfa[f].u = qpa[f * 4 + q4]; qfb[f].u = qpb[f * 4 + q4]; }
        }

        f32x4 oA[8], oB[8];
#pragma unroll
        for (int c = 0; c < 8; ++c) {
            oA[c] = (f32x4){0.f, 0.f, 0.f, 0.f};
            oB[c] = (f32x4){0.f, 0.f, 0.f, 0.f};
        }
        float lA = 0.0f, lB = 0.0f;

        auto softpack = [&](const f32x4 s0, const f32x4 s1, int t0v, int rw0,
                            float& lac) -> U4 {
            float p00, p01, p02, p03, p10, p11, p12, p13;
            if (t0v + 31 <= rw0) {            // fully unmasked tile
                p00 = exp2f(s0[0] - M0_); p01 = exp2f(s0[1] - M0_);
                p02 = exp2f(s0[2] - M0_); p03 = exp2f(s0[3] - M0_);
                p10 = exp2f(s1[0] - M0_); p11 = exp2f(s1[1] - M0_);
                p12 = exp2f(s1[2] - M0_); p13 = exp2f(s1[3] - M0_);
            } else {                          // diagonal tile
                const int sR = rw0 + m;
                const int tb0 = t0v + q4 * 4;
                const int tb1 = tb0 + 16;
                p00 = (tb0 + 0 <= sR) ? exp2f(s0[0] - M0_) : 0.0f;
                p01 = (tb0 + 1 <= sR) ? exp2f(s0[1] - M0_) : 0.0f;
                p02 = (tb0 + 2 <= sR) ? exp2f(s0[2] - M0_) : 0.0f;
                p03 = (tb0 + 3 <= sR) ? exp2f(s0[3] - M0_) : 0.0f;
                p10 = (tb1 + 0 <= sR) ? exp2f(s1[0] - M0_) : 0.0f;
                p11 = (tb1 + 1 <= sR) ? exp2f(s1[1] - M0_) : 0.0f;
                p12 = (tb1 + 2 <= sR) ? exp2f(s1[2] - M0_) : 0.0f;
                p13 = (tb1 + 3 <= sR) ? exp2f(s1[3] - M0_) : 0.0f;
            }
            lac += (p00 + p01) + (p02 + p03) + (p10 + p11) + (p12 + p13);
            uint X0 = cvtpk(p00, p01), X1 = cvtpk(p02, p03);
            uint Y0 = cvtpk(p10, p11), Y1 = cvtpk(p12, p13);
            asm("v_permlane32_swap_b32 %0, %1" : "+v"(X0), "+v"(Y0));
            asm("v_permlane32_swap_b32 %0, %1" : "+v"(X1), "+v"(Y1));
            uint u0 = odd ? X0 : Y0;
            uint u1 = odd ? X1 : Y1;
            uint w0 = (uint)__builtin_amdgcn_ds_swizzle((int)u0, 0x401F); // xor 16
            uint w1 = (uint)__builtin_amdgcn_ds_swizzle((int)u1, 0x401F);
            U4 bb;
            bb.u.x = odd ? w0 : X0;
            bb.u.y = odd ? w1 : X1;
            bb.u.z = odd ? Y0 : w0;
            bb.u.w = odd ? Y1 : w1;
            return bb;
        };

        const int nT2 = 2 * chunk + 2;        // parity-tiles in this pass
        __syncthreads();                 // all reads of prev pass's LDS done
        stage(cur, par);

        for (int v = 0; v < nT2; ++v) {
            const int it = 2 * v + par;
            const int t0 = it * 32;
            __syncthreads();             // drains vmcnt(0): buf[cur] staged
            if (v + 1 < nT2) stage(cur ^ 1, it + 2);   // overlap under compute
            __builtin_amdgcn_sched_barrier(0);

            const uint* bb0 = &buf[cur][0];
            const int abase = lane * 4;
            const bool liveB = (t0 <= row0b + 15);
            const bool liveA = (t0 <= row0a + 15);
            const bool twoA  = (t0 < row0a);
            const bool twoB  = (t0 < row0b);

            if (liveB) {
                f32x4 sA0 = (f32x4){0.f,0.f,0.f,0.f}, sA1 = (f32x4){0.f,0.f,0.f,0.f};
                f32x4 sB0 = (f32x4){0.f,0.f,0.f,0.f}, sB1 = (f32x4){0.f,0.f,0.f,0.f};

                if (twoA) {     // both substrips full: 4 MFMAs per read-pair
#pragma unroll
                    for (int f = 0; f < 6; ++f) {
                        const int ck = (f < 4) ? f * 2 : (f - 4) * 2 + 8;
                        U4 a0, a1;
                        a0.u = *(const uint4*)&bb0[ck * 256 + abase];
                        a1.u = *(const uint4*)&bb0[(ck + 1) * 256 + abase];
                        sA0 = __builtin_amdgcn_mfma_f32_16x16x32_bf16(a0.v, qfa[f].v, sA0, 0, 0, 0);
                        sB0 = __builtin_amdgcn_mfma_f32_16x16x32_bf16(a0.v, qfb[f].v, sB0, 0, 0, 0);
                        sA1 = __builtin_amdgcn_mfma_f32_16x16x32_bf16(a1.v, qfa[f].v, sA1, 0, 0, 0);
                        sB1 = __builtin_amdgcn_mfma_f32_16x16x32_bf16(a1.v, qfb[f].v, sB1, 0, 0, 0);
                    }
                } else {        // A diagonal/dead; B full or diagonal
#pragma unroll
                    for (int f = 0; f < 6; ++f) {
                        const int ck = (f < 4) ? f * 2 : (f - 4) * 2 + 8;
                        U4 a0;
                        a0.u = *(const uint4*)&bb0[ck * 256 + abase];
                        if (liveA)
                            sA0 = __builtin_amdgcn_mfma_f32_16x16x32_bf16(a0.v, qfa[f].v, sA0, 0, 0, 0);
                        sB0 = __builtin_amdgcn_mfma_f32_16x16x32_bf16(a0.v, qfb[f].v, sB0, 0, 0, 0);
                        if (twoB) {
                            U4 a1;
                            a1.u = *(const uint4*)&bb0[(ck + 1) * 256 + abase];
                            sB1 = __builtin_amdgcn_mfma_f32_16x16x32_bf16(a1.v, qfb[f].v, sB1, 0, 0, 0);
                        }
                    }
                }

                U4 bbB = softpack(sB0, sB1, t0, row0b, lB);
                if (liveA) {
                    U4 bbA = softpack(sA0, sA1, t0, row0a, lA);
#pragma unroll
                    for (int c = 0; c < 8; ++c) {
                        U4 av; av.u = *(const uint4*)&bb0[(12 + c) * 256 + abase];
                        oB[c] = __builtin_amdgcn_mfma_f32_16x16x32_bf16(av.v, bbB.v, oB[c], 0, 0, 0);
                        oA[c] = __builtin_amdgcn_mfma_f32_16x16x32_bf16(av.v, bbA.v, oA[c], 0, 0, 0);
                    }
                } else {
#pragma unroll
                    for (int c = 0; c < 8; ++c) {
                        U4 av; av.u = *(const uint4*)&bb0[(12 + c) * 256 + abase];
                        oB[c] = __builtin_amdgcn_mfma_f32_16x16x32_bf16(av.v, bbB.v, oB[c], 0, 0, 0);
                    }
                }
            }
            cur ^= 1;
        }

        // ---- epilogue: reduce l across q4 groups; store f32 partials
        lA += __shfl_xor(lA, 16, 64);
        lA += __shfl_xor(lA, 32, 64);
        lB += __shfl_xor(lB, 16, 64);
        lB += __shfl_xor(lB, 32, 64);

        const int cid  = (b * 16 + h) * 16 + chunk;
        const int slot = cid * 2 + par;
        float* po = part_o + (long long)slot * 16384;
        const int rA = wid * 16 + m;
        const int rB = rA + 64;
#pragma unroll
        for (int c = 0; c < 8; ++c) {
            *(f32x4*)&po[rA * 128 + c * 16 + q4 * 4] = oA[c];
            *(f32x4*)&po[rB * 128 + c * 16 + q4 * 4] = oB[c];
        }
        if (q4 == 0) {
            part_l[slot * 128 + rA] = lA;
            part_l[slot * 128 + rB] = lB;
        }
    }
}

// ---------------------------------------------------------------------------
// Combine the two parity partials: o = (o0+o1)/(l0+l1) -> o_h bf16.
// ---------------------------------------------------------------------------
__global__ __launch_bounds__(256) void combine_kernel(
    const float* __restrict__ part_o, const float* __restrict__ part_l,
    ushort* __restrict__ o_h)
{
    const int idx = blockIdx.x * 256 + threadIdx.x;    // 0..2,097,151
    const int d4  = (idx & 31) * 4;                    // 0..124
    const int r   = (idx >> 5) & 127;
    const int cid = idx >> 12;                         // 0..511
    const int chunk = cid & 15, h = (cid >> 4) & 15, b = cid >> 8;
    const long long s0 = (long long)(cid * 2) * 16384 + r * 128 + d4;
    float4 a = *(const float4*)&part_o[s0];
    float4 c = *(const float4*)&part_o[s0 + 16384];
    const float l = part_l[cid * 256 + r] + part_l[cid * 256 + 128 + r];
    const float inv = 1.0f / l;
    uint2 pk;
    pk.x = cvtpk((a.x + c.x) * inv, (a.y + c.y) * inv);
    pk.y = cvtpk((a.z + c.z) * inv, (a.w + c.w) * inv);
    const int s = chunk * 128 + r;
    *(uint2*)&o_h[(((long long)(b * S_ + s)) * H_ + h) * 128 + d4] = pk;
}

// ---------------------------------------------------------------------------
extern "C" void kernel_launch(void* const* d_in, const int* in_sizes, int n_in,
                              void* d_out, int out_size, void* d_ws, size_t ws_size,
                              hipStream_t stream)
{
    const float* x         = (const float*)d_in[0];
    const float* freqs     = (const float*)d_in[1];
    // d_in[2] = mask (unused: causal handled analytically)
    const float* wq_w      = (const float*)d_in[3];
    const float* wq_b      = (const float*)d_in[4];
    const float* wkv_a_w   = (const float*)d_in[5];
    const float* wkv_a_b   = (const float*)d_in[6];
    const float* kv_norm_w = (const float*)d_in[7];
    const float* wkv_b_w   = (const float*)d_in[8];
    const float* wo_w      = (const float*)d_in[9];
    const float* wo_b      = (const float*)d_in[10];
    float* out = (float*)d_out;

    // ---- workspace layout: persistent region + overlaid scratch
    char* w = (char*)d_ws;
    ushort* wo_bf   = (ushort*)w;  w += 8388608;    // (2048,2048) bf16
    uint4*  khimg   = (uint4*)w;   w += 16777216;   // (B,64,16,8,64)
    uint4*  vhimg   = (uint4*)w;   w += 16777216;   // (B,64,16,8,64)
    uint4*  rimg    = (uint4*)w;   w += 524288;     // (B,64,4,64)
    ushort* q192    = (ushort*)w;  w += 25165824;   // (4096,16,192) bf16
    ushort* o_h     = (ushort*)w;  w += 16777216;   // (4096,16,128) bf16
    char* SCR = w;                                  // scratch: ~68 MB
    // phase 1 (conv + GEMM1/2):
    ushort* x_bf    = (ushort*)(SCR);               // 16,777,216
    ushort* wq_bf   = (ushort*)(SCR + 16777216);    // 12,582,912
    ushort* wkva_bf = (ushort*)(SCR + 29360128);    //  2,621,440
    ushort* wkvbK   = (ushort*)(SCR + 31981568);    //  2,097,152 (live thru step5)
    ushort* wkvbV   = (ushort*)(SCR + 34078720);    //  2,097,152 (live thru step5)
    float*  kv_raw  = (float*)(SCR + 36175872);     // 10,485,760 (dead after step4)
    // phase 2 overlay (x_bf dead after step2):
    ushort* kv_h    = (ushort*)(SCR);               //  4,718,592 (over x_bf)
    // phase 3 overlays (attn partials; everything above dead by attn):
    float*  part_o  = (float*)(SCR);                // 67,108,864
    float*  part_l  = (float*)(SCR + 67108864);     //    524,288

    dim3 blk(256);

    // 0) all f32->bf16 conversions, one launch
    conv_all<<<dim3(21760), blk, 0, stream>>>(
        x, wq_w, wkv_a_w, wo_w, wkv_b_w,
        x_bf, wq_bf, wkva_bf, wo_bf, wkvbK, wkvbV);

    // 1) q192 = [x @ wq_w^T + wq_b, roped, *scale*log2e] bf16 (fused epilogue)
    mgemm<1><<<dim3(24, 32, 1), blk, 0, stream>>>(
        x_bf, 2048, 0LL, 0LL, wq_bf, 2048, 0LL, 0LL, wq_b, 1.0f,
        q192, 3072, 0LL, 0LL, 2048, 1, freqs);

    // 2) kv_raw = x @ wkv_a_w^T (N=640 padded; bias folded into kv_post)
    mgemm<0><<<dim3(5, 32, 1), blk, 0, stream>>>(
        x_bf, 2048, 0LL, 0LL, wkva_bf, 2048, 0LL, 0LL, nullptr, 1.0f,
        kv_raw, 640, 0LL, 0LL, 2048, 1, nullptr);

    // 3) bias + rmsnorm -> kv_h; rope -> rimg directly
    kv_post_kernel<<<dim3(4096), dim3(64), 0, stream>>>(
        kv_raw, wkv_a_b, kv_norm_w, freqs, kv_h, (uint*)rimg);

    // 4) per-head K/V projections writing DIRECTLY in fragment-image layout:
    mgemm<2><<<dim3(1, 16, 32), blk, 0, stream>>>(
        kv_h, 576, 0LL, (long long)S_ * 576,
        wkvbK, 512, 65536LL, 0LL, nullptr, 1.0f,
        khimg, 0, 0LL, 0LL, 512, 16, nullptr);
    mgemm<3><<<dim3(16, 1, 32), blk, 0, stream>>>(
        wkvbV, 512, 65536LL, 0LL,
        kv_h, 576, 0LL, (long long)S_ * 576, nullptr, 1.0f,
        vhimg, 0, 0LL, 0LL, 512, 16, nullptr);

    // 5) MFMA flash attention v13 (split-T, XCD-grouped) -> f32 partials
    attn_kernel<<<dim3(32, 8, 2), blk, 0, stream>>>(
        q192, khimg, rimg, vhimg, part_o, part_l);

    // 5b) combine parity partials -> o_h bf16
    combine_kernel<<<dim3(8192), blk, 0, stream>>>(part_o, part_l, o_h);

    // 6) out = o_h @ wo_w^T + wo_b
    mgemm<0><<<dim3(16, 32, 1), blk, 0, stream>>>(
        o_h, 2048, 0LL, 0LL, wo_bf, 2048, 0LL, 0LL, wo_b, 1.0f,
        out, 2048, 0LL, 0LL, 2048, 1, nullptr);
}